// Round 2
// baseline (4625.058 us; speedup 1.0000x reference)
//
#include <hip/hip_runtime.h>
#include <math.h>

// ---------------- problem constants ----------------
static constexpr int  cB   = 16;
static constexpr int  cS   = 4096;
static constexpr int  cDIN = 64;
static constexpr int  cE   = 512;
static constexpr int  cM   = 128;
static constexpr int  cL   = 4;
static constexpr int  cFF  = 2048;   // 4*E
static constexpr int  cHE  = 256;    // E/2
static constexpr long cNBS = (long)cB * cS;   // 65536 rows

typedef __attribute__((ext_vector_type(8))) short  bf16x8;
typedef __attribute__((ext_vector_type(4))) short  bf16x4;
typedef __attribute__((ext_vector_type(4))) float  f32x4;

typedef const __attribute__((address_space(1))) unsigned int g_u32;
typedef __attribute__((address_space(3))) unsigned int l_u32;

__device__ __forceinline__ float b2f(unsigned short u) {
  union { unsigned int i; float f; } x; x.i = ((unsigned int)u) << 16; return x.f;
}
__device__ __forceinline__ unsigned short f2b(float f) {
  union { float f; unsigned int i; } x; x.f = f;
  unsigned int r = x.i + 0x7FFFu + ((x.i >> 16) & 1u);   // RNE
  return (unsigned short)(r >> 16);
}

// ---------------- GEMM: C[rows x N] = f(alpha*A@Bt^T + bias) -------------
// A: rows x K bf16 (row stride lda). Bt: N x K bf16 (row stride ldb).
#define FLAG_BIAS    2
#define FLAG_GELU    4
#define FLAG_RES     8     // += bf16 Res[idx]
#define FLAG_VT      16    // store transposed per 4096-row batch (E x S), LDS-staged
#define FLAG_DEN     32    // *= 1/(aux[zb*rowsPerBatch+rr]+1e-6)
#define FLAG_RNORM   64    // no C store; atomicAdd row-norms of (acc+bias) into pmax[row]
#define FLAG_PHIK    128   // phi logits: f32 (acc*alpha + bias - 0.5*scale^2*aux[row]) + block max
#define FLAG_F32OUT  256   // store f32
#define FLAG_SPLITK8 512   // blockIdx.z = batch*8 + k-chunk
#define FLAG_ATOMIC  1024  // f32 atomicAdd into C (indexed by batch zb, not zc)

#define GMT 128
#define GNT 128
#define GBK 32

__global__ __launch_bounds__(256, 2)
void gemm_kernel(const unsigned short* __restrict__ A,
                 const unsigned short* __restrict__ Bt,
                 const unsigned short* __restrict__ bias,
                 const unsigned short* __restrict__ Res,
                 const float* __restrict__ aux,
                 float* __restrict__ pmax,
                 void* __restrict__ C,
                 int K, int N, int lda, int ldb, float alpha, int flags,
                 long sA, long sB, long sC)
{
  // 18 KB shared: As(8K)+Bs(8K) during K-loop; stage aliases them post-loop (VT).
  __shared__ __align__(16) unsigned char sraw[18048];
  unsigned short (*As)[32] = (unsigned short (*)[32])sraw;
  unsigned short (*Bs)[32] = (unsigned short (*)[32])(sraw + 8192);
  unsigned short (*stage)[136] = (unsigned short (*)[136])sraw;   // VT post-loop (17408 B)
  float* wred  = (float*)(sraw + 17472);                          // PHIK (16 B)

  const int tid  = threadIdx.x;
  const int lane = tid & 63;
  const int wid  = tid >> 6;
  long zb = blockIdx.z;            // batch index (for A/B/aux)
  const long zc = blockIdx.z;      // C-store base index (keeps k-chunk for split-K)
  int koff = 0;
  if (flags & FLAG_SPLITK8) { koff = (int)(zb & 7) * K; zb >>= 3; }

  const unsigned short* Ab = A + zb * sA + (long)blockIdx.x * GMT * lda + koff;
  const unsigned short* Bb = Bt + zb * sB + (long)blockIdx.y * GNT * ldb + koff;

  // async staging: lane's LDS dest = tile_base + wid*1024 + lane*16 (contiguous)
  const int srow = wid * 16 + (lane >> 2);   // 0..63
  const int scol = (lane & 3) << 3;          // 0,8,16,24
  const unsigned short* gA = Ab + (long)srow * lda + scol;
  const unsigned short* gB = Bb + (long)srow * ldb + scol;
  l_u32* lA0 = (l_u32*)&As[srow][scol];
  l_u32* lA1 = (l_u32*)&As[srow + 64][scol];
  l_u32* lB0 = (l_u32*)&Bs[srow][scol];
  l_u32* lB1 = (l_u32*)&Bs[srow + 64][scol];

  const f32x4 fzero = {0.f, 0.f, 0.f, 0.f};
  f32x4 acc[4][4];
#pragma unroll
  for (int i = 0; i < 4; ++i)
#pragma unroll
    for (int j = 0; j < 4; ++j) acc[i][j] = fzero;

  const int wm = (wid >> 1) << 6;
  const int wn = (wid & 1) << 6;
  const int fm = lane & 15;
  const int kq = (lane >> 4) << 3;

  const long ka64 = (long)64 * lda, kb64 = (long)64 * ldb;
  for (int k0 = 0; k0 < K; k0 += GBK) {
    __builtin_amdgcn_global_load_lds((g_u32*)(gA + k0),        lA0, 16, 0, 0);
    __builtin_amdgcn_global_load_lds((g_u32*)(gA + ka64 + k0), lA1, 16, 0, 0);
    __builtin_amdgcn_global_load_lds((g_u32*)(gB + k0),        lB0, 16, 0, 0);
    __builtin_amdgcn_global_load_lds((g_u32*)(gB + kb64 + k0), lB1, 16, 0, 0);
    __syncthreads();

    bf16x8 af[4], bfv[4];
#pragma unroll
    for (int i = 0; i < 4; ++i) {
      af[i]  = *(const bf16x8*)&As[wm + i * 16 + fm][kq];
      bfv[i] = *(const bf16x8*)&Bs[wn + i * 16 + fm][kq];
    }
#pragma unroll
    for (int i = 0; i < 4; ++i)
#pragma unroll
      for (int j = 0; j < 4; ++j)
        acc[i][j] = __builtin_amdgcn_mfma_f32_16x16x32_bf16(af[i], bfv[j], acc[i][j], 0, 0, 0);
    __syncthreads();
  }

  // epilogue: C/D layout col=lane&15, row=(lane>>4)*4+reg  [verified m89/m91]
  const int rq = (lane >> 4) << 2;
  const long crow0 = (long)blockIdx.x * GMT + wm;
  const int  ccol0 = blockIdx.y * GNT + wn;

  if (flags & FLAG_RNORM) {
    // row-norm of (acc*alpha + bias): reduce over this wave's 64 cols, atomic-add.
#pragma unroll
    for (int i = 0; i < 4; ++i)
#pragma unroll
      for (int r = 0; r < 4; ++r) {
        float s = 0.f;
#pragma unroll
        for (int j = 0; j < 4; ++j) {
          float v = acc[i][j][r] * alpha + b2f(bias[ccol0 + j * 16 + fm]);
          s += v * v;
        }
        s += __shfl_xor(s, 1, 64);
        s += __shfl_xor(s, 2, 64);
        s += __shfl_xor(s, 4, 64);
        s += __shfl_xor(s, 8, 64);
        if (fm == 0)
          unsafeAtomicAdd(&pmax[crow0 + i * 16 + rq + r], s);
      }
    return;
  }

  if (flags & FLAG_PHIK) {
    // phi logits: l = alpha*acc + bias - 0.5*scale^2 * aux[row], f32 out + block max
    float* Cf = (float*)C;
    float mx = -3.0e38f;
#pragma unroll
    for (int i = 0; i < 4; ++i)
#pragma unroll
      for (int r = 0; r < 4; ++r) {
        const long rr = crow0 + i * 16 + rq + r;
        const float nrm = 0.022097086912079608f * aux[rr];   // 0.5*scale^2
#pragma unroll
        for (int j = 0; j < 4; ++j) {
          const int cc = ccol0 + j * 16 + fm;
          const float bv = (flags & FLAG_BIAS) ? b2f(bias[cc]) : 0.f;
          float l = acc[i][j][r] * alpha + bv - nrm;
          mx = fmaxf(mx, l);
          Cf[rr * (long)N + cc] = l;
        }
      }
#pragma unroll
    for (int off = 32; off >= 1; off >>= 1) mx = fmaxf(mx, __shfl_down(mx, off, 64));
    if (lane == 0) wred[wid] = mx;
    __syncthreads();
    if (tid == 0)
      pmax[blockIdx.x] = fmaxf(fmaxf(wred[0], wred[1]), fmaxf(wred[2], wred[3]));
    return;
  }

  if (flags & FLAG_ATOMIC) {
    // split-K reduction in-cache: f32 atomic add into C[zb] (4 MB total, L2/LLC)
    float* Cf = (float*)C + zb * sC;
#pragma unroll
    for (int j = 0; j < 4; ++j) {
      const int cc = ccol0 + j * 16 + fm;
#pragma unroll
      for (int i = 0; i < 4; ++i)
#pragma unroll
        for (int r = 0; r < 4; ++r) {
          const long rr = crow0 + i * 16 + rq + r;
          unsafeAtomicAdd(&Cf[rr * (long)N + cc], acc[i][j][r] * alpha);
        }
    }
    return;
  }

  if (flags & FLAG_VT) {
    // stage 64 cols x 128 rows in LDS, then coalesced column stores (64B/thread)
    unsigned short* Cb = (unsigned short*)C;
    const int bb = (blockIdx.x * GMT) >> 12;
    const long sbase = (long)((blockIdx.x * GMT) & (cS - 1));
#pragma unroll
    for (int rnd = 0; rnd < 2; ++rnd) {
      if ((wn >> 6) == rnd) {
#pragma unroll
        for (int j = 0; j < 4; ++j) {
          const int cc = ccol0 + j * 16 + fm;
          const float bv = (flags & FLAG_BIAS) ? b2f(bias[cc]) : 0.f;
          const int cl = j * 16 + fm;
#pragma unroll
          for (int i = 0; i < 4; ++i)
#pragma unroll
            for (int r = 0; r < 4; ++r)
              stage[cl][wm + i * 16 + rq + r] = f2b(acc[i][j][r] * alpha + bv);
        }
      }
      __syncthreads();
      {
        const int cl = tid >> 2;
        const int sseg = (tid & 3) << 5;
        const int gcol = blockIdx.y * GNT + rnd * 64 + cl;
        unsigned short* dst = Cb + (long)bb * cE * cS + (long)gcol * cS + sbase + sseg;
#pragma unroll
        for (int t = 0; t < 4; ++t)
          *(bf16x8*)(dst + t * 8) = *(const bf16x8*)&stage[cl][sseg + t * 8];
      }
      __syncthreads();
    }
    return;
  }

  // generic epilogue (C indexed by zc so split-K chunks land in distinct slabs)
  const long rowsPerBatch = (long)gridDim.x * GMT;
#pragma unroll
  for (int j = 0; j < 4; ++j) {
    const int cc = ccol0 + j * 16 + fm;
    const float bv = (flags & FLAG_BIAS) ? b2f(bias[cc]) : 0.f;
#pragma unroll
    for (int i = 0; i < 4; ++i) {
      const long rbase = crow0 + i * 16 + rq;
#pragma unroll
      for (int r = 0; r < 4; ++r) {
        const long rr = rbase + r;
        float v = acc[i][j][r] * alpha + bv;
        if (flags & FLAG_GELU) v = 0.5f * v * (1.f + erff(v * 0.7071067811865475f));
        if (flags & FLAG_DEN)
          v *= 1.f / (fmaxf(aux[zb * rowsPerBatch + rr], 0.f) + 1e-6f);
        const long idx = zc * sC + rr * (long)N + cc;
        if (flags & FLAG_RES) v += b2f(Res[idx]);
        if (flags & FLAG_F32OUT) ((float*)C)[idx] = v;
        else                     ((unsigned short*)C)[idx] = f2b(v);
      }
    }
  }
}

// ---------------- dtype shim ----------------
__global__ void detect_kernel(const unsigned short* __restrict__ lng,
                              int* __restrict__ flag) {
  if (threadIdx.x == 0 && blockIdx.x == 0) flag[0] = (lng[0] == 0) ? 1 : 0;
}

__global__ __launch_bounds__(256) void cvt_kernel(const void* __restrict__ in,
                                                  unsigned short* __restrict__ out,
                                                  long n, const int* __restrict__ flag) {
  long i = (long)blockIdx.x * 256 + threadIdx.x;
  if (i >= n) return;
  if (flag[0]) out[i] = f2b(((const float*)in)[i]);
  else         out[i] = ((const unsigned short*)in)[i];
}

// ---------------- small kernels ----------------
__global__ __launch_bounds__(256) void zero4_kernel(float* __restrict__ p) {
  long i = ((long)blockIdx.x * 256 + threadIdx.x) * 4;
  f32x4 z = {0.f, 0.f, 0.f, 0.f};
  *(f32x4*)&p[i] = z;
}

__global__ __launch_bounds__(256) void addpos_kernel(unsigned short* __restrict__ h,
                                                     const unsigned short* __restrict__ pos) {
  long i = ((long)blockIdx.x * 256 + threadIdx.x) * 8;
  long se = i % ((long)cS * cE);
  bf16x8 v = *(bf16x8*)&h[i];
  bf16x8 p = *(const bf16x8*)&pos[se];
#pragma unroll
  for (int r = 0; r < 8; ++r)
    v[r] = (short)f2b(b2f((unsigned short)v[r]) + b2f((unsigned short)p[r]));
  *(bf16x8*)&h[i] = v;
}

// gmax[0] = max(partials[0..n)); single block
__global__ __launch_bounds__(256) void reducemax_kernel(const float* __restrict__ partials,
                                                        float* __restrict__ gmax, int n) {
  __shared__ float sm[4];
  float mx = -3.0e38f;
  for (int i = threadIdx.x; i < n; i += 256) mx = fmaxf(mx, partials[i]);
#pragma unroll
  for (int off = 32; off >= 1; off >>= 1) mx = fmaxf(mx, __shfl_down(mx, off, 64));
  const int w = threadIdx.x >> 6, lane = threadIdx.x & 63;
  if (lane == 0) sm[w] = mx;
  __syncthreads();
  if (threadIdx.x == 0) gmax[0] = fmaxf(fmaxf(sm[0], sm[1]), fmaxf(sm[2], sm[3]));
}

// elementwise exp (row-major): P = bf16(exp(lf - gm)/sqrt(M))
__global__ __launch_bounds__(256) void expq_kernel(const float* __restrict__ lf,
                                                   const float* __restrict__ gmx,
                                                   unsigned short* __restrict__ P) {
  long i = ((long)blockIdx.x * 256 + threadIdx.x) * 4;
  const float gm = gmx[0];
  f32x4 v = *(const f32x4*)&lf[i];
  bf16x4 o;
#pragma unroll
  for (int r = 0; r < 4; ++r)
    o[r] = (short)f2b(__expf(fminf(v[r] - gm, 0.f)) * 0.08838834764831845f);
  *(bf16x4*)&P[i] = o;
}

// fused exp + transpose: lf (B x S x M f32 logits) -> out (B x M x S bf16 phi)
__global__ __launch_bounds__(256) void expT_kernel(const float* __restrict__ lf,
                                                   const float* __restrict__ gmx,
                                                   unsigned short* __restrict__ out) {
  __shared__ unsigned short t[32][33];
  const int b = blockIdx.z;
  const float gm = gmx[0];
  const int bx = blockIdx.x << 5, by = blockIdx.y << 5;   // bx: M, by: S
  const int tx = threadIdx.x & 31, ty = threadIdx.x >> 5;
  const float* src = lf + (long)b * cS * cM;
  unsigned short* dst = out + (long)b * cM * cS;
#pragma unroll
  for (int i = ty; i < 32; i += 8) {
    float l = src[(long)(by + i) * cM + bx + tx];
    t[i][tx] = f2b(__expf(fminf(l - gm, 0.f)) * 0.08838834764831845f);
  }
  __syncthreads();
#pragma unroll
  for (int i = ty; i < 32; i += 8)
    dst[(long)(bx + i) * cS + by + tx] = t[tx][i];
}

// kv f32 accumulators -> bf16
__global__ __launch_bounds__(256) void kvcvt_kernel(const float* __restrict__ kvacc,
                                                    unsigned short* __restrict__ kvtb) {
  long i = ((long)blockIdx.x * 256 + threadIdx.x) * 4;
  f32x4 v = *(const f32x4*)&kvacc[i];
  bf16x4 o;
#pragma unroll
  for (int r = 0; r < 4; ++r) o[r] = (short)f2b(v[r]);
  *(bf16x4*)&kvtb[i] = o;
}

// out[l][m] = scale * sum_e bq[l][e] * R[l][e][m]   (tiny, pre-loop)
__global__ __launch_bounds__(128) void phibias_kernel(const unsigned short* __restrict__ bq,
                                                      const unsigned short* __restrict__ R,
                                                      unsigned short* __restrict__ out,
                                                      float scale) {
  const int l = blockIdx.x, m = threadIdx.x;
  const unsigned short* b = bq + (long)l * cE;
  const unsigned short* r = R + (long)l * cE * cM;
  float a = 0.f;
  for (int e = 0; e < cE; ++e) a += b2f(b[e]) * b2f(r[(long)e * cM + m]);
  out[(long)l * cM + m] = f2b(a * scale);
}

// z[b][m] = sum_s qtb[b][m][s]   (qtb is B x M x S)
__global__ __launch_bounds__(256) void zsumt_kernel(const unsigned short* __restrict__ qtb,
                                                    float* __restrict__ z) {
  __shared__ float sred[4];
  const int b = blockIdx.x, m = blockIdx.y, tid = threadIdx.x;
  const unsigned short* p = qtb + ((long)b * cM + m) * cS + (long)tid * 16;
  bf16x8 a = *(const bf16x8*)p;
  bf16x8 c = *(const bf16x8*)(p + 8);
  float s = 0.f;
#pragma unroll
  for (int t = 0; t < 8; ++t) s += b2f((unsigned short)a[t]) + b2f((unsigned short)c[t]);
#pragma unroll
  for (int off = 32; off >= 1; off >>= 1) s += __shfl_down(s, off, 64);
  const int w = tid >> 6, lane = tid & 63;
  if (lane == 0) sred[w] = s;
  __syncthreads();
  if (tid == 0) z[b * cM + m] = sred[0] + sred[1] + sred[2] + sred[3];
}

// den[row] = dot(pq[row,:], z[b,:]); 4 rows/block
__global__ __launch_bounds__(256) void den_kernel(const unsigned short* __restrict__ P,
                                                  const float* __restrict__ z,
                                                  float* __restrict__ den) {
  const int w = threadIdx.x >> 6, lane = threadIdx.x & 63;
  const long row = (long)blockIdx.x * 4 + w;
  const float* zb = z + (row >> 12) * cM;
  const unsigned short* p = P + row * cM;
  float d = b2f(p[lane]) * zb[lane] + b2f(p[lane + 64]) * zb[lane + 64];
#pragma unroll
  for (int off = 32; off >= 1; off >>= 1) d += __shfl_down(d, off, 64);
  if (lane == 0) den[row] = d;
}

// layernorm in place (bf16 -> bf16), one row per block
__global__ __launch_bounds__(256) void ln_kernel(unsigned short* __restrict__ a,
                                                 const unsigned short* __restrict__ g,
                                                 const unsigned short* __restrict__ bb) {
  __shared__ float sred[8];
  const long row = blockIdx.x;
  unsigned short* ar = a + row * cE;
  const int tid = threadIdx.x;
  float v0 = b2f(ar[tid]), v1 = b2f(ar[tid + 256]);
  float s = v0 + v1, sq = v0 * v0 + v1 * v1;
#pragma unroll
  for (int off = 32; off >= 1; off >>= 1) {
    s  += __shfl_down(s, off, 64);
    sq += __shfl_down(sq, off, 64);
  }
  const int w = tid >> 6, lane = tid & 63;
  if (lane == 0) { sred[w] = s; sred[4 + w] = sq; }
  __syncthreads();
  const float st  = sred[0] + sred[1] + sred[2] + sred[3];
  const float sqt = sred[4] + sred[5] + sred[6] + sred[7];
  const float mean = st * (1.f / 512.f);
  const float var  = fmaxf(sqt * (1.f / 512.f) - mean * mean, 0.f);
  const float rstd = rsqrtf(var + 1e-5f);
  ar[tid]       = f2b((v0 - mean) * rstd * b2f(g[tid])       + b2f(bb[tid]));
  ar[tid + 256] = f2b((v1 - mean) * rstd * b2f(g[tid + 256]) + b2f(bb[tid + 256]));
}

// batched bf16 transpose: in (R x C) -> out (C x R); grid (C/32, R/32, batch)
__global__ __launch_bounds__(256) void transpose_kernel(const unsigned short* __restrict__ in,
                                                        unsigned short* __restrict__ out,
                                                        int R, int C, long sIn, long sOut) {
  __shared__ unsigned short t[32][33];
  in  += (long)blockIdx.z * sIn;
  out += (long)blockIdx.z * sOut;
  const int bx = blockIdx.x << 5, by = blockIdx.y << 5;
  const int tx = threadIdx.x & 31, ty = threadIdx.x >> 5;
#pragma unroll
  for (int i = ty; i < 32; i += 8) t[i][tx] = in[(long)(by + i) * C + bx + tx];
  __syncthreads();
#pragma unroll
  for (int i = ty; i < 32; i += 8) out[(long)(bx + i) * R + by + tx] = t[tx][i];
}

// final head
__global__ __launch_bounds__(256) void head_kernel(const unsigned short* __restrict__ h,
                                                   const unsigned short* __restrict__ Wr1,
                                                   const unsigned short* __restrict__ br1,
                                                   const unsigned short* __restrict__ Wr2,
                                                   const unsigned short* __restrict__ br2,
                                                   void* __restrict__ out,
                                                   const int* __restrict__ flag) {
  __shared__ float pooled[cE];
  __shared__ float red[4];
  const int b = blockIdx.x, tid = threadIdx.x;
  pooled[tid]       = b2f(h[(long)b * cS * cE + tid]);
  pooled[tid + 256] = b2f(h[(long)b * cS * cE + tid + 256]);
  __syncthreads();
  float acc = b2f(br1[tid]);
  for (int e = 0; e < cE; ++e) acc += pooled[e] * b2f(Wr1[e * cHE + tid]);
  acc = fmaxf(acc, 0.f) * b2f(Wr2[tid]);
#pragma unroll
  for (int off = 32; off >= 1; off >>= 1) acc += __shfl_down(acc, off, 64);
  const int w = tid >> 6, lane = tid & 63;
  if (lane == 0) red[w] = acc;
  __syncthreads();
  if (tid == 0) {
    float r = red[0] + red[1] + red[2] + red[3] + b2f(br2[0]);
    if (flag[0]) ((float*)out)[b] = r;
    else         ((unsigned short*)out)[b] = f2b(r);
  }
}

// ---------------- host ----------------
extern "C" void kernel_launch(void* const* d_in, const int* in_sizes, int n_in,
                              void* d_out, int out_size, void* d_ws, size_t ws_size,
                              hipStream_t stream) {
  (void)in_sizes; (void)n_in; (void)out_size;

  char* ws = (char*)d_ws;
  size_t off = 0;
  auto alloc = [&](size_t bytes) -> void* {
    void* p = ws + off;
    off += (bytes + 255) & ~(size_t)255;
    return p;
  };
  // ---- memory plan (~242 MiB total) ----
  unsigned short* h   = (unsigned short*)alloc(cNBS * cE * 2);   // 67 MB residual
  unsigned short* X   = (unsigned short*)alloc(cNBS * cE * 2);   // 67 MB multi-use
  unsigned short* Y   = (unsigned short*)alloc(cNBS * cE * 2);   // 67 MB multi-use
  unsigned short* Pb  = (unsigned short*)alloc(cNBS * cM * 2);   // 16.8 MB phi(q)
  unsigned short* kvtb= (unsigned short*)alloc((long)cB * cE * cM * 2); // 2.1 MB
  float* kvacc        = (float*)alloc((long)cB * cE * cM * 4);   // 4 MB f32 kv acc
  float* vec64k       = (float*)alloc(cNBS * 4);                 // den
  float* rnorm        = (float*)alloc(cNBS * 4);                 // 256 KB row-norms
  float* z            = (float*)alloc(cB * cM * 4);
  float* partials     = (float*)alloc(512 * 4);
  float* gmaxf        = (float*)alloc(256);
  int*   dflag        = (int*)alloc(256);
  unsigned short* WiT = (unsigned short*)alloc((long)cE * cDIN * 2);
  unsigned short* WqT = (unsigned short*)alloc((long)cL * cE * cE * 2);
  unsigned short* WkT = (unsigned short*)alloc((long)cL * cE * cE * 2);
  unsigned short* WvT = (unsigned short*)alloc((long)cL * cE * cE * 2);
  unsigned short* WoT = (unsigned short*)alloc((long)cL * cE * cE * 2);
  unsigned short* RT  = (unsigned short*)alloc((long)cL * cM * cE * 2);
  unsigned short* WqRT= (unsigned short*)alloc((long)cL * cM * cE * 2); // (Wq@R)^T
  unsigned short* WkRT= (unsigned short*)alloc((long)cL * cM * cE * 2); // (Wk@R)^T
  unsigned short* W1T = (unsigned short*)alloc((long)cL * cFF * cE * 2);
  unsigned short* W2T = (unsigned short*)alloc((long)cL * cE * cFF * 2);
  unsigned short* sb  = (unsigned short*)alloc(160000 * 2);

  // weight staging inside X (dead until first in-loop X use)
  unsigned short* WqB = X;
  unsigned short* WkB = WqB + (long)cL * cE * cE;
  unsigned short* WvB = WkB + (long)cL * cE * cE;
  unsigned short* WoB = WvB + (long)cL * cE * cE;
  unsigned short* RmB = WoB + (long)cL * cE * cE;
  unsigned short* W1B = RmB + (long)cL * cE * cM;
  unsigned short* W2B = W1B + (long)cL * cE * cFF;
  unsigned short* WiB = W2B + (long)cL * cE * cFF;
  // x, pos staging inside Y
  unsigned short* xb   = Y;
  unsigned short* posb = Y + cNBS * cDIN;
  // small tensors inside sb
  unsigned short* biC  = sb;
  unsigned short* bqC  = biC  + 512;
  unsigned short* bkC  = bqC  + 2048;
  unsigned short* bvC  = bkC  + 2048;
  unsigned short* boC  = bvC  + 2048;
  unsigned short* b1C  = boC  + 2048;
  unsigned short* b2C  = b1C  + 8192;
  unsigned short* lngC = b2C  + 2048;
  unsigned short* lnbC = lngC + 2048;
  unsigned short* Wr1C = lnbC + 2048;
  unsigned short* br1C = Wr1C + 131072;
  unsigned short* Wr2C = br1C + 256;
  unsigned short* br2C = Wr2C + 256;
  unsigned short* sbqRC = br2C + 16;            // scale*(bq@R), L x M
  unsigned short* sbkRC = sbqRC + cL * cM;      // scale*(bk@R), L x M

  unsigned short* qtb  = X;                       // pk^T (B x M x S), 16.8 MB
  float* logf          = (float*)Y;               // phi logits f32, 33.5 MB (q then k)
  unsigned short* vtb  = Y;                       // v^T (B x E x S)
  unsigned short* attb = X;                       // att output
  unsigned short* ab   = Y;                       // a / y (LN in place)
  unsigned short* u1b  = X;                       // FFN hidden chunk (16384 x 2048)

  if (off > ws_size) return;

  // ---- dtype detect + convert all inputs to bf16 ----
  detect_kernel<<<1, 64, 0, stream>>>((const unsigned short*)d_in[13], dflag);
  auto cvt = [&](const void* src, unsigned short* dst, long n) {
    cvt_kernel<<<(unsigned)((n + 255) / 256), 256, 0, stream>>>(src, dst, n, dflag);
  };
  cvt(d_in[0],  xb,   cNBS * cDIN);
  cvt(d_in[1],  WiB,  (long)cDIN * cE);
  cvt(d_in[2],  biC,  cE);
  cvt(d_in[3],  posb, (long)cS * cE);
  cvt(d_in[4],  WqB,  (long)cL * cE * cE);
  cvt(d_in[5],  bqC,  (long)cL * cE);
  cvt(d_in[6],  WkB,  (long)cL * cE * cE);
  cvt(d_in[7],  bkC,  (long)cL * cE);
  cvt(d_in[8],  WvB,  (long)cL * cE * cE);
  cvt(d_in[9],  bvC,  (long)cL * cE);
  cvt(d_in[10], WoB,  (long)cL * cE * cE);
  cvt(d_in[11], boC,  (long)cL * cE);
  cvt(d_in[12], RmB,  (long)cL * cE * cM);
  cvt(d_in[13], lngC, (long)cL * cE);
  cvt(d_in[14], lnbC, (long)cL * cE);
  cvt(d_in[15], W1B,  (long)cL * cE * cFF);
  cvt(d_in[16], b1C,  (long)cL * cFF);
  cvt(d_in[17], W2B,  (long)cL * cFF * cE);
  cvt(d_in[18], b2C,  (long)cL * cE);
  cvt(d_in[19], Wr1C, (long)cE * cHE);
  cvt(d_in[20], br1C, cHE);
  cvt(d_in[21], Wr2C, cHE);
  cvt(d_in[22], br2C, 1);

  typedef const unsigned short* cus;
  auto gemm = [&](const void* A, const void* Bt, const void* bias_,
                  const float* aux_, float* pmax_, void* C,
                  long rows, int K, int N, int lda, int ldb, float alpha, int flags,
                  long sA, long sB, long sC, int batches, const void* Res_ = nullptr) {
    dim3 g((unsigned)(rows / 128), (unsigned)(N / 128), (unsigned)batches);
    gemm_kernel<<<g, dim3(256), 0, stream>>>(
        (const unsigned short*)A, (const unsigned short*)Bt,
        (const unsigned short*)bias_, (const unsigned short*)Res_,
        aux_, pmax_, C, K, N, lda, ldb, alpha, flags, sA, sB, sC);
  };

  // ---- weight pre-transposes ----
  transpose_kernel<<<dim3(16, 2, 1), 256, 0, stream>>>(WiB, WiT, cDIN, cE, 0, 0);
  transpose_kernel<<<dim3(16, 16, cL), 256, 0, stream>>>(WqB, WqT, cE, cE, (long)cE * cE, (long)cE * cE);
  transpose_kernel<<<dim3(16, 16, cL), 256, 0, stream>>>(WkB, WkT, cE, cE, (long)cE * cE, (long)cE * cE);
  transpose_kernel<<<dim3(16, 16, cL), 256, 0, stream>>>(WvB, WvT, cE, cE, (long)cE * cE, (long)cE * cE);
  transpose_kernel<<<dim3(16, 16, cL), 256, 0, stream>>>(WoB, WoT, cE, cE, (long)cE * cE, (long)cE * cE);
  transpose_kernel<<<dim3(4, 16, cL), 256, 0, stream>>>(RmB, RT, cE, cM, (long)cE * cM, (long)cE * cM);
  transpose_kernel<<<dim3(64, 16, cL), 256, 0, stream>>>(W1B, W1T, cE, cFF, (long)cE * cFF, (long)cE * cFF);
  transpose_kernel<<<dim3(16, 64, cL), 256, 0, stream>>>(W2B, W2T, cFF, cE, (long)cFF * cE, (long)cFF * cE);

  const float scale = 0.21022410381342863f;    // 512^-0.25

  // ---- fold R into Wq/Wk (while WqB/WkB/RmB are still staged in X) ----
  // WqRT[l] = (Wq[l] @ R[l])^T  (M x E):  C = RT[l] @ WqB[l]^T
  gemm(RT, WqB, nullptr, nullptr, nullptr, WqRT, cM, cE, cE, cE, cE, 1.f, 0,
       (long)cM * cE, (long)cE * cE, (long)cM * cE, cL);
  gemm(RT, WkB, nullptr, nullptr, nullptr, WkRT, cM, cE, cE, cE, cE, 1.f, 0,
       (long)cM * cE, (long)cE * cE, (long)cM * cE, cL);
  phibias_kernel<<<cL, 128, 0, stream>>>(bqC, RmB, sbqRC, scale);
  phibias_kernel<<<cL, 128, 0, stream>>>(bkC, RmB, sbkRC, scale);

  // ---- input projection + positional embedding ----
  gemm(xb, WiT, biC, nullptr, nullptr, h, cNBS, cDIN, cE, cDIN, cDIN, 1.f,
       FLAG_BIAS, 0, 0, 0, 1);
  addpos_kernel<<<16384, 256, 0, stream>>>(h, posb);

  for (int i = 0; i < cL; ++i) {
    cus WqT_i = WqT + (long)i * cE * cE;  cus bq_i = bqC + (long)i * cE;
    cus WkT_i = WkT + (long)i * cE * cE;  cus bk_i = bkC + (long)i * cE;
    cus WvT_i = WvT + (long)i * cE * cE;  cus bv_i = bvC + (long)i * cE;
    cus WoT_i = WoT + (long)i * cE * cE;  cus bo_i = boC + (long)i * cE;
    cus WqRT_i = WqRT + (long)i * cM * cE;  cus sbq_i = sbqRC + (long)i * cM;
    cus WkRT_i = WkRT + (long)i * cM * cE;  cus sbk_i = sbkRC + (long)i * cM;
    cus g_i   = lngC + (long)i * cE;      cus b_i  = lnbC + (long)i * cE;
    cus W1T_i = W1T + (long)i * cFF * cE; cus b1_i = b1C + (long)i * cFF;
    cus W2T_i = W2T + (long)i * cE * cFF; cus b2_i = b2C + (long)i * cE;

    // --- phi(q): row-norms of q (no q materialization), logits from h@(WqR) ---
    zero4_kernel<<<64, 256, 0, stream>>>(rnorm);
    gemm(h, WqT_i, bq_i, nullptr, rnorm, nullptr, cNBS, cE, cE, cE, cE, 1.f,
         FLAG_RNORM, 0, 0, 0, 1);
    gemm(h, WqRT_i, sbq_i, rnorm, partials, logf, cNBS, cE, cM, cE, cE, scale,
         FLAG_PHIK | FLAG_BIAS, 0, 0, 0, 1);
    reducemax_kernel<<<1, 256, 0, stream>>>(partials, gmaxf, 512);
    expq_kernel<<<8192, 256, 0, stream>>>(logf, gmaxf, Pb);

    // --- phi(k): same, fused exp+transpose -> qtb ---
    zero4_kernel<<<64, 256, 0, stream>>>(rnorm);
    gemm(h, WkT_i, bk_i, nullptr, rnorm, nullptr, cNBS, cE, cE, cE, cE, 1.f,
         FLAG_RNORM, 0, 0, 0, 1);
    gemm(h, WkRT_i, sbk_i, rnorm, partials, logf, cNBS, cE, cM, cE, cE, scale,
         FLAG_PHIK | FLAG_BIAS, 0, 0, 0, 1);
    reducemax_kernel<<<1, 256, 0, stream>>>(partials, gmaxf, 512);
    expT_kernel<<<dim3(4, 128, cB), 256, 0, stream>>>(logf, gmaxf, qtb);

    // --- v projection, stored transposed via LDS-staged epilogue ---
    gemm(h, WvT_i, bv_i, nullptr, nullptr, vtb, cNBS, cE, cE, cE, cE, 1.f,
         FLAG_BIAS | FLAG_VT, 0, 0, 0, 1);

    // --- z, den ---
    zsumt_kernel<<<dim3(cB, cM), 256, 0, stream>>>(qtb, z);
    den_kernel<<<16384, 256, 0, stream>>>(Pb, z, vec64k);

    // --- kv^T[b] = v^T[b] @ pk[b], split-K x8 with in-cache f32 atomics ---
    zero4_kernel<<<1024, 256, 0, stream>>>(kvacc);
    gemm(vtb, qtb, nullptr, nullptr, nullptr, kvacc, cE, cS / 8, cM, cS, cS, 1.f,
         FLAG_SPLITK8 | FLAG_ATOMIC, (long)cE * cS, (long)cM * cS, (long)cE * cM, cB * 8);
    kvcvt_kernel<<<1024, 256, 0, stream>>>(kvacc, kvtb);

    // --- att[b] = (pq[b] @ kv[b]) / (den+1e-6) -> X ---
    gemm(Pb, kvtb, nullptr, vec64k, nullptr, attb, cS, cM, cE, cM, cM, 1.f,
         FLAG_DEN, (long)cS * cM, (long)cE * cM, (long)cS * cE, cB);

    // --- a = att @ Wo + bo -> Y ; LN in place ---
    gemm(attb, WoT_i, bo_i, nullptr, nullptr, ab, cNBS, cE, cE, cE, cE, 1.f,
         FLAG_BIAS, 0, 0, 0, 1);
    ln_kernel<<<cNBS, 256, 0, stream>>>(ab, g_i, b_i);

    // --- FFN in 4 row-chunks of 16384; h += ffn(y) ---
    for (int c = 0; c < 4; ++c) {
      const unsigned short* yc = ab + (long)c * 16384 * cE;
      unsigned short* hc = h + (long)c * 16384 * cE;
      gemm(yc, W1T_i, b1_i, nullptr, nullptr, u1b, 16384, cE, cFF, cE, cE, 1.f,
           FLAG_BIAS | FLAG_GELU, 0, 0, 0, 1);
      gemm(u1b, W2T_i, b2_i, nullptr, nullptr, hc, 16384, cFF, cE, cFF, cFF, 1.f,
           FLAG_BIAS | FLAG_RES, 0, 0, 0, 1, hc);
    }
  }

  head_kernel<<<cB, 256, 0, stream>>>(h, Wr1C, br1C, Wr2C, br2C, d_out, dflag);
}

// Round 7
// 4274.657 us; speedup vs baseline: 1.0820x; 1.0820x over previous
//
#include <hip/hip_runtime.h>
#include <math.h>

// ---------------- problem constants ----------------
static constexpr int  cB   = 16;
static constexpr int  cS   = 4096;
static constexpr int  cDIN = 64;
static constexpr int  cE   = 512;
static constexpr int  cM   = 128;
static constexpr int  cL   = 4;
static constexpr int  cFF  = 2048;   // 4*E
static constexpr int  cHE  = 256;    // E/2
static constexpr long cNBS = (long)cB * cS;   // 65536 rows
static constexpr int  cNF  = 1536;   // fused N = 512(v) + 512(k-norm) + 512(q-norm)

typedef __attribute__((ext_vector_type(8))) short  bf16x8;
typedef __attribute__((ext_vector_type(4))) short  bf16x4;
typedef __attribute__((ext_vector_type(4))) float  f32x4;

typedef const __attribute__((address_space(1))) unsigned int g_u32;
typedef __attribute__((address_space(3))) unsigned int l_u32;

__device__ __forceinline__ float b2f(unsigned short u) {
  union { unsigned int i; float f; } x; x.i = ((unsigned int)u) << 16; return x.f;
}
__device__ __forceinline__ unsigned short f2b(float f) {
  union { float f; unsigned int i; } x; x.f = f;
  unsigned int r = x.i + 0x7FFFu + ((x.i >> 16) & 1u);   // RNE
  return (unsigned short)(r >> 16);
}

// phi math. NOTE (round-6 post-mortem): the global-max shift and q-row-norm
// do NOT cancel out of num/(den+1e-6) -- the 1e-6 breaks scale invariance.
// Faithful computation (norm + max) restored, identical to the measured-good
// round-1 kernel (absmax 0.0078).
#define PSCALE 0.21022410381342863f     // 512^-0.25
#define PNRM   0.022097086912079608f    // 0.5 * PSCALE^2
#define PINV   0.08838834764831845f     // 1/sqrt(M)

// ---------------- GEMM: C[rows x N] = f(alpha*A@Bt^T + bias) -------------
// A: rows x K bf16 (row stride lda). Bt: N x K bf16 (row stride ldb).
#define FLAG_BIAS    2
#define FLAG_GELU    4
#define FLAG_RES     8     // += bf16 Res[idx]
#define FLAG_VT      16    // store transposed per 4096-row batch, batch stride sC
#define FLAG_DEN     32    // *= 1/(aux[zb*rowsPerBatch+rr]+1e-6)
#define FLAG_RNORM   64    // no C store; atomicAdd row-norms of (acc+bias) into pmax[rnoff+row]
#define FLAG_PHIK    128   // dual q/k logits: by=0 q (aux+cNBS), by=1 k (aux+0);
                           // l = PSCALE*acc + bias - PNRM*aux; f32 out + block max
#define FLAG_F32OUT  256   // store f32
#define FLAG_SPLITK8 512   // blockIdx.z = batch*8 + k-chunk
#define FLAG_ATOMIC  1024  // f32 atomicAdd into C (indexed by batch zb)
#define FLAG_FUSED   2048  // grid (12,512): by<4 VT(v), by<8 RNORM(k), by<12 RNORM(q)

#define GMT 128
#define GNT 128
#define GBK 32

__global__ __launch_bounds__(256, 2)
void gemm_kernel(const unsigned short* __restrict__ A,
                 const unsigned short* __restrict__ Bt,
                 const unsigned short* __restrict__ bias,
                 const unsigned short* __restrict__ Res,
                 const float* __restrict__ aux,
                 float* __restrict__ pmax,
                 void* __restrict__ C,
                 int K, int N, int lda, int ldb, float alpha, int flags,
                 long sA, long sB, long sC)
{
  // 18 KB shared: As(8K)+Bs(8K) during K-loop; stage aliases them post-loop (VT).
  __shared__ __align__(16) unsigned char sraw[18048];
  unsigned short (*As)[32] = (unsigned short (*)[32])sraw;
  unsigned short (*Bs)[32] = (unsigned short (*)[32])(sraw + 8192);
  unsigned short (*stage)[136] = (unsigned short (*)[136])sraw;   // VT post-loop (17408 B)
  float* wred  = (float*)(sraw + 17472);                          // PHIK block max (16 B)

  const int tid  = threadIdx.x;
  const int lane = tid & 63;
  const int wid  = tid >> 6;

  // FUSED launches with grid (12, 512) so the 12 blocks sharing one A-tile are
  // dispatch-adjacent (L2 A-reuse); swap the roles back here.
  int bx = blockIdx.x, by = blockIdx.y;
  if (flags & FLAG_FUSED) { bx = blockIdx.y; by = blockIdx.x; }

  long zb = blockIdx.z;            // batch index (for A/B/aux)
  const long zc = blockIdx.z;      // C-store base index (keeps k-chunk for split-K)
  int koff = 0;
  if (flags & FLAG_SPLITK8) { koff = (int)(zb & 7) * K; zb >>= 3; }

  const unsigned short* Ab = A + zb * sA + (long)bx * GMT * lda + koff;
  const unsigned short* Bb = Bt + zb * sB + (long)by * GNT * ldb + koff;

  // async staging: lane's LDS dest = tile_base + wid*1024 + lane*16 (contiguous)
  const int srow = wid * 16 + (lane >> 2);   // 0..63
  const int scol = (lane & 3) << 3;          // 0,8,16,24
  const unsigned short* gA = Ab + (long)srow * lda + scol;
  const unsigned short* gB = Bb + (long)srow * ldb + scol;
  l_u32* lA0 = (l_u32*)&As[srow][scol];
  l_u32* lA1 = (l_u32*)&As[srow + 64][scol];
  l_u32* lB0 = (l_u32*)&Bs[srow][scol];
  l_u32* lB1 = (l_u32*)&Bs[srow + 64][scol];

  const f32x4 fzero = {0.f, 0.f, 0.f, 0.f};
  f32x4 acc[4][4];
#pragma unroll
  for (int i = 0; i < 4; ++i)
#pragma unroll
    for (int j = 0; j < 4; ++j) acc[i][j] = fzero;

  const int wm = (wid >> 1) << 6;
  const int wn = (wid & 1) << 6;
  const int fm = lane & 15;
  const int kq = (lane >> 4) << 3;

  const long ka64 = (long)64 * lda, kb64 = (long)64 * ldb;
  for (int k0 = 0; k0 < K; k0 += GBK) {
    __builtin_amdgcn_global_load_lds((g_u32*)(gA + k0),        lA0, 16, 0, 0);
    __builtin_amdgcn_global_load_lds((g_u32*)(gA + ka64 + k0), lA1, 16, 0, 0);
    __builtin_amdgcn_global_load_lds((g_u32*)(gB + k0),        lB0, 16, 0, 0);
    __builtin_amdgcn_global_load_lds((g_u32*)(gB + kb64 + k0), lB1, 16, 0, 0);
    __syncthreads();

    bf16x8 af[4], bfv[4];
#pragma unroll
    for (int i = 0; i < 4; ++i) {
      af[i]  = *(const bf16x8*)&As[wm + i * 16 + fm][kq];
      bfv[i] = *(const bf16x8*)&Bs[wn + i * 16 + fm][kq];
    }
#pragma unroll
    for (int i = 0; i < 4; ++i)
#pragma unroll
      for (int j = 0; j < 4; ++j)
        acc[i][j] = __builtin_amdgcn_mfma_f32_16x16x32_bf16(af[i], bfv[j], acc[i][j], 0, 0, 0);
    __syncthreads();
  }

  // epilogue: C/D layout col=lane&15, row=(lane>>4)*4+reg  [verified m89/m91]
  const int rq = (lane >> 4) << 2;
  const long crow0 = (long)bx * GMT + wm;
  const int  ccol0 = by * GNT + wn;

  long rnoff = 0;
  if (flags & FLAG_FUSED) {
    if (by < 4) flags = FLAG_BIAS | FLAG_VT;
    else { flags = FLAG_BIAS | FLAG_RNORM; if (by >= 8) rnoff = cNBS; }
  }

  if (flags & FLAG_RNORM) {
    // row-norm of (acc*alpha + bias): reduce over this wave's 64 cols, atomic-add.
#pragma unroll
    for (int i = 0; i < 4; ++i)
#pragma unroll
      for (int r = 0; r < 4; ++r) {
        float s = 0.f;
#pragma unroll
        for (int j = 0; j < 4; ++j) {
          float v = acc[i][j][r] * alpha + b2f(bias[ccol0 + j * 16 + fm]);
          s += v * v;
        }
        s += __shfl_xor(s, 1, 64);
        s += __shfl_xor(s, 2, 64);
        s += __shfl_xor(s, 4, 64);
        s += __shfl_xor(s, 8, 64);
        if (fm == 0)
          unsafeAtomicAdd(&pmax[rnoff + crow0 + i * 16 + rq + r], s);
      }
    return;
  }

  if (flags & FLAG_PHIK) {
    // dual q/k phi logits (grid (512,2)): by=0 q (aux offset cNBS), by=1 k.
    // l = PSCALE*acc + bias - PNRM*aux[row]; f32 out + block max to pmax[by*512+bx].
    const long aoff = (by == 0) ? cNBS : 0;
    float* Cf = (float*)C + (long)by * (cNBS * (long)cM);
    float mx = -3.0e38f;
#pragma unroll
    for (int i = 0; i < 4; ++i)
#pragma unroll
      for (int r = 0; r < 4; ++r) {
        const long rr = crow0 + i * 16 + rq + r;
        const float nrm = PNRM * aux[aoff + rr];
#pragma unroll
        for (int j = 0; j < 4; ++j) {
          const int cc = ccol0 + j * 16 + fm;
          const float bv = b2f(bias[cc]);
          float l = acc[i][j][r] * PSCALE + bv - nrm;
          mx = fmaxf(mx, l);
          Cf[rr * (long)cM + (cc & (cM - 1))] = l;
        }
      }
#pragma unroll
    for (int off = 32; off >= 1; off >>= 1) mx = fmaxf(mx, __shfl_down(mx, off, 64));
    if (lane == 0) wred[wid] = mx;
    __syncthreads();
    if (tid == 0)
      pmax[by * 512 + bx] = fmaxf(fmaxf(wred[0], wred[1]), fmaxf(wred[2], wred[3]));
    return;
  }

  if (flags & FLAG_ATOMIC) {
    // split-K reduction in-cache: f32 atomic add into C[zb]
    float* Cf = (float*)C + zb * sC;
#pragma unroll
    for (int j = 0; j < 4; ++j) {
      const int cc = ccol0 + j * 16 + fm;
#pragma unroll
      for (int i = 0; i < 4; ++i)
#pragma unroll
        for (int r = 0; r < 4; ++r) {
          const long rr = crow0 + i * 16 + rq + r;
          unsafeAtomicAdd(&Cf[rr * (long)N + cc], acc[i][j][r] * alpha);
        }
    }
    return;
  }

  if (flags & FLAG_VT) {
    // stage 64 cols x 128 rows in LDS, then coalesced column stores (64B/thread)
    unsigned short* Cb = (unsigned short*)C;
    const int bb = (bx * GMT) >> 12;
    const long sbase = (long)((bx * GMT) & (cS - 1));
#pragma unroll
    for (int rnd = 0; rnd < 2; ++rnd) {
      if ((wn >> 6) == rnd) {
#pragma unroll
        for (int j = 0; j < 4; ++j) {
          const int cc = ccol0 + j * 16 + fm;
          const float bv = (flags & FLAG_BIAS) ? b2f(bias[cc]) : 0.f;
          const int cl = j * 16 + fm;
#pragma unroll
          for (int i = 0; i < 4; ++i)
#pragma unroll
            for (int r = 0; r < 4; ++r)
              stage[cl][wm + i * 16 + rq + r] = f2b(acc[i][j][r] * alpha + bv);
        }
      }
      __syncthreads();
      {
        const int cl = tid >> 2;
        const int sseg = (tid & 3) << 5;
        const int gcol = by * GNT + rnd * 64 + cl;
        unsigned short* dst = Cb + (long)bb * sC + (long)gcol * cS + sbase + sseg;
#pragma unroll
        for (int t = 0; t < 4; ++t)
          *(bf16x8*)(dst + t * 8) = *(const bf16x8*)&stage[cl][sseg + t * 8];
      }
      __syncthreads();
    }
    return;
  }

  // generic epilogue (C indexed by zc so split-K chunks land in distinct slabs)
  const long rowsPerBatch = (long)gridDim.x * GMT;
#pragma unroll
  for (int j = 0; j < 4; ++j) {
    const int cc = ccol0 + j * 16 + fm;
    const float bv = (flags & FLAG_BIAS) ? b2f(bias[cc]) : 0.f;
#pragma unroll
    for (int i = 0; i < 4; ++i) {
      const long rbase = crow0 + i * 16 + rq;
#pragma unroll
      for (int r = 0; r < 4; ++r) {
        const long rr = rbase + r;
        float v = acc[i][j][r] * alpha + bv;
        if (flags & FLAG_GELU) v = 0.5f * v * (1.f + erff(v * 0.7071067811865475f));
        if (flags & FLAG_DEN)
          v *= 1.f / (fmaxf(aux[zb * rowsPerBatch + rr], 0.f) + 1e-6f);
        const long idx = zc * sC + rr * (long)N + cc;
        if (flags & FLAG_RES) v += b2f(Res[idx]);
        if (flags & FLAG_F32OUT) ((float*)C)[idx] = v;
        else                     ((unsigned short*)C)[idx] = f2b(v);
      }
    }
  }
}

// ---------------- dtype shim ----------------
__global__ void detect_kernel(const unsigned short* __restrict__ lng,
                              int* __restrict__ flag) {
  if (threadIdx.x == 0 && blockIdx.x == 0) flag[0] = (lng[0] == 0) ? 1 : 0;
}

__global__ __launch_bounds__(256) void cvt_kernel(const void* __restrict__ in,
                                                  unsigned short* __restrict__ out,
                                                  long n, const int* __restrict__ flag) {
  long i = (long)blockIdx.x * 256 + threadIdx.x;
  if (i >= n) return;
  if (flag[0]) out[i] = f2b(((const float*)in)[i]);
  else         out[i] = ((const unsigned short*)in)[i];
}

// ---------------- small kernels ----------------
__global__ __launch_bounds__(256) void zero4_kernel(float* __restrict__ p) {
  long i = ((long)blockIdx.x * 256 + threadIdx.x) * 4;
  f32x4 z = {0.f, 0.f, 0.f, 0.f};
  *(f32x4*)&p[i] = z;
}

__global__ __launch_bounds__(256) void addpos_kernel(unsigned short* __restrict__ h,
                                                     const unsigned short* __restrict__ pos) {
  long i = ((long)blockIdx.x * 256 + threadIdx.x) * 8;
  long se = i % ((long)cS * cE);
  bf16x8 v = *(bf16x8*)&h[i];
  bf16x8 p = *(const bf16x8*)&pos[se];
#pragma unroll
  for (int r = 0; r < 8; ++r)
    v[r] = (short)f2b(b2f((unsigned short)v[r]) + b2f((unsigned short)p[r]));
  *(bf16x8*)&h[i] = v;
}

// gmax[0]=max(partials[0..512)) (q), gmax[1]=max(partials[512..1024)) (k)
__global__ __launch_bounds__(256) void reducemax2_kernel(const float* __restrict__ partials,
                                                         float* __restrict__ gmax) {
  __shared__ float sm[8];
  const int tid = threadIdx.x;
  for (int half = 0; half < 2; ++half) {
    float mx = -3.0e38f;
    for (int i = tid; i < 512; i += 256) mx = fmaxf(mx, partials[half * 512 + i]);
#pragma unroll
    for (int off = 32; off >= 1; off >>= 1) mx = fmaxf(mx, __shfl_down(mx, off, 64));
    if ((tid & 63) == 0) sm[(half << 2) + (tid >> 6)] = mx;
  }
  __syncthreads();
  if (tid == 0) gmax[0] = fmaxf(fmaxf(sm[0], sm[1]), fmaxf(sm[2], sm[3]));
  if (tid == 1) gmax[1] = fmaxf(fmaxf(sm[4], sm[5]), fmaxf(sm[6], sm[7]));
}

// elementwise exp (row-major): P = bf16(exp(lf - gm)/sqrt(M))
__global__ __launch_bounds__(256) void expq_kernel(const float* __restrict__ lf,
                                                   const float* __restrict__ gmx,
                                                   unsigned short* __restrict__ P) {
  long i = ((long)blockIdx.x * 256 + threadIdx.x) * 4;
  const float gm = gmx[0];
  f32x4 v = *(const f32x4*)&lf[i];
  bf16x4 o;
#pragma unroll
  for (int r = 0; r < 4; ++r)
    o[r] = (short)f2b(__expf(fminf(v[r] - gm, 0.f)) * PINV);
  *(bf16x4*)&P[i] = o;
}

// fused exp + transpose: lf (B x S x M f32 logits) -> out (B x M x S bf16 phi)
__global__ __launch_bounds__(256) void expT_kernel(const float* __restrict__ lf,
                                                   const float* __restrict__ gmx,
                                                   unsigned short* __restrict__ out) {
  __shared__ unsigned short t[32][33];
  const int b = blockIdx.z;
  const float gm = gmx[0];
  const int bx = blockIdx.x << 5, by = blockIdx.y << 5;   // bx: M, by: S
  const int tx = threadIdx.x & 31, ty = threadIdx.x >> 5;
  const float* src = lf + (long)b * cS * cM;
  unsigned short* dst = out + (long)b * cM * cS;
#pragma unroll
  for (int i = ty; i < 32; i += 8) {
    float l = src[(long)(by + i) * cM + bx + tx];
    t[i][tx] = f2b(__expf(fminf(l - gm, 0.f)) * PINV);
  }
  __syncthreads();
#pragma unroll
  for (int i = ty; i < 32; i += 8)
    dst[(long)(bx + i) * cS + by + tx] = t[tx][i];
}

// kv f32 accumulators -> bf16
__global__ __launch_bounds__(256) void kvcvt_kernel(const float* __restrict__ kvacc,
                                                    unsigned short* __restrict__ kvtb) {
  long i = ((long)blockIdx.x * 256 + threadIdx.x) * 4;
  f32x4 v = *(const f32x4*)&kvacc[i];
  bf16x4 o;
#pragma unroll
  for (int r = 0; r < 4; ++r) o[r] = (short)f2b(v[r]);
  *(bf16x4*)&kvtb[i] = o;
}

// out[l*ldo + m] = scale * sum_e bq[l][e] * R[l][e][m]   (tiny, pre-loop)
__global__ __launch_bounds__(128) void phibias_kernel(const unsigned short* __restrict__ bq,
                                                      const unsigned short* __restrict__ R,
                                                      unsigned short* __restrict__ out,
                                                      float scale, int ldo) {
  const int l = blockIdx.x, m = threadIdx.x;
  const unsigned short* b = bq + (long)l * cE;
  const unsigned short* r = R + (long)l * cE * cM;
  float a = 0.f;
  for (int e = 0; e < cE; ++e) a += b2f(b[e]) * b2f(r[(long)e * cM + m]);
  out[(long)l * ldo + m] = f2b(a * scale);
}

// packed bias for fused GEMM: [bv(512) | bk(512) | bq(512)] per layer
__global__ __launch_bounds__(256) void packb_kernel(const unsigned short* __restrict__ bv,
                                                    const unsigned short* __restrict__ bk,
                                                    const unsigned short* __restrict__ bq,
                                                    unsigned short* __restrict__ out) {
  const int l = blockIdx.x, t = threadIdx.x;
#pragma unroll
  for (int s = 0; s < 512; s += 256) {
    out[l * cNF + s + t]        = bv[l * 512 + s + t];
    out[l * cNF + 512 + s + t]  = bk[l * 512 + s + t];
    out[l * cNF + 1024 + s + t] = bq[l * 512 + s + t];
  }
}

// z[b][m] = sum_s qtb[b][m][s]   (qtb is B x M x S)
__global__ __launch_bounds__(256) void zsumt_kernel(const unsigned short* __restrict__ qtb,
                                                    float* __restrict__ z) {
  __shared__ float sred[4];
  const int b = blockIdx.x, m = blockIdx.y, tid = threadIdx.x;
  const unsigned short* p = qtb + ((long)b * cM + m) * cS + (long)tid * 16;
  bf16x8 a = *(const bf16x8*)p;
  bf16x8 c = *(const bf16x8*)(p + 8);
  float s = 0.f;
#pragma unroll
  for (int t = 0; t < 8; ++t) s += b2f((unsigned short)a[t]) + b2f((unsigned short)c[t]);
#pragma unroll
  for (int off = 32; off >= 1; off >>= 1) s += __shfl_down(s, off, 64);
  const int w = tid >> 6, lane = tid & 63;
  if (lane == 0) sred[w] = s;
  __syncthreads();
  if (tid == 0) z[b * cM + m] = sred[0] + sred[1] + sred[2] + sred[3];
}

// den[row] = dot(pq[row,:], z[b,:]); 4 rows/block
__global__ __launch_bounds__(256) void den_kernel(const unsigned short* __restrict__ P,
                                                  const float* __restrict__ z,
                                                  float* __restrict__ den) {
  const int w = threadIdx.x >> 6, lane = threadIdx.x & 63;
  const long row = (long)blockIdx.x * 4 + w;
  const float* zb = z + (row >> 12) * cM;
  const unsigned short* p = P + row * cM;
  float d = b2f(p[lane]) * zb[lane] + b2f(p[lane + 64]) * zb[lane + 64];
#pragma unroll
  for (int off = 32; off >= 1; off >>= 1) d += __shfl_down(d, off, 64);
  if (lane == 0) den[row] = d;
}

// layernorm in place (bf16 -> bf16), one row per block
__global__ __launch_bounds__(256) void ln_kernel(unsigned short* __restrict__ a,
                                                 const unsigned short* __restrict__ g,
                                                 const unsigned short* __restrict__ bb) {
  __shared__ float sred[8];
  const long row = blockIdx.x;
  unsigned short* ar = a + row * cE;
  const int tid = threadIdx.x;
  float v0 = b2f(ar[tid]), v1 = b2f(ar[tid + 256]);
  float s = v0 + v1, sq = v0 * v0 + v1 * v1;
#pragma unroll
  for (int off = 32; off >= 1; off >>= 1) {
    s  += __shfl_down(s, off, 64);
    sq += __shfl_down(sq, off, 64);
  }
  const int w = tid >> 6, lane = tid & 63;
  if (lane == 0) { sred[w] = s; sred[4 + w] = sq; }
  __syncthreads();
  const float st  = sred[0] + sred[1] + sred[2] + sred[3];
  const float sqt = sred[4] + sred[5] + sred[6] + sred[7];
  const float mean = st * (1.f / 512.f);
  const float var  = fmaxf(sqt * (1.f / 512.f) - mean * mean, 0.f);
  const float rstd = rsqrtf(var + 1e-5f);
  ar[tid]       = f2b((v0 - mean) * rstd * b2f(g[tid])       + b2f(bb[tid]));
  ar[tid + 256] = f2b((v1 - mean) * rstd * b2f(g[tid + 256]) + b2f(bb[tid + 256]));
}

// batched bf16 transpose: in (R x C) -> out (C x R); grid (C/32, R/32, batch)
__global__ __launch_bounds__(256) void transpose_kernel(const unsigned short* __restrict__ in,
                                                        unsigned short* __restrict__ out,
                                                        int R, int C, long sIn, long sOut) {
  __shared__ unsigned short t[32][33];
  in  += (long)blockIdx.z * sIn;
  out += (long)blockIdx.z * sOut;
  const int bx = blockIdx.x << 5, by = blockIdx.y << 5;
  const int tx = threadIdx.x & 31, ty = threadIdx.x >> 5;
#pragma unroll
  for (int i = ty; i < 32; i += 8) t[i][tx] = in[(long)(by + i) * C + bx + tx];
  __syncthreads();
#pragma unroll
  for (int i = ty; i < 32; i += 8) out[(long)(bx + i) * R + by + tx] = t[tx][i];
}

// final head
__global__ __launch_bounds__(256) void head_kernel(const unsigned short* __restrict__ h,
                                                   const unsigned short* __restrict__ Wr1,
                                                   const unsigned short* __restrict__ br1,
                                                   const unsigned short* __restrict__ Wr2,
                                                   const unsigned short* __restrict__ br2,
                                                   void* __restrict__ out,
                                                   const int* __restrict__ flag) {
  __shared__ float pooled[cE];
  __shared__ float red[4];
  const int b = blockIdx.x, tid = threadIdx.x;
  pooled[tid]       = b2f(h[(long)b * cS * cE + tid]);
  pooled[tid + 256] = b2f(h[(long)b * cS * cE + tid + 256]);
  __syncthreads();
  float acc = b2f(br1[tid]);
  for (int e = 0; e < cE; ++e) acc += pooled[e] * b2f(Wr1[e * cHE + tid]);
  acc = fmaxf(acc, 0.f) * b2f(Wr2[tid]);
#pragma unroll
  for (int off = 32; off >= 1; off >>= 1) acc += __shfl_down(acc, off, 64);
  const int w = tid >> 6, lane = tid & 63;
  if (lane == 0) red[w] = acc;
  __syncthreads();
  if (tid == 0) {
    float r = red[0] + red[1] + red[2] + red[3] + b2f(br2[0]);
    if (flag[0]) ((float*)out)[b] = r;
    else         ((unsigned short*)out)[b] = f2b(r);
  }
}

// ---------------- host ----------------
extern "C" void kernel_launch(void* const* d_in, const int* in_sizes, int n_in,
                              void* d_out, int out_size, void* d_ws, size_t ws_size,
                              hipStream_t stream) {
  (void)in_sizes; (void)n_in; (void)out_size;

  char* ws = (char*)d_ws;
  size_t off = 0;
  auto alloc = [&](size_t bytes) -> void* {
    void* p = ws + off;
    off += (bytes + 255) & ~(size_t)255;
    return p;
  };
  // ---- memory plan ----
  unsigned short* h   = (unsigned short*)alloc(cNBS * cE * 2);   // 67 MB residual
  unsigned short* X   = (unsigned short*)alloc(cNBS * cE * 2);   // 67 MB multi-use
  unsigned short* Y   = (unsigned short*)alloc(cNBS * cE * 2);   // 67 MB multi-use
  unsigned short* Pb  = (unsigned short*)alloc(cNBS * cM * 2);   // 16.8 MB phi(q)
  unsigned short* kvtb= (unsigned short*)alloc((long)cB * cE * cM * 2); // 2.1 MB
  float* kvacc        = (float*)alloc((long)cB * cE * cM * 4);   // 4 MB f32 kv acc
  float* vec64k       = (float*)alloc(cNBS * 4);                 // den
  float* rnorm2       = (float*)alloc(2 * cNBS * 4);             // 512 KB: [k | q] row-norms
  float* z            = (float*)alloc(cB * cM * 4);
  float* partials     = (float*)alloc(1024 * 4);                 // [q 512 | k 512] block maxes
  float* gmaxf        = (float*)alloc(256);                      // gmax[0]=q, gmax[1]=k
  int*   dflag        = (int*)alloc(256);
  unsigned short* WiT = (unsigned short*)alloc((long)cE * cDIN * 2);
  unsigned short* BigB= (unsigned short*)alloc((long)cL * cNF * cE * 2); // 6.3 MB [WvT|WkT|WqT]
  unsigned short* BigL= (unsigned short*)alloc((long)cL * 256 * cE * 2); // 1 MB [WqRT|WkRT]
  unsigned short* WoT = (unsigned short*)alloc((long)cL * cE * cE * 2);
  unsigned short* RT  = (unsigned short*)alloc((long)cL * cM * cE * 2);
  unsigned short* W1T = (unsigned short*)alloc((long)cL * cFF * cE * 2);
  unsigned short* W2T = (unsigned short*)alloc((long)cL * cE * cFF * 2);
  unsigned short* sb  = (unsigned short*)alloc(170000 * 2);

  // weight staging inside X (dead until first in-loop X use)
  unsigned short* WqB = X;
  unsigned short* WkB = WqB + (long)cL * cE * cE;
  unsigned short* WvB = WkB + (long)cL * cE * cE;
  unsigned short* WoB = WvB + (long)cL * cE * cE;
  unsigned short* RmB = WoB + (long)cL * cE * cE;
  unsigned short* W1B = RmB + (long)cL * cE * cM;
  unsigned short* W2B = W1B + (long)cL * cE * cFF;
  unsigned short* WiB = W2B + (long)cL * cE * cFF;
  // x, pos staging inside Y
  unsigned short* xb   = Y;
  unsigned short* posb = Y + cNBS * cDIN;
  // small tensors inside sb
  unsigned short* biC  = sb;
  unsigned short* bqC  = biC  + 512;
  unsigned short* bkC  = bqC  + 2048;
  unsigned short* bvC  = bkC  + 2048;
  unsigned short* boC  = bvC  + 2048;
  unsigned short* b1C  = boC  + 2048;
  unsigned short* b2C  = b1C  + 8192;
  unsigned short* lngC = b2C  + 2048;
  unsigned short* lnbC = lngC + 2048;
  unsigned short* Wr1C = lnbC + 2048;
  unsigned short* br1C = Wr1C + 131072;
  unsigned short* Wr2C = br1C + 256;
  unsigned short* br2C = Wr2C + 256;
  unsigned short* bqkC  = br2C + 16;            // [scale*(bq@R) | scale*(bk@R)], L x 256
  unsigned short* b1536C = bqkC + cL * 256;     // packed fused bias, L x 1536

  unsigned short* qtb  = X;                       // pk^T (B x M x S), 16.8 MB
  float* logfX         = (float*)X;               // [logf_q | logf_k] f32, 67 MB
  unsigned short* vtb  = Y;                       // v^T (B x E x S)
  unsigned short* attb = X;                       // att output
  unsigned short* ab   = Y;                       // a / y (LN in place)
  unsigned short* u1b  = X;                       // FFN hidden chunk (16384 x 2048)

  if (off > ws_size) return;

  // ---- dtype detect + convert all inputs to bf16 ----
  detect_kernel<<<1, 64, 0, stream>>>((const unsigned short*)d_in[13], dflag);
  auto cvt = [&](const void* src, unsigned short* dst, long n) {
    cvt_kernel<<<(unsigned)((n + 255) / 256), 256, 0, stream>>>(src, dst, n, dflag);
  };
  cvt(d_in[0],  xb,   cNBS * cDIN);
  cvt(d_in[1],  WiB,  (long)cDIN * cE);
  cvt(d_in[2],  biC,  cE);
  cvt(d_in[3],  posb, (long)cS * cE);
  cvt(d_in[4],  WqB,  (long)cL * cE * cE);
  cvt(d_in[5],  bqC,  (long)cL * cE);
  cvt(d_in[6],  WkB,  (long)cL * cE * cE);
  cvt(d_in[7],  bkC,  (long)cL * cE);
  cvt(d_in[8],  WvB,  (long)cL * cE * cE);
  cvt(d_in[9],  bvC,  (long)cL * cE);
  cvt(d_in[10], WoB,  (long)cL * cE * cE);
  cvt(d_in[11], boC,  (long)cL * cE);
  cvt(d_in[12], RmB,  (long)cL * cE * cM);
  cvt(d_in[13], lngC, (long)cL * cE);
  cvt(d_in[14], lnbC, (long)cL * cE);
  cvt(d_in[15], W1B,  (long)cL * cE * cFF);
  cvt(d_in[16], b1C,  (long)cL * cFF);
  cvt(d_in[17], W2B,  (long)cL * cFF * cE);
  cvt(d_in[18], b2C,  (long)cL * cE);
  cvt(d_in[19], Wr1C, (long)cE * cHE);
  cvt(d_in[20], br1C, cHE);
  cvt(d_in[21], Wr2C, cHE);
  cvt(d_in[22], br2C, 1);

  typedef const unsigned short* cus;
  auto gemm = [&](const void* A, const void* Bt, const void* bias_,
                  const float* aux_, float* pmax_, void* C,
                  long rows, int K, int N, int lda, int ldb, float alpha, int flags,
                  long sA, long sB, long sC, int batches, const void* Res_ = nullptr) {
    dim3 g((unsigned)(rows / 128), (unsigned)(N / 128), (unsigned)batches);
    gemm_kernel<<<g, dim3(256), 0, stream>>>(
        (const unsigned short*)A, (const unsigned short*)Bt,
        (const unsigned short*)bias_, (const unsigned short*)Res_,
        aux_, pmax_, C, K, N, lda, ldb, alpha, flags, sA, sB, sC);
  };

  // ---- weight pre-transposes (BigB = [WvT | WkT | WqT] per layer) ----
  transpose_kernel<<<dim3(16, 2, 1), 256, 0, stream>>>(WiB, WiT, cDIN, cE, 0, 0);
  transpose_kernel<<<dim3(16, 16, cL), 256, 0, stream>>>(WvB, BigB, cE, cE, (long)cE * cE, (long)cNF * cE);
  transpose_kernel<<<dim3(16, 16, cL), 256, 0, stream>>>(WkB, BigB + (long)512 * cE, cE, cE, (long)cE * cE, (long)cNF * cE);
  transpose_kernel<<<dim3(16, 16, cL), 256, 0, stream>>>(WqB, BigB + (long)1024 * cE, cE, cE, (long)cE * cE, (long)cNF * cE);
  transpose_kernel<<<dim3(16, 16, cL), 256, 0, stream>>>(WoB, WoT, cE, cE, (long)cE * cE, (long)cE * cE);
  transpose_kernel<<<dim3(4, 16, cL), 256, 0, stream>>>(RmB, RT, cE, cM, (long)cE * cM, (long)cE * cM);
  transpose_kernel<<<dim3(64, 16, cL), 256, 0, stream>>>(W1B, W1T, cE, cFF, (long)cE * cFF, (long)cE * cFF);
  transpose_kernel<<<dim3(16, 64, cL), 256, 0, stream>>>(W2B, W2T, cFF, cE, (long)cFF * cE, (long)cFF * cE);

  // ---- fold R into Wq/Wk: BigL = [(Wq@R)^T | (Wk@R)^T] per layer ----
  gemm(RT, WqB, nullptr, nullptr, nullptr, BigL, cM, cE, cE, cE, cE, 1.f, 0,
       (long)cM * cE, (long)cE * cE, (long)256 * cE, cL);
  gemm(RT, WkB, nullptr, nullptr, nullptr, BigL + (long)128 * cE, cM, cE, cE, cE, cE, 1.f, 0,
       (long)cM * cE, (long)cE * cE, (long)256 * cE, cL);
  phibias_kernel<<<cL, 128, 0, stream>>>(bqC, RmB, bqkC, PSCALE, 256);
  phibias_kernel<<<cL, 128, 0, stream>>>(bkC, RmB, bqkC + 128, PSCALE, 256);
  packb_kernel<<<cL, 256, 0, stream>>>(bvC, bkC, bqC, b1536C);

  // ---- input projection + positional embedding ----
  gemm(xb, WiT, biC, nullptr, nullptr, h, cNBS, cDIN, cE, cDIN, cDIN, 1.f,
       FLAG_BIAS, 0, 0, 0, 1);
  addpos_kernel<<<16384, 256, 0, stream>>>(h, posb);

  for (int i = 0; i < cL; ++i) {
    cus WoT_i = WoT + (long)i * cE * cE;  cus bo_i = boC + (long)i * cE;
    cus BigB_i = BigB + (long)i * cNF * cE;
    cus BigL_i = BigL + (long)i * 256 * cE;
    cus b1536_i = b1536C + (long)i * cNF;
    cus bqk_i = bqkC + (long)i * 256;
    cus g_i   = lngC + (long)i * cE;      cus b_i  = lnbC + (long)i * cE;
    cus W1T_i = W1T + (long)i * cFF * cE; cus b1_i = b1C + (long)i * cFF;
    cus W2T_i = W2T + (long)i * cE * cFF; cus b2_i = b2C + (long)i * cE;

    // --- fused one pass over h: v^T (VT), ||k||^2 + ||q||^2 (RNORM atomics) ---
    zero4_kernel<<<128, 256, 0, stream>>>(rnorm2);
    gemm_kernel<<<dim3(12, 512, 1), dim3(256), 0, stream>>>(
        h, BigB_i, b1536_i, nullptr, nullptr, rnorm2, vtb,
        cE, cNF, cE, cE, 1.f, FLAG_FUSED, 0, 0, (long)cE * cS);

    // --- dual logits: q (by=0) and k (by=1), f32 + block maxes ---
    gemm_kernel<<<dim3(512, 2, 1), dim3(256), 0, stream>>>(
        h, BigL_i, bqk_i, nullptr, rnorm2, partials, logfX,
        cE, 256, cE, cE, PSCALE, FLAG_PHIK | FLAG_BIAS, 0, 0, 0);

    reducemax2_kernel<<<1, 256, 0, stream>>>(partials, gmaxf);
    expq_kernel<<<8192, 256, 0, stream>>>(logfX, gmaxf, Pb);
    expT_kernel<<<dim3(4, 128, cB), 256, 0, stream>>>(logfX + cNBS * cM, gmaxf + 1, qtb);

    // --- z, den ---
    zsumt_kernel<<<dim3(cB, cM), 256, 0, stream>>>(qtb, z);
    den_kernel<<<16384, 256, 0, stream>>>(Pb, z, vec64k);

    // --- kv^T[b] = v^T[b] @ pk[b], split-K x8 with in-cache f32 atomics ---
    zero4_kernel<<<1024, 256, 0, stream>>>(kvacc);
    gemm(vtb, qtb, nullptr, nullptr, nullptr, kvacc, cE, cS / 8, cM, cS, cS, 1.f,
         FLAG_SPLITK8 | FLAG_ATOMIC, (long)cE * cS, (long)cM * cS, (long)cE * cM, cB * 8);
    kvcvt_kernel<<<1024, 256, 0, stream>>>(kvacc, kvtb);

    // --- att[b] = (pq[b] @ kv[b]) / (den+1e-6) -> X ---
    gemm(Pb, kvtb, nullptr, vec64k, nullptr, attb, cS, cM, cE, cM, cM, 1.f,
         FLAG_DEN, (long)cS * cM, (long)cE * cM, (long)cS * cE, cB);

    // --- a = att @ Wo + bo -> Y ; LN in place ---
    gemm(attb, WoT_i, bo_i, nullptr, nullptr, ab, cNBS, cE, cE, cE, cE, 1.f,
         FLAG_BIAS, 0, 0, 0, 1);
    ln_kernel<<<cNBS, 256, 0, stream>>>(ab, g_i, b_i);

    // --- FFN in 4 row-chunks of 16384; h += ffn(y) ---
    for (int c = 0; c < 4; ++c) {
      const unsigned short* yc = ab + (long)c * 16384 * cE;
      unsigned short* hc = h + (long)c * 16384 * cE;
      gemm(yc, W1T_i, b1_i, nullptr, nullptr, u1b, 16384, cE, cFF, cE, cE, 1.f,
           FLAG_BIAS | FLAG_GELU, 0, 0, 0, 1);
      gemm(u1b, W2T_i, b2_i, nullptr, nullptr, hc, 16384, cFF, cE, cFF, cFF, 1.f,
           FLAG_BIAS | FLAG_RES, 0, 0, 0, 1, hc);
    }
  }

  head_kernel<<<cB, 256, 0, stream>>>(h, Wr1C, br1C, Wr2C, br2C, d_out, dflag);
}

// Round 9
// 4032.538 us; speedup vs baseline: 1.1469x; 1.0600x over previous
//
#include <hip/hip_runtime.h>
#include <math.h>

// ---------------- problem constants ----------------
static constexpr int  cB   = 16;
static constexpr int  cS   = 4096;
static constexpr int  cDIN = 64;
static constexpr int  cE   = 512;
static constexpr int  cM   = 128;
static constexpr int  cL   = 4;
static constexpr int  cFF  = 2048;   // 4*E
static constexpr int  cHE  = 256;    // E/2
static constexpr long cNBS = (long)cB * cS;   // 65536 rows
static constexpr int  cNF  = 1536;   // fused N = 512(v) + 512(k-norm) + 512(q-norm)

typedef __attribute__((ext_vector_type(8))) short  bf16x8;
typedef __attribute__((ext_vector_type(4))) short  bf16x4;
typedef __attribute__((ext_vector_type(4))) float  f32x4;

typedef const __attribute__((address_space(1))) unsigned int g_u32;
typedef __attribute__((address_space(3))) unsigned int l_u32;

__device__ __forceinline__ float b2f(unsigned short u) {
  union { unsigned int i; float f; } x; x.i = ((unsigned int)u) << 16; return x.f;
}
__device__ __forceinline__ unsigned short f2b(float f) {
  union { float f; unsigned int i; } x; x.f = f;
  unsigned int r = x.i + 0x7FFFu + ((x.i >> 16) & 1u);   // RNE
  return (unsigned short)(r >> 16);
}

// phi math (round-6 post-mortem): max-shift and q-row-norm do NOT cancel out
// of num/(den+1e-6); faithful computation kept (round-7: absmax 0.0078).
#define PSCALE 0.21022410381342863f     // 512^-0.25
#define PNRM   0.022097086912079608f    // 0.5 * PSCALE^2
#define PINV   0.08838834764831845f     // 1/sqrt(M)

// ---------------- GEMM: C[rows x N] = f(alpha*A@Bt^T + bias) -------------
// A: rows x K bf16 (row stride lda). Bt: N x K bf16 (row stride ldb).
#define FLAG_BIAS    2
#define FLAG_GELU    4
#define FLAG_RES     8     // += bf16 Res[idx]
#define FLAG_VT      16    // store transposed per 4096-row batch, batch stride sC
#define FLAG_DEN     32    // v = acc/(aux[zb*rowsPerBatch+rr]+1e-6) BEFORE bias
#define FLAG_RNORM   64    // no C store; atomicAdd row-norms of (acc+bias) into pmax[rnoff+row]
#define FLAG_PHIK    128   // dual q/k logits: by=0 q (aux+cNBS), by=1 k (aux+0);
                           // l = PSCALE*acc + bias - PNRM*aux; f32 out + block max
#define FLAG_F32OUT  256   // store f32
#define FLAG_SPLITK8 512   // blockIdx.z = batch*8 + k-chunk
#define FLAG_ATOMIC  1024  // f32 atomicAdd into C (indexed by batch zb)
#define FLAG_FUSED   2048  // (with SWZ, grid (12,512)): by<4 VT(v), by<8 RNORM(k), by<12 RNORM(q)
#define FLAG_SWZ     4096  // grid (NBcols, nbx): XCD-aware remap so all column-blocks
                           // sharing an A-row-panel land on ONE XCD's L2 (round-7 PM:
                           // round-robin spread caused 4x A re-fetch, 269 MB FETCH)

#define GMT 128
#define GNT 128
#define GBK 32

__global__ __launch_bounds__(256, 2)
void gemm_kernel(const unsigned short* __restrict__ A,
                 const unsigned short* __restrict__ Bt,
                 const unsigned short* __restrict__ bias,
                 const unsigned short* __restrict__ Res,
                 const float* __restrict__ aux,
                 float* __restrict__ pmax,
                 void* __restrict__ C,
                 int K, int N, int lda, int ldb, float alpha, int flags,
                 long sA, long sB, long sC)
{
  // 18 KB shared: As(8K)+Bs(8K) during K-loop; stage aliases them post-loop (VT).
  __shared__ __align__(16) unsigned char sraw[18048];
  unsigned short (*As)[32] = (unsigned short (*)[32])sraw;
  unsigned short (*Bs)[32] = (unsigned short (*)[32])(sraw + 8192);
  unsigned short (*stage)[136] = (unsigned short (*)[136])sraw;   // VT post-loop (17408 B)
  float* wred  = (float*)(sraw + 17472);                          // PHIK block max (16 B)

  const int tid  = threadIdx.x;
  const int lane = tid & 63;
  const int wid  = tid >> 6;

  int bx = blockIdx.x, by = blockIdx.y;
  if (flags & FLAG_SWZ) {
    // lid%8 = XCD (observed round-robin); give each XCD a contiguous bx range,
    // iterate by fastest within it -> A-panel read by exactly one L2.
    const unsigned lid  = blockIdx.x + gridDim.x * blockIdx.y;
    const unsigned xcd  = lid & 7u;
    const unsigned slot = lid >> 3;
    bx = (int)(xcd * (gridDim.y >> 3) + slot / gridDim.x);
    by = (int)(slot % gridDim.x);
  }

  long zb = blockIdx.z;            // batch index (for A/B/aux)
  const long zc = blockIdx.z;      // C-store base index (keeps k-chunk for split-K)
  int koff = 0;
  if (flags & FLAG_SPLITK8) { koff = (int)(zb & 7) * K; zb >>= 3; }

  const unsigned short* Ab = A + zb * sA + (long)bx * GMT * lda + koff;
  const unsigned short* Bb = Bt + zb * sB + (long)by * GNT * ldb + koff;

  // async staging: lane's LDS dest = tile_base + wid*1024 + lane*16 (contiguous)
  const int srow = wid * 16 + (lane >> 2);   // 0..63
  const int scol = (lane & 3) << 3;          // 0,8,16,24
  const unsigned short* gA = Ab + (long)srow * lda + scol;
  const unsigned short* gB = Bb + (long)srow * ldb + scol;
  l_u32* lA0 = (l_u32*)&As[srow][scol];
  l_u32* lA1 = (l_u32*)&As[srow + 64][scol];
  l_u32* lB0 = (l_u32*)&Bs[srow][scol];
  l_u32* lB1 = (l_u32*)&Bs[srow + 64][scol];

  const f32x4 fzero = {0.f, 0.f, 0.f, 0.f};
  f32x4 acc[4][4];
#pragma unroll
  for (int i = 0; i < 4; ++i)
#pragma unroll
    for (int j = 0; j < 4; ++j) acc[i][j] = fzero;

  const int wm = (wid >> 1) << 6;
  const int wn = (wid & 1) << 6;
  const int fm = lane & 15;
  const int kq = (lane >> 4) << 3;

  const long ka64 = (long)64 * lda, kb64 = (long)64 * ldb;
  for (int k0 = 0; k0 < K; k0 += GBK) {
    __builtin_amdgcn_global_load_lds((g_u32*)(gA + k0),        lA0, 16, 0, 0);
    __builtin_amdgcn_global_load_lds((g_u32*)(gA + ka64 + k0), lA1, 16, 0, 0);
    __builtin_amdgcn_global_load_lds((g_u32*)(gB + k0),        lB0, 16, 0, 0);
    __builtin_amdgcn_global_load_lds((g_u32*)(gB + kb64 + k0), lB1, 16, 0, 0);
    __syncthreads();

    bf16x8 af[4], bfv[4];
#pragma unroll
    for (int i = 0; i < 4; ++i) {
      af[i]  = *(const bf16x8*)&As[wm + i * 16 + fm][kq];
      bfv[i] = *(const bf16x8*)&Bs[wn + i * 16 + fm][kq];
    }
#pragma unroll
    for (int i = 0; i < 4; ++i)
#pragma unroll
      for (int j = 0; j < 4; ++j)
        acc[i][j] = __builtin_amdgcn_mfma_f32_16x16x32_bf16(af[i], bfv[j], acc[i][j], 0, 0, 0);
    __syncthreads();
  }

  // epilogue: C/D layout col=lane&15, row=(lane>>4)*4+reg  [verified m89/m91]
  const int rq = (lane >> 4) << 2;
  const long crow0 = (long)bx * GMT + wm;
  const int  ccol0 = by * GNT + wn;

  long rnoff = 0;
  if (flags & FLAG_FUSED) {
    if (by < 4) flags = FLAG_BIAS | FLAG_VT;
    else { flags = FLAG_BIAS | FLAG_RNORM; if (by >= 8) rnoff = cNBS; }
  }

  if (flags & FLAG_RNORM) {
    // row-norm of (acc*alpha + bias): reduce over this wave's 64 cols, atomic-add.
#pragma unroll
    for (int i = 0; i < 4; ++i)
#pragma unroll
      for (int r = 0; r < 4; ++r) {
        float s = 0.f;
#pragma unroll
        for (int j = 0; j < 4; ++j) {
          float v = acc[i][j][r] * alpha + b2f(bias[ccol0 + j * 16 + fm]);
          s += v * v;
        }
        s += __shfl_xor(s, 1, 64);
        s += __shfl_xor(s, 2, 64);
        s += __shfl_xor(s, 4, 64);
        s += __shfl_xor(s, 8, 64);
        if (fm == 0)
          unsafeAtomicAdd(&pmax[rnoff + crow0 + i * 16 + rq + r], s);
      }
    return;
  }

  if (flags & FLAG_PHIK) {
    // dual q/k phi logits (grid (2,512)+SWZ): by=0 q (aux offset cNBS), by=1 k.
    // l = PSCALE*acc + bias - PNRM*aux[row]; f32 out + block max to pmax[by*512+bx].
    const long aoff = (by == 0) ? cNBS : 0;
    float* Cf = (float*)C + (long)by * (cNBS * (long)cM);
    float mx = -3.0e38f;
#pragma unroll
    for (int i = 0; i < 4; ++i)
#pragma unroll
      for (int r = 0; r < 4; ++r) {
        const long rr = crow0 + i * 16 + rq + r;
        const float nrm = PNRM * aux[aoff + rr];
#pragma unroll
        for (int j = 0; j < 4; ++j) {
          const int cc = ccol0 + j * 16 + fm;
          const float bv = b2f(bias[cc]);
          float l = acc[i][j][r] * PSCALE + bv - nrm;
          mx = fmaxf(mx, l);
          Cf[rr * (long)cM + (cc & (cM - 1))] = l;
        }
      }
#pragma unroll
    for (int off = 32; off >= 1; off >>= 1) mx = fmaxf(mx, __shfl_down(mx, off, 64));
    if (lane == 0) wred[wid] = mx;
    __syncthreads();
    if (tid == 0)
      pmax[by * 512 + bx] = fmaxf(fmaxf(wred[0], wred[1]), fmaxf(wred[2], wred[3]));
    return;
  }

  if (flags & FLAG_ATOMIC) {
    // split-K reduction in-cache: f32 atomic add into C[zb]
    float* Cf = (float*)C + zb * sC;
#pragma unroll
    for (int j = 0; j < 4; ++j) {
      const int cc = ccol0 + j * 16 + fm;
#pragma unroll
      for (int i = 0; i < 4; ++i)
#pragma unroll
        for (int r = 0; r < 4; ++r) {
          const long rr = crow0 + i * 16 + rq + r;
          unsafeAtomicAdd(&Cf[rr * (long)N + cc], acc[i][j][r] * alpha);
        }
    }
    return;
  }

  if (flags & FLAG_VT) {
    // stage 64 cols x 128 rows in LDS, then coalesced column stores (64B/thread)
    unsigned short* Cb = (unsigned short*)C;
    const int bb = (bx * GMT) >> 12;
    const long sbase = (long)((bx * GMT) & (cS - 1));
#pragma unroll
    for (int rnd = 0; rnd < 2; ++rnd) {
      if ((wn >> 6) == rnd) {
#pragma unroll
        for (int j = 0; j < 4; ++j) {
          const int cc = ccol0 + j * 16 + fm;
          const float bv = (flags & FLAG_BIAS) ? b2f(bias[cc]) : 0.f;
          const int cl = j * 16 + fm;
#pragma unroll
          for (int i = 0; i < 4; ++i)
#pragma unroll
            for (int r = 0; r < 4; ++r)
              stage[cl][wm + i * 16 + rq + r] = f2b(acc[i][j][r] * alpha + bv);
        }
      }
      __syncthreads();
      {
        const int cl = tid >> 2;
        const int sseg = (tid & 3) << 5;
        const int gcol = by * GNT + rnd * 64 + cl;
        unsigned short* dst = Cb + (long)bb * sC + (long)gcol * cS + sbase + sseg;
#pragma unroll
        for (int t = 0; t < 4; ++t)
          *(bf16x8*)(dst + t * 8) = *(const bf16x8*)&stage[cl][sseg + t * 8];
      }
      __syncthreads();
    }
    return;
  }

  // generic epilogue. Order: acc -> DEN -> +bias -> GELU -> RES (DEN before bias
  // so att = (pq@kvo)/den + bo works; plain BIAS/GELU paths unaffected).
  const long rowsPerBatch = (long)gridDim.x * GMT;
#pragma unroll
  for (int j = 0; j < 4; ++j) {
    const int cc = ccol0 + j * 16 + fm;
    const float bv = (flags & FLAG_BIAS) ? b2f(bias[cc]) : 0.f;
#pragma unroll
    for (int i = 0; i < 4; ++i) {
      const long rbase = crow0 + i * 16 + rq;
#pragma unroll
      for (int r = 0; r < 4; ++r) {
        const long rr = rbase + r;
        float v = acc[i][j][r] * alpha;
        if (flags & FLAG_DEN)
          v *= 1.f / (fmaxf(aux[zb * rowsPerBatch + rr], 0.f) + 1e-6f);
        v += bv;
        if (flags & FLAG_GELU) v = 0.5f * v * (1.f + erff(v * 0.7071067811865475f));
        const long idx = zc * sC + rr * (long)N + cc;
        if (flags & FLAG_RES) v += b2f(Res[idx]);
        if (flags & FLAG_F32OUT) ((float*)C)[idx] = v;
        else                     ((unsigned short*)C)[idx] = f2b(v);
      }
    }
  }
}

// ---------------- dtype shim ----------------
__global__ void detect_kernel(const unsigned short* __restrict__ lng,
                              int* __restrict__ flag) {
  if (threadIdx.x == 0 && blockIdx.x == 0) flag[0] = (lng[0] == 0) ? 1 : 0;
}

__global__ __launch_bounds__(256) void cvt_kernel(const void* __restrict__ in,
                                                  unsigned short* __restrict__ out,
                                                  long n, const int* __restrict__ flag) {
  long i = (long)blockIdx.x * 256 + threadIdx.x;
  if (i >= n) return;
  if (flag[0]) out[i] = f2b(((const float*)in)[i]);
  else         out[i] = ((const unsigned short*)in)[i];
}

// ---------------- small kernels ----------------
__global__ __launch_bounds__(256) void zero4_kernel(float* __restrict__ p) {
  long i = ((long)blockIdx.x * 256 + threadIdx.x) * 4;
  f32x4 z = {0.f, 0.f, 0.f, 0.f};
  *(f32x4*)&p[i] = z;
}

__global__ __launch_bounds__(256) void addpos_kernel(unsigned short* __restrict__ h,
                                                     const unsigned short* __restrict__ pos) {
  long i = ((long)blockIdx.x * 256 + threadIdx.x) * 8;
  long se = i % ((long)cS * cE);
  bf16x8 v = *(bf16x8*)&h[i];
  bf16x8 p = *(const bf16x8*)&pos[se];
#pragma unroll
  for (int r = 0; r < 8; ++r)
    v[r] = (short)f2b(b2f((unsigned short)v[r]) + b2f((unsigned short)p[r]));
  *(bf16x8*)&h[i] = v;
}

// gmax[0]=max(partials[0..512)) (q), gmax[1]=max(partials[512..1024)) (k)
__global__ __launch_bounds__(256) void reducemax2_kernel(const float* __restrict__ partials,
                                                         float* __restrict__ gmax) {
  __shared__ float sm[8];
  const int tid = threadIdx.x;
  for (int half = 0; half < 2; ++half) {
    float mx = -3.0e38f;
    for (int i = tid; i < 512; i += 256) mx = fmaxf(mx, partials[half * 512 + i]);
#pragma unroll
    for (int off = 32; off >= 1; off >>= 1) mx = fmaxf(mx, __shfl_down(mx, off, 64));
    if ((tid & 63) == 0) sm[(half << 2) + (tid >> 6)] = mx;
  }
  __syncthreads();
  if (tid == 0) gmax[0] = fmaxf(fmaxf(sm[0], sm[1]), fmaxf(sm[2], sm[3]));
  if (tid == 1) gmax[1] = fmaxf(fmaxf(sm[4], sm[5]), fmaxf(sm[6], sm[7]));
}

// elementwise exp (row-major): P = bf16(exp(lf - gm)/sqrt(M))
__global__ __launch_bounds__(256) void expq_kernel(const float* __restrict__ lf,
                                                   const float* __restrict__ gmx,
                                                   unsigned short* __restrict__ P) {
  long i = ((long)blockIdx.x * 256 + threadIdx.x) * 4;
  const float gm = gmx[0];
  f32x4 v = *(const f32x4*)&lf[i];
  bf16x4 o;
#pragma unroll
  for (int r = 0; r < 4; ++r)
    o[r] = (short)f2b(__expf(fminf(v[r] - gm, 0.f)) * PINV);
  *(bf16x4*)&P[i] = o;
}

// fused exp + transpose: lf (B x S x M f32 logits) -> out (B x M x S bf16 phi)
__global__ __launch_bounds__(256) void expT_kernel(const float* __restrict__ lf,
                                                   const float* __restrict__ gmx,
                                                   unsigned short* __restrict__ out) {
  __shared__ unsigned short t[32][33];
  const int b = blockIdx.z;
  const float gm = gmx[0];
  const int bx = blockIdx.x << 5, by = blockIdx.y << 5;   // bx: M, by: S
  const int tx = threadIdx.x & 31, ty = threadIdx.x >> 5;
  const float* src = lf + (long)b * cS * cM;
  unsigned short* dst = out + (long)b * cM * cS;
#pragma unroll
  for (int i = ty; i < 32; i += 8) {
    float l = src[(long)(by + i) * cM + bx + tx];
    t[i][tx] = f2b(__expf(fminf(l - gm, 0.f)) * PINV);
  }
  __syncthreads();
#pragma unroll
  for (int i = ty; i < 32; i += 8)
    dst[(long)(bx + i) * cS + by + tx] = t[tx][i];
}

// kv f32 accumulators -> bf16
__global__ __launch_bounds__(256) void kvcvt_kernel(const float* __restrict__ kvacc,
                                                    unsigned short* __restrict__ kvtb) {
  long i = ((long)blockIdx.x * 256 + threadIdx.x) * 4;
  f32x4 v = *(const f32x4*)&kvacc[i];
  bf16x4 o;
#pragma unroll
  for (int r = 0; r < 4; ++r) o[r] = (short)f2b(v[r]);
  *(bf16x4*)&kvtb[i] = o;
}

// out[l*ldo + m] = scale * sum_e bq[l][e] * R[l][e][m]   (tiny, pre-loop)
__global__ __launch_bounds__(128) void phibias_kernel(const unsigned short* __restrict__ bq,
                                                      const unsigned short* __restrict__ R,
                                                      unsigned short* __restrict__ out,
                                                      float scale, int ldo) {
  const int l = blockIdx.x, m = threadIdx.x;
  const unsigned short* b = bq + (long)l * cE;
  const unsigned short* r = R + (long)l * cE * cM;
  float a = 0.f;
  for (int e = 0; e < cE; ++e) a += b2f(b[e]) * b2f(r[(long)e * cM + m]);
  out[(long)l * ldo + m] = f2b(a * scale);
}

// packed bias for fused GEMM: [bv(512) | bk(512) | bq(512)] per layer
__global__ __launch_bounds__(256) void packb_kernel(const unsigned short* __restrict__ bv,
                                                    const unsigned short* __restrict__ bk,
                                                    const unsigned short* __restrict__ bq,
                                                    unsigned short* __restrict__ out) {
  const int l = blockIdx.x, t = threadIdx.x;
#pragma unroll
  for (int s = 0; s < 512; s += 256) {
    out[l * cNF + s + t]        = bv[l * 512 + s + t];
    out[l * cNF + 512 + s + t]  = bk[l * 512 + s + t];
    out[l * cNF + 1024 + s + t] = bq[l * 512 + s + t];
  }
}

// z[b][m] = sum_s qtb[b][m][s]   (qtb is B x M x S)
__global__ __launch_bounds__(256) void zsumt_kernel(const unsigned short* __restrict__ qtb,
                                                    float* __restrict__ z) {
  __shared__ float sred[4];
  const int b = blockIdx.x, m = blockIdx.y, tid = threadIdx.x;
  const unsigned short* p = qtb + ((long)b * cM + m) * cS + (long)tid * 16;
  bf16x8 a = *(const bf16x8*)p;
  bf16x8 c = *(const bf16x8*)(p + 8);
  float s = 0.f;
#pragma unroll
  for (int t = 0; t < 8; ++t) s += b2f((unsigned short)a[t]) + b2f((unsigned short)c[t]);
#pragma unroll
  for (int off = 32; off >= 1; off >>= 1) s += __shfl_down(s, off, 64);
  const int w = tid >> 6, lane = tid & 63;
  if (lane == 0) sred[w] = s;
  __syncthreads();
  if (tid == 0) z[b * cM + m] = sred[0] + sred[1] + sred[2] + sred[3];
}

// den[row] = dot(pq[row,:], z[b,:]); 4 rows/block
__global__ __launch_bounds__(256) void den_kernel(const unsigned short* __restrict__ P,
                                                  const float* __restrict__ z,
                                                  float* __restrict__ den) {
  const int w = threadIdx.x >> 6, lane = threadIdx.x & 63;
  const long row = (long)blockIdx.x * 4 + w;
  const float* zb = z + (row >> 12) * cM;
  const unsigned short* p = P + row * cM;
  float d = b2f(p[lane]) * zb[lane] + b2f(p[lane + 64]) * zb[lane + 64];
#pragma unroll
  for (int off = 32; off >= 1; off >>= 1) d += __shfl_down(d, off, 64);
  if (lane == 0) den[row] = d;
}

// layernorm in place (bf16 -> bf16), one row per block
__global__ __launch_bounds__(256) void ln_kernel(unsigned short* __restrict__ a,
                                                 const unsigned short* __restrict__ g,
                                                 const unsigned short* __restrict__ bb) {
  __shared__ float sred[8];
  const long row = blockIdx.x;
  unsigned short* ar = a + row * cE;
  const int tid = threadIdx.x;
  float v0 = b2f(ar[tid]), v1 = b2f(ar[tid + 256]);
  float s = v0 + v1, sq = v0 * v0 + v1 * v1;
#pragma unroll
  for (int off = 32; off >= 1; off >>= 1) {
    s  += __shfl_down(s, off, 64);
    sq += __shfl_down(sq, off, 64);
  }
  const int w = tid >> 6, lane = tid & 63;
  if (lane == 0) { sred[w] = s; sred[4 + w] = sq; }
  __syncthreads();
  const float st  = sred[0] + sred[1] + sred[2] + sred[3];
  const float sqt = sred[4] + sred[5] + sred[6] + sred[7];
  const float mean = st * (1.f / 512.f);
  const float var  = fmaxf(sqt * (1.f / 512.f) - mean * mean, 0.f);
  const float rstd = rsqrtf(var + 1e-5f);
  ar[tid]       = f2b((v0 - mean) * rstd * b2f(g[tid])       + b2f(bb[tid]));
  ar[tid + 256] = f2b((v1 - mean) * rstd * b2f(g[tid + 256]) + b2f(bb[tid + 256]));
}

// batched bf16 transpose: in (R x C) -> out (C x R); grid (C/32, R/32, batch)
__global__ __launch_bounds__(256) void transpose_kernel(const unsigned short* __restrict__ in,
                                                        unsigned short* __restrict__ out,
                                                        int R, int C, long sIn, long sOut) {
  __shared__ unsigned short t[32][33];
  in  += (long)blockIdx.z * sIn;
  out += (long)blockIdx.z * sOut;
  const int bx = blockIdx.x << 5, by = blockIdx.y << 5;
  const int tx = threadIdx.x & 31, ty = threadIdx.x >> 5;
#pragma unroll
  for (int i = ty; i < 32; i += 8) t[i][tx] = in[(long)(by + i) * C + bx + tx];
  __syncthreads();
#pragma unroll
  for (int i = ty; i < 32; i += 8) out[(long)(bx + i) * R + by + tx] = t[tx][i];
}

// final head
__global__ __launch_bounds__(256) void head_kernel(const unsigned short* __restrict__ h,
                                                   const unsigned short* __restrict__ Wr1,
                                                   const unsigned short* __restrict__ br1,
                                                   const unsigned short* __restrict__ Wr2,
                                                   const unsigned short* __restrict__ br2,
                                                   void* __restrict__ out,
                                                   const int* __restrict__ flag) {
  __shared__ float pooled[cE];
  __shared__ float red[4];
  const int b = blockIdx.x, tid = threadIdx.x;
  pooled[tid]       = b2f(h[(long)b * cS * cE + tid]);
  pooled[tid + 256] = b2f(h[(long)b * cS * cE + tid + 256]);
  __syncthreads();
  float acc = b2f(br1[tid]);
  for (int e = 0; e < cE; ++e) acc += pooled[e] * b2f(Wr1[e * cHE + tid]);
  acc = fmaxf(acc, 0.f) * b2f(Wr2[tid]);
#pragma unroll
  for (int off = 32; off >= 1; off >>= 1) acc += __shfl_down(acc, off, 64);
  const int w = tid >> 6, lane = tid & 63;
  if (lane == 0) red[w] = acc;
  __syncthreads();
  if (tid == 0) {
    float r = red[0] + red[1] + red[2] + red[3] + b2f(br2[0]);
    if (flag[0]) ((float*)out)[b] = r;
    else         ((unsigned short*)out)[b] = f2b(r);
  }
}

// ---------------- host ----------------
extern "C" void kernel_launch(void* const* d_in, const int* in_sizes, int n_in,
                              void* d_out, int out_size, void* d_ws, size_t ws_size,
                              hipStream_t stream) {
  (void)in_sizes; (void)n_in; (void)out_size;

  char* ws = (char*)d_ws;
  size_t off = 0;
  auto alloc = [&](size_t bytes) -> void* {
    void* p = ws + off;
    off += (bytes + 255) & ~(size_t)255;
    return p;
  };
  // ---- memory plan ----
  unsigned short* h   = (unsigned short*)alloc(cNBS * cE * 2);   // 67 MB residual
  unsigned short* X   = (unsigned short*)alloc(cNBS * cE * 2);   // 67 MB multi-use
  unsigned short* Y   = (unsigned short*)alloc(cNBS * cE * 2);   // 67 MB multi-use
  unsigned short* Pb  = (unsigned short*)alloc(cNBS * cM * 2);   // 16.8 MB phi(q)
  unsigned short* kvtb= (unsigned short*)alloc((long)cB * cM * cE * 2); // 2.1 MB kv (M x E)
  unsigned short* kvotb=(unsigned short*)alloc((long)cB * cE * cM * 2); // 2.1 MB (kv@Wo)^T
  float* kvacc        = (float*)alloc((long)cB * cM * cE * 4);   // 4 MB f32 kv acc
  float* vec64k       = (float*)alloc(cNBS * 4);                 // den
  float* rnorm2       = (float*)alloc(2 * cNBS * 4);             // 512 KB: [k | q] row-norms
  float* z            = (float*)alloc(cB * cM * 4);
  float* partials     = (float*)alloc(1024 * 4);                 // [q 512 | k 512] block maxes
  float* gmaxf        = (float*)alloc(256);                      // gmax[0]=q, gmax[1]=k
  int*   dflag        = (int*)alloc(256);
  unsigned short* WiT = (unsigned short*)alloc((long)cE * cDIN * 2);
  unsigned short* BigB= (unsigned short*)alloc((long)cL * cNF * cE * 2); // 6.3 MB [WvT|WkT|WqT]
  unsigned short* BigL= (unsigned short*)alloc((long)cL * 256 * cE * 2); // 1 MB [WqRT|WkRT]
  unsigned short* WoT = (unsigned short*)alloc((long)cL * cE * cE * 2);
  unsigned short* RT  = (unsigned short*)alloc((long)cL * cM * cE * 2);
  unsigned short* W1T = (unsigned short*)alloc((long)cL * cFF * cE * 2);
  unsigned short* W2T = (unsigned short*)alloc((long)cL * cE * cFF * 2);
  unsigned short* sb  = (unsigned short*)alloc(170000 * 2);

  // weight staging inside X (dead until first in-loop X use)
  unsigned short* WqB = X;
  unsigned short* WkB = WqB + (long)cL * cE * cE;
  unsigned short* WvB = WkB + (long)cL * cE * cE;
  unsigned short* WoB = WvB + (long)cL * cE * cE;
  unsigned short* RmB = WoB + (long)cL * cE * cE;
  unsigned short* W1B = RmB + (long)cL * cE * cM;
  unsigned short* W2B = W1B + (long)cL * cE * cFF;
  unsigned short* WiB = W2B + (long)cL * cE * cFF;
  // x, pos staging inside Y
  unsigned short* xb   = Y;
  unsigned short* posb = Y + cNBS * cDIN;
  // small tensors inside sb
  unsigned short* biC  = sb;
  unsigned short* bqC  = biC  + 512;
  unsigned short* bkC  = bqC  + 2048;
  unsigned short* bvC  = bkC  + 2048;
  unsigned short* boC  = bvC  + 2048;
  unsigned short* b1C  = boC  + 2048;
  unsigned short* b2C  = b1C  + 8192;
  unsigned short* lngC = b2C  + 2048;
  unsigned short* lnbC = lngC + 2048;
  unsigned short* Wr1C = lnbC + 2048;
  unsigned short* br1C = Wr1C + 131072;
  unsigned short* Wr2C = br1C + 256;
  unsigned short* br2C = Wr2C + 256;
  unsigned short* bqkC  = br2C + 16;            // [scale*(bq@R) | scale*(bk@R)], L x 256
  unsigned short* b1536C = bqkC + cL * 256;     // packed fused bias, L x 1536

  unsigned short* qtb  = X;                       // pk^T (B x M x S), 16.8 MB
  float* logfX         = (float*)X;               // [logf_q | logf_k] f32, 67 MB
  unsigned short* vtb  = Y;                       // v^T (B x E x S)
  unsigned short* ab   = Y;                       // a / y (LN in place)
  unsigned short* u1b  = X;                       // FFN hidden chunk (16384 x 2048)

  if (off > ws_size) return;

  // ---- dtype detect + convert all inputs to bf16 ----
  detect_kernel<<<1, 64, 0, stream>>>((const unsigned short*)d_in[13], dflag);
  auto cvt = [&](const void* src, unsigned short* dst, long n) {
    cvt_kernel<<<(unsigned)((n + 255) / 256), 256, 0, stream>>>(src, dst, n, dflag);
  };
  cvt(d_in[0],  xb,   cNBS * cDIN);
  cvt(d_in[1],  WiB,  (long)cDIN * cE);
  cvt(d_in[2],  biC,  cE);
  cvt(d_in[3],  posb, (long)cS * cE);
  cvt(d_in[4],  WqB,  (long)cL * cE * cE);
  cvt(d_in[5],  bqC,  (long)cL * cE);
  cvt(d_in[6],  WkB,  (long)cL * cE * cE);
  cvt(d_in[7],  bkC,  (long)cL * cE);
  cvt(d_in[8],  WvB,  (long)cL * cE * cE);
  cvt(d_in[9],  bvC,  (long)cL * cE);
  cvt(d_in[10], WoB,  (long)cL * cE * cE);
  cvt(d_in[11], boC,  (long)cL * cE);
  cvt(d_in[12], RmB,  (long)cL * cE * cM);
  cvt(d_in[13], lngC, (long)cL * cE);
  cvt(d_in[14], lnbC, (long)cL * cE);
  cvt(d_in[15], W1B,  (long)cL * cE * cFF);
  cvt(d_in[16], b1C,  (long)cL * cFF);
  cvt(d_in[17], W2B,  (long)cL * cFF * cE);
  cvt(d_in[18], b2C,  (long)cL * cE);
  cvt(d_in[19], Wr1C, (long)cE * cHE);
  cvt(d_in[20], br1C, cHE);
  cvt(d_in[21], Wr2C, cHE);
  cvt(d_in[22], br2C, 1);

  typedef const unsigned short* cus;
  auto gemm = [&](const void* A, const void* Bt, const void* bias_,
                  const float* aux_, float* pmax_, void* C,
                  long rows, int K, int N, int lda, int ldb, float alpha, int flags,
                  long sA, long sB, long sC, int batches, const void* Res_ = nullptr) {
    dim3 g((unsigned)(rows / 128), (unsigned)(N / 128), (unsigned)batches);
    gemm_kernel<<<g, dim3(256), 0, stream>>>(
        (const unsigned short*)A, (const unsigned short*)Bt,
        (const unsigned short*)bias_, (const unsigned short*)Res_,
        aux_, pmax_, C, K, N, lda, ldb, alpha, flags, sA, sB, sC);
  };

  // ---- weight pre-transposes (BigB = [WvT | WkT | WqT] per layer) ----
  transpose_kernel<<<dim3(16, 2, 1), 256, 0, stream>>>(WiB, WiT, cDIN, cE, 0, 0);
  transpose_kernel<<<dim3(16, 16, cL), 256, 0, stream>>>(WvB, BigB, cE, cE, (long)cE * cE, (long)cNF * cE);
  transpose_kernel<<<dim3(16, 16, cL), 256, 0, stream>>>(WkB, BigB + (long)512 * cE, cE, cE, (long)cE * cE, (long)cNF * cE);
  transpose_kernel<<<dim3(16, 16, cL), 256, 0, stream>>>(WqB, BigB + (long)1024 * cE, cE, cE, (long)cE * cE, (long)cNF * cE);
  transpose_kernel<<<dim3(16, 16, cL), 256, 0, stream>>>(WoB, WoT, cE, cE, (long)cE * cE, (long)cE * cE);
  transpose_kernel<<<dim3(4, 16, cL), 256, 0, stream>>>(RmB, RT, cE, cM, (long)cE * cM, (long)cE * cM);
  transpose_kernel<<<dim3(64, 16, cL), 256, 0, stream>>>(W1B, W1T, cE, cFF, (long)cE * cFF, (long)cE * cFF);
  transpose_kernel<<<dim3(16, 64, cL), 256, 0, stream>>>(W2B, W2T, cFF, cE, (long)cFF * cE, (long)cFF * cE);

  // ---- fold R into Wq/Wk: BigL = [(Wq@R)^T | (Wk@R)^T] per layer ----
  gemm(RT, WqB, nullptr, nullptr, nullptr, BigL, cM, cE, cE, cE, cE, 1.f, 0,
       (long)cM * cE, (long)cE * cE, (long)256 * cE, cL);
  gemm(RT, WkB, nullptr, nullptr, nullptr, BigL + (long)128 * cE, cM, cE, cE, cE, cE, 1.f, 0,
       (long)cM * cE, (long)cE * cE, (long)256 * cE, cL);
  phibias_kernel<<<cL, 128, 0, stream>>>(bqC, RmB, bqkC, PSCALE, 256);
  phibias_kernel<<<cL, 128, 0, stream>>>(bkC, RmB, bqkC + 128, PSCALE, 256);
  packb_kernel<<<cL, 256, 0, stream>>>(bvC, bkC, bqC, b1536C);

  // ---- input projection + positional embedding ----
  gemm(xb, WiT, biC, nullptr, nullptr, h, cNBS, cDIN, cE, cDIN, cDIN, 1.f,
       FLAG_BIAS, 0, 0, 0, 1);
  addpos_kernel<<<16384, 256, 0, stream>>>(h, posb);

  for (int i = 0; i < cL; ++i) {
    cus WoT_i = WoT + (long)i * cE * cE;  cus bo_i = boC + (long)i * cE;
    cus BigB_i = BigB + (long)i * cNF * cE;
    cus BigL_i = BigL + (long)i * 256 * cE;
    cus b1536_i = b1536C + (long)i * cNF;
    cus bqk_i = bqkC + (long)i * 256;
    cus g_i   = lngC + (long)i * cE;      cus b_i  = lnbC + (long)i * cE;
    cus W1T_i = W1T + (long)i * cFF * cE; cus b1_i = b1C + (long)i * cFF;
    cus W2T_i = W2T + (long)i * cE * cFF; cus b2_i = b2C + (long)i * cE;

    // --- fused one pass over h: v^T (VT), ||k||^2 + ||q||^2 (RNORM atomics);
    //     XCD-swizzled so each h-panel is fetched by exactly one L2 ---
    zero4_kernel<<<128, 256, 0, stream>>>(rnorm2);
    gemm_kernel<<<dim3(12, 512, 1), dim3(256), 0, stream>>>(
        h, BigB_i, b1536_i, nullptr, nullptr, rnorm2, vtb,
        cE, cNF, cE, cE, 1.f, FLAG_FUSED | FLAG_SWZ, 0, 0, (long)cE * cS);

    // --- dual logits: q (by=0) and k (by=1), f32 + block maxes; XCD-swizzled ---
    gemm_kernel<<<dim3(2, 512, 1), dim3(256), 0, stream>>>(
        h, BigL_i, bqk_i, nullptr, rnorm2, partials, logfX,
        cE, 256, cE, cE, PSCALE, FLAG_PHIK | FLAG_BIAS | FLAG_SWZ, 0, 0, 0);

    reducemax2_kernel<<<1, 256, 0, stream>>>(partials, gmaxf);
    expq_kernel<<<8192, 256, 0, stream>>>(logfX, gmaxf, Pb);
    expT_kernel<<<dim3(4, 128, cB), 256, 0, stream>>>(logfX + cNBS * cM, gmaxf + 1, qtb);

    // --- z, den ---
    zsumt_kernel<<<dim3(cB, cM), 256, 0, stream>>>(qtb, z);
    den_kernel<<<16384, 256, 0, stream>>>(Pb, z, vec64k);

    // --- kv[b] (M x E) = pk^T[b] @ v^T[b]^T, split-K x8 in-cache atomics ---
    zero4_kernel<<<1024, 256, 0, stream>>>(kvacc);
    gemm(qtb, vtb, nullptr, nullptr, nullptr, kvacc, cM, cS / 8, cE, cS, cS, 1.f,
         FLAG_SPLITK8 | FLAG_ATOMIC, (long)cM * cS, (long)cE * cS, (long)cM * cE, cB * 8);
    kvcvt_kernel<<<1024, 256, 0, stream>>>(kvacc, kvtb);

    // --- fold Wo into kv: kvo^T[b] (E x M) = WoT @ kv[b]^T  (tiny, 64 blocks) ---
    gemm(WoT_i, kvtb, nullptr, nullptr, nullptr, kvotb, cE, cE, cM, cE, cE, 1.f,
         0, 0, (long)cM * cE, (long)cE * cM, cB);

    // --- a[b] = (pq[b] @ kvo[b]) / (den+1e-6) + bo -> Y ; LN in place ---
    gemm(Pb, kvotb, bo_i, vec64k, nullptr, ab, cS, cM, cE, cM, cM, 1.f,
         FLAG_DEN | FLAG_BIAS, (long)cS * cM, (long)cE * cM, (long)cS * cE, cB);
    ln_kernel<<<cNBS, 256, 0, stream>>>(ab, g_i, b_i);

    // --- FFN in 4 row-chunks of 16384; h += ffn(y); XCD-swizzled ---
    for (int c = 0; c < 4; ++c) {
      const unsigned short* yc = ab + (long)c * 16384 * cE;
      unsigned short* hc = h + (long)c * 16384 * cE;
      gemm_kernel<<<dim3(16, 128, 1), dim3(256), 0, stream>>>(
          yc, W1T_i, b1_i, nullptr, nullptr, nullptr, u1b,
          cE, cFF, cE, cE, 1.f, FLAG_BIAS | FLAG_GELU | FLAG_SWZ, 0, 0, 0);
      gemm_kernel<<<dim3(4, 128, 1), dim3(256), 0, stream>>>(
          u1b, W2T_i, b2_i, hc, nullptr, nullptr, hc,
          cFF, cE, cFF, cFF, 1.f, FLAG_BIAS | FLAG_RES | FLAG_SWZ, 0, 0, 0);
    }
  }

  head_kernel<<<cB, 256, 0, stream>>>(h, Wr1C, br1C, Wr2C, br2C, d_out, dflag);
}

// Round 10
// 3972.493 us; speedup vs baseline: 1.1643x; 1.0151x over previous
//
#include <hip/hip_runtime.h>
#include <math.h>

// ---------------- problem constants ----------------
static constexpr int  cB   = 16;
static constexpr int  cS   = 4096;
static constexpr int  cDIN = 64;
static constexpr int  cE   = 512;
static constexpr int  cM   = 128;
static constexpr int  cL   = 4;
static constexpr int  cFF  = 2048;   // 4*E
static constexpr int  cHE  = 256;    // E/2
static constexpr long cNBS = (long)cB * cS;   // 65536 rows
static constexpr int  cNF  = 1536;   // fused N = 512(v) + 512(k-norm) + 512(q-norm)

typedef __attribute__((ext_vector_type(8))) short  bf16x8;
typedef __attribute__((ext_vector_type(4))) short  bf16x4;
typedef __attribute__((ext_vector_type(4))) float  f32x4;

typedef const __attribute__((address_space(1))) unsigned int g_u32;
typedef __attribute__((address_space(3))) unsigned int l_u32;

__device__ __forceinline__ float b2f(unsigned short u) {
  union { unsigned int i; float f; } x; x.i = ((unsigned int)u) << 16; return x.f;
}
__device__ __forceinline__ unsigned short f2b(float f) {
  union { float f; unsigned int i; } x; x.f = f;
  unsigned int r = x.i + 0x7FFFu + ((x.i >> 16) & 1u);   // RNE
  return (unsigned short)(r >> 16);
}

// phi math (round-6 post-mortem): max-shift and q-row-norm do NOT cancel out
// of num/(den+1e-6); faithful computation kept (round-7: absmax 0.0078).
#define PSCALE 0.21022410381342863f     // 512^-0.25
#define PNRM   0.022097086912079608f    // 0.5 * PSCALE^2
#define PINV   0.08838834764831845f     // 1/sqrt(M)

// ---------------- GEMM: C[rows x N] = f(alpha*A@Bt^T + bias) -------------
// A: rows x K bf16 (row stride lda). Bt: N x K bf16 (row stride ldb).
#define FLAG_BIAS    2
#define FLAG_GELU    4
#define FLAG_RES     8     // += bf16 Res[idx]
#define FLAG_VT      16    // store transposed per 4096-row batch, batch stride sC
#define FLAG_DEN     32    // v = acc/(aux[zb*rowsPerBatch+rr]+1e-6) BEFORE bias
#define FLAG_RNORM   64    // no C store; atomicAdd row-norms of (acc+bias) into pmax[rnoff+row]
#define FLAG_PHIK    128   // dual q/k logits: by=0 q (aux+cNBS), by=1 k (aux+0);
                           // l = PSCALE*acc + bias - PNRM*aux; f32 out + block max
#define FLAG_F32OUT  256   // store f32
#define FLAG_SPLITK8 512   // blockIdx.z = batch*8 + k-chunk
#define FLAG_ATOMIC  1024  // f32 atomicAdd into C (indexed by batch zb)
#define FLAG_FUSED   2048  // (with SWZ, grid (12,512)): by<4 VT(v), by<8 RNORM(k), by<12 RNORM(q)
#define FLAG_SWZ     4096  // grid (NBcols, nbx): XCD-aware remap so all column-blocks
                           // sharing an A-row-panel land on ONE XCD's L2 (round-9:
                           // FETCH 269.6 -> 41.5 MB on the FUSED dispatch)

#define GMT 128
#define GNT 128
#define GBK 32

// round-9 post-mortem: FUSED dispatch is NOT HBM-bound (9.9% peak) -- the cost
// is 13.1M LDS bank-conflict cycles (8-way: 16 rows x 64B stride = 2 bank-quads).
// Fix (rule #21, both-sides-or-neither): keep LDS dest linear for global_load_lds,
// XOR the 16B-chunk index by (row&3) on the GLOBAL SOURCE and on the READ.
// 8-way -> 4-way (m136: 2.94x -> 1.58x). Bit-exact (pure permutation).

__global__ __launch_bounds__(256, 2)
void gemm_kernel(const unsigned short* __restrict__ A,
                 const unsigned short* __restrict__ Bt,
                 const unsigned short* __restrict__ bias,
                 const unsigned short* __restrict__ Res,
                 const float* __restrict__ aux,
                 float* __restrict__ pmax,
                 void* __restrict__ C,
                 int K, int N, int lda, int ldb, float alpha, int flags,
                 long sA, long sB, long sC)
{
  // 18 KB shared: As(8K)+Bs(8K) during K-loop; stage aliases them post-loop (VT).
  __shared__ __align__(16) unsigned char sraw[18048];
  unsigned short (*As)[32] = (unsigned short (*)[32])sraw;
  unsigned short (*Bs)[32] = (unsigned short (*)[32])(sraw + 8192);
  unsigned short (*stage)[136] = (unsigned short (*)[136])sraw;   // VT post-loop (17408 B)
  float* wred  = (float*)(sraw + 17472);                          // PHIK block max (16 B)

  const int tid  = threadIdx.x;
  const int lane = tid & 63;
  const int wid  = tid >> 6;

  int bx = blockIdx.x, by = blockIdx.y;
  if (flags & FLAG_SWZ) {
    // lid%8 = XCD (observed round-robin); give each XCD a contiguous bx range,
    // iterate by fastest within it -> A-panel read by exactly one L2.
    const unsigned lid  = blockIdx.x + gridDim.x * blockIdx.y;
    const unsigned xcd  = lid & 7u;
    const unsigned slot = lid >> 3;
    bx = (int)(xcd * (gridDim.y >> 3) + slot / gridDim.x);
    by = (int)(slot % gridDim.x);
  }

  long zb = blockIdx.z;            // batch index (for A/B/aux)
  const long zc = blockIdx.z;      // C-store base index (keeps k-chunk for split-K)
  int koff = 0;
  if (flags & FLAG_SPLITK8) { koff = (int)(zb & 7) * K; zb >>= 3; }

  const unsigned short* Ab = A + zb * sA + (long)bx * GMT * lda + koff;
  const unsigned short* Bb = Bt + zb * sB + (long)by * GNT * ldb + koff;

  // async staging: lane's LDS dest = tile_base + wid*1024 + lane*16 (contiguous,
  // LINEAR -- required by global_load_lds). Global source chunk is XOR-swizzled.
  const int srow  = wid * 16 + (lane >> 2);                 // 0..63
  const int scolL = (lane & 3) << 3;                        // linear LDS chunk
  const int scolG = ((lane & 3) ^ (srow & 3)) << 3;         // swizzled global chunk
  const unsigned short* gA = Ab + (long)srow * lda + scolG;
  const unsigned short* gB = Bb + (long)srow * ldb + scolG;
  l_u32* lA0 = (l_u32*)&As[srow][scolL];
  l_u32* lA1 = (l_u32*)&As[srow + 64][scolL];
  l_u32* lB0 = (l_u32*)&Bs[srow][scolL];
  l_u32* lB1 = (l_u32*)&Bs[srow + 64][scolL];

  const f32x4 fzero = {0.f, 0.f, 0.f, 0.f};
  f32x4 acc[4][4];
#pragma unroll
  for (int i = 0; i < 4; ++i)
#pragma unroll
    for (int j = 0; j < 4; ++j) acc[i][j] = fzero;

  const int wm = (wid >> 1) << 6;
  const int wn = (wid & 1) << 6;
  const int fm = lane & 15;
  const int kq = (lane >> 4) << 3;
  // swizzled read offset: LDS chunk = (global chunk) ^ (row&3); row&3 == fm&3
  // for every fragment row this lane touches (wm, wn, i*16 are multiples of 4).
  const int kqs = (((kq >> 3) ^ (fm & 3)) << 3);

  const long ka64 = (long)64 * lda, kb64 = (long)64 * ldb;
  for (int k0 = 0; k0 < K; k0 += GBK) {
    __builtin_amdgcn_global_load_lds((g_u32*)(gA + k0),        lA0, 16, 0, 0);
    __builtin_amdgcn_global_load_lds((g_u32*)(gA + ka64 + k0), lA1, 16, 0, 0);
    __builtin_amdgcn_global_load_lds((g_u32*)(gB + k0),        lB0, 16, 0, 0);
    __builtin_amdgcn_global_load_lds((g_u32*)(gB + kb64 + k0), lB1, 16, 0, 0);
    __syncthreads();

    bf16x8 af[4], bfv[4];
#pragma unroll
    for (int i = 0; i < 4; ++i) {
      af[i]  = *(const bf16x8*)&As[wm + i * 16 + fm][kqs];
      bfv[i] = *(const bf16x8*)&Bs[wn + i * 16 + fm][kqs];
    }
#pragma unroll
    for (int i = 0; i < 4; ++i)
#pragma unroll
      for (int j = 0; j < 4; ++j)
        acc[i][j] = __builtin_amdgcn_mfma_f32_16x16x32_bf16(af[i], bfv[j], acc[i][j], 0, 0, 0);
    __syncthreads();
  }

  // epilogue: C/D layout col=lane&15, row=(lane>>4)*4+reg  [verified m89/m91]
  const int rq = (lane >> 4) << 2;
  const long crow0 = (long)bx * GMT + wm;
  const int  ccol0 = by * GNT + wn;

  long rnoff = 0;
  if (flags & FLAG_FUSED) {
    if (by < 4) flags = FLAG_BIAS | FLAG_VT;
    else { flags = FLAG_BIAS | FLAG_RNORM; if (by >= 8) rnoff = cNBS; }
  }

  if (flags & FLAG_RNORM) {
    // row-norm of (acc*alpha + bias): reduce over this wave's 64 cols, atomic-add.
#pragma unroll
    for (int i = 0; i < 4; ++i)
#pragma unroll
      for (int r = 0; r < 4; ++r) {
        float s = 0.f;
#pragma unroll
        for (int j = 0; j < 4; ++j) {
          float v = acc[i][j][r] * alpha + b2f(bias[ccol0 + j * 16 + fm]);
          s += v * v;
        }
        s += __shfl_xor(s, 1, 64);
        s += __shfl_xor(s, 2, 64);
        s += __shfl_xor(s, 4, 64);
        s += __shfl_xor(s, 8, 64);
        if (fm == 0)
          unsafeAtomicAdd(&pmax[rnoff + crow0 + i * 16 + rq + r], s);
      }
    return;
  }

  if (flags & FLAG_PHIK) {
    // dual q/k phi logits (grid (2,512)+SWZ): by=0 q (aux offset cNBS), by=1 k.
    // l = PSCALE*acc + bias - PNRM*aux[row]; f32 out + block max to pmax[by*512+bx].
    const long aoff = (by == 0) ? cNBS : 0;
    float* Cf = (float*)C + (long)by * (cNBS * (long)cM);
    float mx = -3.0e38f;
#pragma unroll
    for (int i = 0; i < 4; ++i)
#pragma unroll
      for (int r = 0; r < 4; ++r) {
        const long rr = crow0 + i * 16 + rq + r;
        const float nrm = PNRM * aux[aoff + rr];
#pragma unroll
        for (int j = 0; j < 4; ++j) {
          const int cc = ccol0 + j * 16 + fm;
          const float bv = b2f(bias[cc]);
          float l = acc[i][j][r] * PSCALE + bv - nrm;
          mx = fmaxf(mx, l);
          Cf[rr * (long)cM + (cc & (cM - 1))] = l;
        }
      }
#pragma unroll
    for (int off = 32; off >= 1; off >>= 1) mx = fmaxf(mx, __shfl_down(mx, off, 64));
    if (lane == 0) wred[wid] = mx;
    __syncthreads();
    if (tid == 0)
      pmax[by * 512 + bx] = fmaxf(fmaxf(wred[0], wred[1]), fmaxf(wred[2], wred[3]));
    return;
  }

  if (flags & FLAG_ATOMIC) {
    // split-K reduction in-cache: f32 atomic add into C[zb]
    float* Cf = (float*)C + zb * sC;
#pragma unroll
    for (int j = 0; j < 4; ++j) {
      const int cc = ccol0 + j * 16 + fm;
#pragma unroll
      for (int i = 0; i < 4; ++i)
#pragma unroll
        for (int r = 0; r < 4; ++r) {
          const long rr = crow0 + i * 16 + rq + r;
          unsafeAtomicAdd(&Cf[rr * (long)N + cc], acc[i][j][r] * alpha);
        }
    }
    return;
  }

  if (flags & FLAG_VT) {
    // stage 64 cols x 128 rows in LDS, then coalesced column stores (64B/thread)
    unsigned short* Cb = (unsigned short*)C;
    const int bb = (bx * GMT) >> 12;
    const long sbase = (long)((bx * GMT) & (cS - 1));
#pragma unroll
    for (int rnd = 0; rnd < 2; ++rnd) {
      if ((wn >> 6) == rnd) {
#pragma unroll
        for (int j = 0; j < 4; ++j) {
          const int cc = ccol0 + j * 16 + fm;
          const float bv = (flags & FLAG_BIAS) ? b2f(bias[cc]) : 0.f;
          const int cl = j * 16 + fm;
#pragma unroll
          for (int i = 0; i < 4; ++i)
#pragma unroll
            for (int r = 0; r < 4; ++r)
              stage[cl][wm + i * 16 + rq + r] = f2b(acc[i][j][r] * alpha + bv);
        }
      }
      __syncthreads();
      {
        const int cl = tid >> 2;
        const int sseg = (tid & 3) << 5;
        const int gcol = by * GNT + rnd * 64 + cl;
        unsigned short* dst = Cb + (long)bb * sC + (long)gcol * cS + sbase + sseg;
#pragma unroll
        for (int t = 0; t < 4; ++t)
          *(bf16x8*)(dst + t * 8) = *(const bf16x8*)&stage[cl][sseg + t * 8];
      }
      __syncthreads();
    }
    return;
  }

  // generic epilogue. Order: acc -> DEN -> +bias -> GELU -> RES (DEN before bias
  // so att = (pq@kvo)/den + bo works; plain BIAS/GELU paths unaffected).
  const long rowsPerBatch = (long)gridDim.x * GMT;
#pragma unroll
  for (int j = 0; j < 4; ++j) {
    const int cc = ccol0 + j * 16 + fm;
    const float bv = (flags & FLAG_BIAS) ? b2f(bias[cc]) : 0.f;
#pragma unroll
    for (int i = 0; i < 4; ++i) {
      const long rbase = crow0 + i * 16 + rq;
#pragma unroll
      for (int r = 0; r < 4; ++r) {
        const long rr = rbase + r;
        float v = acc[i][j][r] * alpha;
        if (flags & FLAG_DEN)
          v *= 1.f / (fmaxf(aux[zb * rowsPerBatch + rr], 0.f) + 1e-6f);
        v += bv;
        if (flags & FLAG_GELU) v = 0.5f * v * (1.f + erff(v * 0.7071067811865475f));
        const long idx = zc * sC + rr * (long)N + cc;
        if (flags & FLAG_RES) v += b2f(Res[idx]);
        if (flags & FLAG_F32OUT) ((float*)C)[idx] = v;
        else                     ((unsigned short*)C)[idx] = f2b(v);
      }
    }
  }
}

// ---------------- dtype shim ----------------
__global__ void detect_kernel(const unsigned short* __restrict__ lng,
                              int* __restrict__ flag) {
  if (threadIdx.x == 0 && blockIdx.x == 0) flag[0] = (lng[0] == 0) ? 1 : 0;
}

__global__ __launch_bounds__(256) void cvt_kernel(const void* __restrict__ in,
                                                  unsigned short* __restrict__ out,
                                                  long n, const int* __restrict__ flag) {
  long i = (long)blockIdx.x * 256 + threadIdx.x;
  if (i >= n) return;
  if (flag[0]) out[i] = f2b(((const float*)in)[i]);
  else         out[i] = ((const unsigned short*)in)[i];
}

// ---------------- small kernels ----------------
__global__ __launch_bounds__(256) void zero4_kernel(float* __restrict__ p) {
  long i = ((long)blockIdx.x * 256 + threadIdx.x) * 4;
  f32x4 z = {0.f, 0.f, 0.f, 0.f};
  *(f32x4*)&p[i] = z;
}

__global__ __launch_bounds__(256) void addpos_kernel(unsigned short* __restrict__ h,
                                                     const unsigned short* __restrict__ pos) {
  long i = ((long)blockIdx.x * 256 + threadIdx.x) * 8;
  long se = i % ((long)cS * cE);
  bf16x8 v = *(bf16x8*)&h[i];
  bf16x8 p = *(const bf16x8*)&pos[se];
#pragma unroll
  for (int r = 0; r < 8; ++r)
    v[r] = (short)f2b(b2f((unsigned short)v[r]) + b2f((unsigned short)p[r]));
  *(bf16x8*)&h[i] = v;
}

// gmax[0]=max(partials[0..512)) (q), gmax[1]=max(partials[512..1024)) (k)
__global__ __launch_bounds__(256) void reducemax2_kernel(const float* __restrict__ partials,
                                                         float* __restrict__ gmax) {
  __shared__ float sm[8];
  const int tid = threadIdx.x;
  for (int half = 0; half < 2; ++half) {
    float mx = -3.0e38f;
    for (int i = tid; i < 512; i += 256) mx = fmaxf(mx, partials[half * 512 + i]);
#pragma unroll
    for (int off = 32; off >= 1; off >>= 1) mx = fmaxf(mx, __shfl_down(mx, off, 64));
    if ((tid & 63) == 0) sm[(half << 2) + (tid >> 6)] = mx;
  }
  __syncthreads();
  if (tid == 0) gmax[0] = fmaxf(fmaxf(sm[0], sm[1]), fmaxf(sm[2], sm[3]));
  if (tid == 1) gmax[1] = fmaxf(fmaxf(sm[4], sm[5]), fmaxf(sm[6], sm[7]));
}

// elementwise exp (row-major): P = bf16(exp(lf - gm)/sqrt(M))
__global__ __launch_bounds__(256) void expq_kernel(const float* __restrict__ lf,
                                                   const float* __restrict__ gmx,
                                                   unsigned short* __restrict__ P) {
  long i = ((long)blockIdx.x * 256 + threadIdx.x) * 4;
  const float gm = gmx[0];
  f32x4 v = *(const f32x4*)&lf[i];
  bf16x4 o;
#pragma unroll
  for (int r = 0; r < 4; ++r)
    o[r] = (short)f2b(__expf(fminf(v[r] - gm, 0.f)) * PINV);
  *(bf16x4*)&P[i] = o;
}

// fused exp + transpose: lf (B x S x M f32 logits) -> out (B x M x S bf16 phi)
__global__ __launch_bounds__(256) void expT_kernel(const float* __restrict__ lf,
                                                   const float* __restrict__ gmx,
                                                   unsigned short* __restrict__ out) {
  __shared__ unsigned short t[32][33];
  const int b = blockIdx.z;
  const float gm = gmx[0];
  const int bx = blockIdx.x << 5, by = blockIdx.y << 5;   // bx: M, by: S
  const int tx = threadIdx.x & 31, ty = threadIdx.x >> 5;
  const float* src = lf + (long)b * cS * cM;
  unsigned short* dst = out + (long)b * cM * cS;
#pragma unroll
  for (int i = ty; i < 32; i += 8) {
    float l = src[(long)(by + i) * cM + bx + tx];
    t[i][tx] = f2b(__expf(fminf(l - gm, 0.f)) * PINV);
  }
  __syncthreads();
#pragma unroll
  for (int i = ty; i < 32; i += 8)
    dst[(long)(bx + i) * cS + by + tx] = t[tx][i];
}

// kv f32 accumulators -> bf16
__global__ __launch_bounds__(256) void kvcvt_kernel(const float* __restrict__ kvacc,
                                                    unsigned short* __restrict__ kvtb) {
  long i = ((long)blockIdx.x * 256 + threadIdx.x) * 4;
  f32x4 v = *(const f32x4*)&kvacc[i];
  bf16x4 o;
#pragma unroll
  for (int r = 0; r < 4; ++r) o[r] = (short)f2b(v[r]);
  *(bf16x4*)&kvtb[i] = o;
}

// out[l*ldo + m] = scale * sum_e bq[l][e] * R[l][e][m]   (tiny, pre-loop)
__global__ __launch_bounds__(128) void phibias_kernel(const unsigned short* __restrict__ bq,
                                                      const unsigned short* __restrict__ R,
                                                      unsigned short* __restrict__ out,
                                                      float scale, int ldo) {
  const int l = blockIdx.x, m = threadIdx.x;
  const unsigned short* b = bq + (long)l * cE;
  const unsigned short* r = R + (long)l * cE * cM;
  float a = 0.f;
  for (int e = 0; e < cE; ++e) a += b2f(b[e]) * b2f(r[(long)e * cM + m]);
  out[(long)l * ldo + m] = f2b(a * scale);
}

// packed bias for fused GEMM: [bv(512) | bk(512) | bq(512)] per layer
__global__ __launch_bounds__(256) void packb_kernel(const unsigned short* __restrict__ bv,
                                                    const unsigned short* __restrict__ bk,
                                                    const unsigned short* __restrict__ bq,
                                                    unsigned short* __restrict__ out) {
  const int l = blockIdx.x, t = threadIdx.x;
#pragma unroll
  for (int s = 0; s < 512; s += 256) {
    out[l * cNF + s + t]        = bv[l * 512 + s + t];
    out[l * cNF + 512 + s + t]  = bk[l * 512 + s + t];
    out[l * cNF + 1024 + s + t] = bq[l * 512 + s + t];
  }
}

// z[b][m] = sum_s qtb[b][m][s]   (qtb is B x M x S)
__global__ __launch_bounds__(256) void zsumt_kernel(const unsigned short* __restrict__ qtb,
                                                    float* __restrict__ z) {
  __shared__ float sred[4];
  const int b = blockIdx.x, m = blockIdx.y, tid = threadIdx.x;
  const unsigned short* p = qtb + ((long)b * cM + m) * cS + (long)tid * 16;
  bf16x8 a = *(const bf16x8*)p;
  bf16x8 c = *(const bf16x8*)(p + 8);
  float s = 0.f;
#pragma unroll
  for (int t = 0; t < 8; ++t) s += b2f((unsigned short)a[t]) + b2f((unsigned short)c[t]);
#pragma unroll
  for (int off = 32; off >= 1; off >>= 1) s += __shfl_down(s, off, 64);
  const int w = tid >> 6, lane = tid & 63;
  if (lane == 0) sred[w] = s;
  __syncthreads();
  if (tid == 0) z[b * cM + m] = sred[0] + sred[1] + sred[2] + sred[3];
}

// den[row] = dot(pq[row,:], z[b,:]); 4 rows/block
__global__ __launch_bounds__(256) void den_kernel(const unsigned short* __restrict__ P,
                                                  const float* __restrict__ z,
                                                  float* __restrict__ den) {
  const int w = threadIdx.x >> 6, lane = threadIdx.x & 63;
  const long row = (long)blockIdx.x * 4 + w;
  const float* zb = z + (row >> 12) * cM;
  const unsigned short* p = P + row * cM;
  float d = b2f(p[lane]) * zb[lane] + b2f(p[lane + 64]) * zb[lane + 64];
#pragma unroll
  for (int off = 32; off >= 1; off >>= 1) d += __shfl_down(d, off, 64);
  if (lane == 0) den[row] = d;
}

// layernorm in place (bf16 -> bf16), one row per block
__global__ __launch_bounds__(256) void ln_kernel(unsigned short* __restrict__ a,
                                                 const unsigned short* __restrict__ g,
                                                 const unsigned short* __restrict__ bb) {
  __shared__ float sred[8];
  const long row = blockIdx.x;
  unsigned short* ar = a + row * cE;
  const int tid = threadIdx.x;
  float v0 = b2f(ar[tid]), v1 = b2f(ar[tid + 256]);
  float s = v0 + v1, sq = v0 * v0 + v1 * v1;
#pragma unroll
  for (int off = 32; off >= 1; off >>= 1) {
    s  += __shfl_down(s, off, 64);
    sq += __shfl_down(sq, off, 64);
  }
  const int w = tid >> 6, lane = tid & 63;
  if (lane == 0) { sred[w] = s; sred[4 + w] = sq; }
  __syncthreads();
  const float st  = sred[0] + sred[1] + sred[2] + sred[3];
  const float sqt = sred[4] + sred[5] + sred[6] + sred[7];
  const float mean = st * (1.f / 512.f);
  const float var  = fmaxf(sqt * (1.f / 512.f) - mean * mean, 0.f);
  const float rstd = rsqrtf(var + 1e-5f);
  ar[tid]       = f2b((v0 - mean) * rstd * b2f(g[tid])       + b2f(bb[tid]));
  ar[tid + 256] = f2b((v1 - mean) * rstd * b2f(g[tid + 256]) + b2f(bb[tid + 256]));
}

// batched bf16 transpose: in (R x C) -> out (C x R); grid (C/32, R/32, batch)
__global__ __launch_bounds__(256) void transpose_kernel(const unsigned short* __restrict__ in,
                                                        unsigned short* __restrict__ out,
                                                        int R, int C, long sIn, long sOut) {
  __shared__ unsigned short t[32][33];
  in  += (long)blockIdx.z * sIn;
  out += (long)blockIdx.z * sOut;
  const int bx = blockIdx.x << 5, by = blockIdx.y << 5;
  const int tx = threadIdx.x & 31, ty = threadIdx.x >> 5;
#pragma unroll
  for (int i = ty; i < 32; i += 8) t[i][tx] = in[(long)(by + i) * C + bx + tx];
  __syncthreads();
#pragma unroll
  for (int i = ty; i < 32; i += 8) out[(long)(bx + i) * R + by + tx] = t[tx][i];
}

// final head
__global__ __launch_bounds__(256) void head_kernel(const unsigned short* __restrict__ h,
                                                   const unsigned short* __restrict__ Wr1,
                                                   const unsigned short* __restrict__ br1,
                                                   const unsigned short* __restrict__ Wr2,
                                                   const unsigned short* __restrict__ br2,
                                                   void* __restrict__ out,
                                                   const int* __restrict__ flag) {
  __shared__ float pooled[cE];
  __shared__ float red[4];
  const int b = blockIdx.x, tid = threadIdx.x;
  pooled[tid]       = b2f(h[(long)b * cS * cE + tid]);
  pooled[tid + 256] = b2f(h[(long)b * cS * cE + tid + 256]);
  __syncthreads();
  float acc = b2f(br1[tid]);
  for (int e = 0; e < cE; ++e) acc += pooled[e] * b2f(Wr1[e * cHE + tid]);
  acc = fmaxf(acc, 0.f) * b2f(Wr2[tid]);
#pragma unroll
  for (int off = 32; off >= 1; off >>= 1) acc += __shfl_down(acc, off, 64);
  const int w = tid >> 6, lane = tid & 63;
  if (lane == 0) red[w] = acc;
  __syncthreads();
  if (tid == 0) {
    float r = red[0] + red[1] + red[2] + red[3] + b2f(br2[0]);
    if (flag[0]) ((float*)out)[b] = r;
    else         ((unsigned short*)out)[b] = f2b(r);
  }
}

// ---------------- host ----------------
extern "C" void kernel_launch(void* const* d_in, const int* in_sizes, int n_in,
                              void* d_out, int out_size, void* d_ws, size_t ws_size,
                              hipStream_t stream) {
  (void)in_sizes; (void)n_in; (void)out_size;

  char* ws = (char*)d_ws;
  size_t off = 0;
  auto alloc = [&](size_t bytes) -> void* {
    void* p = ws + off;
    off += (bytes + 255) & ~(size_t)255;
    return p;
  };
  // ---- memory plan ----
  unsigned short* h   = (unsigned short*)alloc(cNBS * cE * 2);   // 67 MB residual
  unsigned short* X   = (unsigned short*)alloc(cNBS * cE * 2);   // 67 MB multi-use
  unsigned short* Y   = (unsigned short*)alloc(cNBS * cE * 2);   // 67 MB multi-use
  unsigned short* Pb  = (unsigned short*)alloc(cNBS * cM * 2);   // 16.8 MB phi(q)
  unsigned short* kvtb= (unsigned short*)alloc((long)cB * cM * cE * 2); // 2.1 MB kv (M x E)
  unsigned short* kvotb=(unsigned short*)alloc((long)cB * cE * cM * 2); // 2.1 MB (kv@Wo)^T
  float* kvacc        = (float*)alloc((long)cB * cM * cE * 4);   // 4 MB f32 kv acc
  float* vec64k       = (float*)alloc(cNBS * 4);                 // den
  float* rnorm2       = (float*)alloc(2 * cNBS * 4);             // 512 KB: [k | q] row-norms
  float* z            = (float*)alloc(cB * cM * 4);
  float* partials     = (float*)alloc(1024 * 4);                 // [q 512 | k 512] block maxes
  float* gmaxf        = (float*)alloc(256);                      // gmax[0]=q, gmax[1]=k
  int*   dflag        = (int*)alloc(256);
  unsigned short* WiT = (unsigned short*)alloc((long)cE * cDIN * 2);
  unsigned short* BigB= (unsigned short*)alloc((long)cL * cNF * cE * 2); // 6.3 MB [WvT|WkT|WqT]
  unsigned short* BigL= (unsigned short*)alloc((long)cL * 256 * cE * 2); // 1 MB [WqRT|WkRT]
  unsigned short* WoT = (unsigned short*)alloc((long)cL * cE * cE * 2);
  unsigned short* RT  = (unsigned short*)alloc((long)cL * cM * cE * 2);
  unsigned short* W1T = (unsigned short*)alloc((long)cL * cFF * cE * 2);
  unsigned short* W2T = (unsigned short*)alloc((long)cL * cE * cFF * 2);
  unsigned short* sb  = (unsigned short*)alloc(170000 * 2);

  // weight staging inside X (dead until first in-loop X use)
  unsigned short* WqB = X;
  unsigned short* WkB = WqB + (long)cL * cE * cE;
  unsigned short* WvB = WkB + (long)cL * cE * cE;
  unsigned short* WoB = WvB + (long)cL * cE * cE;
  unsigned short* RmB = WoB + (long)cL * cE * cE;
  unsigned short* W1B = RmB + (long)cL * cE * cM;
  unsigned short* W2B = W1B + (long)cL * cE * cFF;
  unsigned short* WiB = W2B + (long)cL * cE * cFF;
  // x, pos staging inside Y
  unsigned short* xb   = Y;
  unsigned short* posb = Y + cNBS * cDIN;
  // small tensors inside sb
  unsigned short* biC  = sb;
  unsigned short* bqC  = biC  + 512;
  unsigned short* bkC  = bqC  + 2048;
  unsigned short* bvC  = bkC  + 2048;
  unsigned short* boC  = bvC  + 2048;
  unsigned short* b1C  = boC  + 2048;
  unsigned short* b2C  = b1C  + 8192;
  unsigned short* lngC = b2C  + 2048;
  unsigned short* lnbC = lngC + 2048;
  unsigned short* Wr1C = lnbC + 2048;
  unsigned short* br1C = Wr1C + 131072;
  unsigned short* Wr2C = br1C + 256;
  unsigned short* br2C = Wr2C + 256;
  unsigned short* bqkC  = br2C + 16;            // [scale*(bq@R) | scale*(bk@R)], L x 256
  unsigned short* b1536C = bqkC + cL * 256;     // packed fused bias, L x 1536

  unsigned short* qtb  = X;                       // pk^T (B x M x S), 16.8 MB
  float* logfX         = (float*)X;               // [logf_q | logf_k] f32, 67 MB
  unsigned short* vtb  = Y;                       // v^T (B x E x S)
  unsigned short* ab   = Y;                       // a / y (LN in place)
  unsigned short* u1b  = X;                       // FFN hidden chunk (16384 x 2048)

  if (off > ws_size) return;

  // ---- dtype detect + convert all inputs to bf16 ----
  detect_kernel<<<1, 64, 0, stream>>>((const unsigned short*)d_in[13], dflag);
  auto cvt = [&](const void* src, unsigned short* dst, long n) {
    cvt_kernel<<<(unsigned)((n + 255) / 256), 256, 0, stream>>>(src, dst, n, dflag);
  };
  cvt(d_in[0],  xb,   cNBS * cDIN);
  cvt(d_in[1],  WiB,  (long)cDIN * cE);
  cvt(d_in[2],  biC,  cE);
  cvt(d_in[3],  posb, (long)cS * cE);
  cvt(d_in[4],  WqB,  (long)cL * cE * cE);
  cvt(d_in[5],  bqC,  (long)cL * cE);
  cvt(d_in[6],  WkB,  (long)cL * cE * cE);
  cvt(d_in[7],  bkC,  (long)cL * cE);
  cvt(d_in[8],  WvB,  (long)cL * cE * cE);
  cvt(d_in[9],  bvC,  (long)cL * cE);
  cvt(d_in[10], WoB,  (long)cL * cE * cE);
  cvt(d_in[11], boC,  (long)cL * cE);
  cvt(d_in[12], RmB,  (long)cL * cE * cM);
  cvt(d_in[13], lngC, (long)cL * cE);
  cvt(d_in[14], lnbC, (long)cL * cE);
  cvt(d_in[15], W1B,  (long)cL * cE * cFF);
  cvt(d_in[16], b1C,  (long)cL * cFF);
  cvt(d_in[17], W2B,  (long)cL * cFF * cE);
  cvt(d_in[18], b2C,  (long)cL * cE);
  cvt(d_in[19], Wr1C, (long)cE * cHE);
  cvt(d_in[20], br1C, cHE);
  cvt(d_in[21], Wr2C, cHE);
  cvt(d_in[22], br2C, 1);

  typedef const unsigned short* cus;
  auto gemm = [&](const void* A, const void* Bt, const void* bias_,
                  const float* aux_, float* pmax_, void* C,
                  long rows, int K, int N, int lda, int ldb, float alpha, int flags,
                  long sA, long sB, long sC, int batches, const void* Res_ = nullptr) {
    dim3 g((unsigned)(rows / 128), (unsigned)(N / 128), (unsigned)batches);
    gemm_kernel<<<g, dim3(256), 0, stream>>>(
        (const unsigned short*)A, (const unsigned short*)Bt,
        (const unsigned short*)bias_, (const unsigned short*)Res_,
        aux_, pmax_, C, K, N, lda, ldb, alpha, flags, sA, sB, sC);
  };

  // ---- weight pre-transposes (BigB = [WvT | WkT | WqT] per layer) ----
  transpose_kernel<<<dim3(16, 2, 1), 256, 0, stream>>>(WiB, WiT, cDIN, cE, 0, 0);
  transpose_kernel<<<dim3(16, 16, cL), 256, 0, stream>>>(WvB, BigB, cE, cE, (long)cE * cE, (long)cNF * cE);
  transpose_kernel<<<dim3(16, 16, cL), 256, 0, stream>>>(WkB, BigB + (long)512 * cE, cE, cE, (long)cE * cE, (long)cNF * cE);
  transpose_kernel<<<dim3(16, 16, cL), 256, 0, stream>>>(WqB, BigB + (long)1024 * cE, cE, cE, (long)cE * cE, (long)cNF * cE);
  transpose_kernel<<<dim3(16, 16, cL), 256, 0, stream>>>(WoB, WoT, cE, cE, (long)cE * cE, (long)cE * cE);
  transpose_kernel<<<dim3(4, 16, cL), 256, 0, stream>>>(RmB, RT, cE, cM, (long)cE * cM, (long)cE * cM);
  transpose_kernel<<<dim3(64, 16, cL), 256, 0, stream>>>(W1B, W1T, cE, cFF, (long)cE * cFF, (long)cE * cFF);
  transpose_kernel<<<dim3(16, 64, cL), 256, 0, stream>>>(W2B, W2T, cFF, cE, (long)cFF * cE, (long)cFF * cE);

  // ---- fold R into Wq/Wk: BigL = [(Wq@R)^T | (Wk@R)^T] per layer ----
  gemm(RT, WqB, nullptr, nullptr, nullptr, BigL, cM, cE, cE, cE, cE, 1.f, 0,
       (long)cM * cE, (long)cE * cE, (long)256 * cE, cL);
  gemm(RT, WkB, nullptr, nullptr, nullptr, BigL + (long)128 * cE, cM, cE, cE, cE, cE, 1.f, 0,
       (long)cM * cE, (long)cE * cE, (long)256 * cE, cL);
  phibias_kernel<<<cL, 128, 0, stream>>>(bqC, RmB, bqkC, PSCALE, 256);
  phibias_kernel<<<cL, 128, 0, stream>>>(bkC, RmB, bqkC + 128, PSCALE, 256);
  packb_kernel<<<cL, 256, 0, stream>>>(bvC, bkC, bqC, b1536C);

  // ---- input projection + positional embedding ----
  gemm(xb, WiT, biC, nullptr, nullptr, h, cNBS, cDIN, cE, cDIN, cDIN, 1.f,
       FLAG_BIAS, 0, 0, 0, 1);
  addpos_kernel<<<16384, 256, 0, stream>>>(h, posb);

  for (int i = 0; i < cL; ++i) {
    cus WoT_i = WoT + (long)i * cE * cE;  cus bo_i = boC + (long)i * cE;
    cus BigB_i = BigB + (long)i * cNF * cE;
    cus BigL_i = BigL + (long)i * 256 * cE;
    cus b1536_i = b1536C + (long)i * cNF;
    cus bqk_i = bqkC + (long)i * 256;
    cus g_i   = lngC + (long)i * cE;      cus b_i  = lnbC + (long)i * cE;
    cus W1T_i = W1T + (long)i * cFF * cE; cus b1_i = b1C + (long)i * cFF;
    cus W2T_i = W2T + (long)i * cE * cFF; cus b2_i = b2C + (long)i * cE;

    // --- fused one pass over h: v^T (VT), ||k||^2 + ||q||^2 (RNORM atomics);
    //     XCD-swizzled so each h-panel is fetched by exactly one L2 ---
    zero4_kernel<<<128, 256, 0, stream>>>(rnorm2);
    gemm_kernel<<<dim3(12, 512, 1), dim3(256), 0, stream>>>(
        h, BigB_i, b1536_i, nullptr, nullptr, rnorm2, vtb,
        cE, cNF, cE, cE, 1.f, FLAG_FUSED | FLAG_SWZ, 0, 0, (long)cE * cS);

    // --- dual logits: q (by=0) and k (by=1), f32 + block maxes; XCD-swizzled ---
    gemm_kernel<<<dim3(2, 512, 1), dim3(256), 0, stream>>>(
        h, BigL_i, bqk_i, nullptr, rnorm2, partials, logfX,
        cE, 256, cE, cE, PSCALE, FLAG_PHIK | FLAG_BIAS | FLAG_SWZ, 0, 0, 0);

    reducemax2_kernel<<<1, 256, 0, stream>>>(partials, gmaxf);
    expq_kernel<<<8192, 256, 0, stream>>>(logfX, gmaxf, Pb);
    expT_kernel<<<dim3(4, 128, cB), 256, 0, stream>>>(logfX + cNBS * cM, gmaxf + 1, qtb);

    // --- z, den ---
    zsumt_kernel<<<dim3(cB, cM), 256, 0, stream>>>(qtb, z);
    den_kernel<<<16384, 256, 0, stream>>>(Pb, z, vec64k);

    // --- kv[b] (M x E) = pk^T[b] @ v^T[b]^T, split-K x8 in-cache atomics ---
    zero4_kernel<<<1024, 256, 0, stream>>>(kvacc);
    gemm(qtb, vtb, nullptr, nullptr, nullptr, kvacc, cM, cS / 8, cE, cS, cS, 1.f,
         FLAG_SPLITK8 | FLAG_ATOMIC, (long)cM * cS, (long)cE * cS, (long)cM * cE, cB * 8);
    kvcvt_kernel<<<1024, 256, 0, stream>>>(kvacc, kvtb);

    // --- fold Wo into kv: kvo^T[b] (E x M) = WoT @ kv[b]^T  (tiny, 64 blocks) ---
    gemm(WoT_i, kvtb, nullptr, nullptr, nullptr, kvotb, cE, cE, cM, cE, cE, 1.f,
         0, 0, (long)cM * cE, (long)cE * cM, cB);

    // --- a[b] = (pq[b] @ kvo[b]) / (den+1e-6) + bo -> Y ; LN in place ---
    gemm(Pb, kvotb, bo_i, vec64k, nullptr, ab, cS, cM, cE, cM, cM, 1.f,
         FLAG_DEN | FLAG_BIAS, (long)cS * cM, (long)cE * cM, (long)cS * cE, cB);
    ln_kernel<<<cNBS, 256, 0, stream>>>(ab, g_i, b_i);

    // --- FFN in 4 row-chunks of 16384; h += ffn(y); XCD-swizzled ---
    for (int c = 0; c < 4; ++c) {
      const unsigned short* yc = ab + (long)c * 16384 * cE;
      unsigned short* hc = h + (long)c * 16384 * cE;
      gemm_kernel<<<dim3(16, 128, 1), dim3(256), 0, stream>>>(
          yc, W1T_i, b1_i, nullptr, nullptr, nullptr, u1b,
          cE, cFF, cE, cE, 1.f, FLAG_BIAS | FLAG_GELU | FLAG_SWZ, 0, 0, 0);
      gemm_kernel<<<dim3(4, 128, 1), dim3(256), 0, stream>>>(
          u1b, W2T_i, b2_i, hc, nullptr, nullptr, hc,
          cFF, cE, cFF, cFF, 1.f, FLAG_BIAS | FLAG_RES | FLAG_SWZ, 0, 0, 0);
    }
  }

  head_kernel<<<cB, 256, 0, stream>>>(h, Wr1C, br1C, Wr2C, br2C, d_out, dflag);
}

// Round 13
// 3714.286 us; speedup vs baseline: 1.2452x; 1.0695x over previous
//
#include <hip/hip_runtime.h>
#include <math.h>

// ---------------- problem constants ----------------
static constexpr int  cB   = 16;
static constexpr int  cS   = 4096;
static constexpr int  cDIN = 64;
static constexpr int  cE   = 512;
static constexpr int  cM   = 128;
static constexpr int  cL   = 4;
static constexpr int  cFF  = 2048;   // 4*E
static constexpr int  cHE  = 256;    // E/2
static constexpr long cNBS = (long)cB * cS;   // 65536 rows
static constexpr int  cNF  = 1536;   // fused N = 512(v) + 512(k-norm) + 512(q-norm)

typedef __attribute__((ext_vector_type(8))) short  bf16x8;
typedef __attribute__((ext_vector_type(4))) short  bf16x4;
typedef __attribute__((ext_vector_type(4))) float  f32x4;

typedef const __attribute__((address_space(1))) unsigned int g_u32;
typedef __attribute__((address_space(3))) unsigned int l_u32;

__device__ __forceinline__ float b2f(unsigned short u) {
  union { unsigned int i; float f; } x; x.i = ((unsigned int)u) << 16; return x.f;
}
__device__ __forceinline__ unsigned short f2b(float f) {
  union { float f; unsigned int i; } x; x.f = f;
  unsigned int r = x.i + 0x7FFFu + ((x.i >> 16) & 1u);   // RNE
  return (unsigned short)(r >> 16);
}

// phi math (round-6 post-mortem): max-shift and q-row-norm do NOT cancel out
// of num/(den+1e-6); faithful computation kept (round-7: absmax 0.0078).
#define PSCALE 0.21022410381342863f     // 512^-0.25
#define PNRM   0.022097086912079608f    // 0.5 * PSCALE^2
#define PINV   0.08838834764831845f     // 1/sqrt(M)

// ---------------- GEMM: C[rows x N] = f(alpha*A@Bt^T + bias) -------------
// A: rows x K bf16 (row stride lda). Bt: N x K bf16 (row stride ldb).
#define FLAG_BIAS    2
#define FLAG_GELU    4
#define FLAG_RES     8     // += bf16 Res[idx]
#define FLAG_VT      16    // store transposed per 4096-row batch, batch stride sC
#define FLAG_DEN     32    // v = acc/(aux[zb*rowsPerBatch+rr]+1e-6) BEFORE bias
#define FLAG_RNORM   64    // no C store; atomicAdd row-norms of (acc+bias) into pmax[rnoff+row]
#define FLAG_PHIK    128   // dual q/k logits: by=0 q (aux+cNBS), by=1 k (aux+0);
                           // l = PSCALE*acc + bias - PNRM*aux; f32 out + block max
#define FLAG_F32OUT  256   // store f32
#define FLAG_SPLITK8 512   // blockIdx.z = batch*8 + k-chunk
#define FLAG_ATOMIC  1024  // f32 atomicAdd into C (indexed by batch zb)
#define FLAG_FUSED   2048  // (with SWZ, grid (12,512)): by<4 VT(v), by<8 RNORM(k), by<12 RNORM(q)
#define FLAG_SWZ     4096  // grid (NBcols, nbx): XCD-aware remap so all column-blocks
                           // sharing an A-row-panel land on ONE XCD's L2 (round-9:
                           // FETCH 269.6 -> 41.5 MB on the FUSED dispatch)

#define GMT 128
#define GNT 128
#define GBK 64

// round-10 post-mortem: the round-9 "bank conflict fix" was a null -- b128 wave64
// reads have a structural floor of 8 lanes/bank and the old layout already met it
// (BANK_CONFLICT byte-identical 1.311e7, dur unchanged). The real residual cost is
// the 2-barrier-per-K-step drain (16 K-iters at K=512). This round: GBK 32->64 --
// halves barriers/vmcnt drains per K-element. LDS 32.8KB -> 4 blocks/CU (equal to
// the VGPR+AGPR limit, occupancy unchanged). 128B rows would be a REAL 16-way
// conflict (2x floor), so chunk^=(row&7) XOR on global source + fragment read
// (LDS dest stays linear for global_load_lds). Bit-exact.

__global__ __launch_bounds__(256, 2)
void gemm_kernel(const unsigned short* __restrict__ A,
                 const unsigned short* __restrict__ Bt,
                 const unsigned short* __restrict__ bias,
                 const unsigned short* __restrict__ Res,
                 const float* __restrict__ aux,
                 float* __restrict__ pmax,
                 void* __restrict__ C,
                 int K, int N, int lda, int ldb, float alpha, int flags,
                 long sA, long sB, long sC)
{
  // 32.8 KB shared: As(16K)+Bs(16K) during K-loop; stage aliases them post-loop (VT).
  __shared__ __align__(16) unsigned char sraw[32800];
  unsigned short (*As)[64] = (unsigned short (*)[64])sraw;
  unsigned short (*Bs)[64] = (unsigned short (*)[64])(sraw + 16384);
  unsigned short (*stage)[136] = (unsigned short (*)[136])sraw;   // VT post-loop (17408 B)
  float* wred  = (float*)(sraw + 32768);                          // PHIK block max (16 B)

  const int tid  = threadIdx.x;
  const int lane = tid & 63;
  const int wid  = tid >> 6;

  int bx = blockIdx.x, by = blockIdx.y;
  if (flags & FLAG_SWZ) {
    // lid%8 = XCD (observed round-robin); give each XCD a contiguous bx range,
    // iterate by fastest within it -> A-panel read by exactly one L2.
    const unsigned lid  = blockIdx.x + gridDim.x * blockIdx.y;
    const unsigned xcd  = lid & 7u;
    const unsigned slot = lid >> 3;
    bx = (int)(xcd * (gridDim.y >> 3) + slot / gridDim.x);
    by = (int)(slot % gridDim.x);
  }

  long zb = blockIdx.z;            // batch index (for A/B/aux)
  const long zc = blockIdx.z;      // C-store base index (keeps k-chunk for split-K)
  int koff = 0;
  if (flags & FLAG_SPLITK8) { koff = (int)(zb & 7) * K; zb >>= 3; }

  const unsigned short* Ab = A + zb * sA + (long)bx * GMT * lda + koff;
  const unsigned short* Bb = Bt + zb * sB + (long)by * GNT * ldb + koff;

  // staging (128 rows x 64 cols per matrix, 4 stripes of 32 rows):
  // LDS dest stays LINEAR (stripe*4096 + tid*16 bytes, wave-contiguous);
  // global source chunk is XOR-swizzled by row&7 so fragment b128 reads
  // stay at the 8-lanes/bank structural floor despite 128B row stride.
  const int srow  = tid >> 3;                            // 0..31 within stripe
  const int scolG = (((tid & 7) ^ (srow & 7)) << 3);     // swizzled global col
  const unsigned short* gA = Ab + (long)srow * lda + scolG;
  const unsigned short* gB = Bb + (long)srow * ldb + scolG;
  l_u32* lA = (l_u32*)(sraw + tid * 16);
  l_u32* lB = (l_u32*)(sraw + 16384 + tid * 16);

  const f32x4 fzero = {0.f, 0.f, 0.f, 0.f};
  f32x4 acc[4][4];
#pragma unroll
  for (int i = 0; i < 4; ++i)
#pragma unroll
    for (int j = 0; j < 4; ++j) acc[i][j] = fzero;

  const int wm = (wid >> 1) << 6;
  const int wn = (wid & 1) << 6;
  const int fm = lane & 15;
  const int kqh = lane >> 4;   // 0..3 (which 16B chunk of the K=32 slice)

  const long ka32 = (long)32 * lda, kb32 = (long)32 * ldb;
  for (int k0 = 0; k0 < K; k0 += GBK) {
#pragma unroll
    for (int s = 0; s < 4; ++s) {
      __builtin_amdgcn_global_load_lds((g_u32*)(gA + (long)s * ka32 + k0),
                                       (l_u32*)((__attribute__((address_space(3))) char*)lA + s * 4096), 16, 0, 0);
      __builtin_amdgcn_global_load_lds((g_u32*)(gB + (long)s * kb32 + k0),
                                       (l_u32*)((__attribute__((address_space(3))) char*)lB + s * 4096), 16, 0, 0);
    }
    __syncthreads();

#pragma unroll
    for (int kk = 0; kk < 2; ++kk) {
      bf16x8 af[4], bfv[4];
#pragma unroll
      for (int i = 0; i < 4; ++i) {
        const int ca = ((((kk << 2) | kqh) ^ (fm & 7)) << 3);
        af[i]  = *(const bf16x8*)&As[wm + i * 16 + fm][ca];
        bfv[i] = *(const bf16x8*)&Bs[wn + i * 16 + fm][ca];
      }
#pragma unroll
      for (int i = 0; i < 4; ++i)
#pragma unroll
        for (int j = 0; j < 4; ++j)
          acc[i][j] = __builtin_amdgcn_mfma_f32_16x16x32_bf16(af[i], bfv[j], acc[i][j], 0, 0, 0);
    }
    __syncthreads();
  }

  // epilogue: C/D layout col=lane&15, row=(lane>>4)*4+reg  [verified m89/m91]
  const int rq = (lane >> 4) << 2;
  const long crow0 = (long)bx * GMT + wm;
  const int  ccol0 = by * GNT + wn;

  long rnoff = 0;
  if (flags & FLAG_FUSED) {
    if (by < 4) flags = FLAG_BIAS | FLAG_VT;
    else { flags = FLAG_BIAS | FLAG_RNORM; if (by >= 8) rnoff = cNBS; }
  }

  if (flags & FLAG_RNORM) {
    // row-norm of (acc*alpha + bias): reduce over this wave's 64 cols, atomic-add.
#pragma unroll
    for (int i = 0; i < 4; ++i)
#pragma unroll
      for (int r = 0; r < 4; ++r) {
        float s = 0.f;
#pragma unroll
        for (int j = 0; j < 4; ++j) {
          float v = acc[i][j][r] * alpha + b2f(bias[ccol0 + j * 16 + fm]);
          s += v * v;
        }
        s += __shfl_xor(s, 1, 64);
        s += __shfl_xor(s, 2, 64);
        s += __shfl_xor(s, 4, 64);
        s += __shfl_xor(s, 8, 64);
        if (fm == 0)
          unsafeAtomicAdd(&pmax[rnoff + crow0 + i * 16 + rq + r], s);
      }
    return;
  }

  if (flags & FLAG_PHIK) {
    // dual q/k phi logits (grid (2,512)+SWZ): by=0 q (aux offset cNBS), by=1 k.
    // l = PSCALE*acc + bias - PNRM*aux[row]; f32 out + block max to pmax[by*512+bx].
    const long aoff = (by == 0) ? cNBS : 0;
    float* Cf = (float*)C + (long)by * (cNBS * (long)cM);
    float mx = -3.0e38f;
#pragma unroll
    for (int i = 0; i < 4; ++i)
#pragma unroll
      for (int r = 0; r < 4; ++r) {
        const long rr = crow0 + i * 16 + rq + r;
        const float nrm = PNRM * aux[aoff + rr];
#pragma unroll
        for (int j = 0; j < 4; ++j) {
          const int cc = ccol0 + j * 16 + fm;
          const float bv = b2f(bias[cc]);
          float l = acc[i][j][r] * PSCALE + bv - nrm;
          mx = fmaxf(mx, l);
          Cf[rr * (long)cM + (cc & (cM - 1))] = l;
        }
      }
#pragma unroll
    for (int off = 32; off >= 1; off >>= 1) mx = fmaxf(mx, __shfl_down(mx, off, 64));
    if (lane == 0) wred[wid] = mx;
    __syncthreads();
    if (tid == 0)
      pmax[by * 512 + bx] = fmaxf(fmaxf(wred[0], wred[1]), fmaxf(wred[2], wred[3]));
    return;
  }

  if (flags & FLAG_ATOMIC) {
    // split-K reduction in-cache: f32 atomic add into C[zb]
    float* Cf = (float*)C + zb * sC;
#pragma unroll
    for (int j = 0; j < 4; ++j) {
      const int cc = ccol0 + j * 16 + fm;
#pragma unroll
      for (int i = 0; i < 4; ++i)
#pragma unroll
        for (int r = 0; r < 4; ++r) {
          const long rr = crow0 + i * 16 + rq + r;
          unsafeAtomicAdd(&Cf[rr * (long)N + cc], acc[i][j][r] * alpha);
        }
    }
    return;
  }

  if (flags & FLAG_VT) {
    // stage 64 cols x 128 rows in LDS, then coalesced column stores (64B/thread)
    unsigned short* Cb = (unsigned short*)C;
    const int bb = (bx * GMT) >> 12;
    const long sbase = (long)((bx * GMT) & (cS - 1));
#pragma unroll
    for (int rnd = 0; rnd < 2; ++rnd) {
      if ((wn >> 6) == rnd) {
#pragma unroll
        for (int j = 0; j < 4; ++j) {
          const int cc = ccol0 + j * 16 + fm;
          const float bv = (flags & FLAG_BIAS) ? b2f(bias[cc]) : 0.f;
          const int cl = j * 16 + fm;
#pragma unroll
          for (int i = 0; i < 4; ++i)
#pragma unroll
            for (int r = 0; r < 4; ++r)
              stage[cl][wm + i * 16 + rq + r] = f2b(acc[i][j][r] * alpha + bv);
        }
      }
      __syncthreads();
      {
        const int cl = tid >> 2;
        const int sseg = (tid & 3) << 5;
        const int gcol = by * GNT + rnd * 64 + cl;
        unsigned short* dst = Cb + (long)bb * sC + (long)gcol * cS + sbase + sseg;
#pragma unroll
        for (int t = 0; t < 4; ++t)
          *(bf16x8*)(dst + t * 8) = *(const bf16x8*)&stage[cl][sseg + t * 8];
      }
      __syncthreads();
    }
    return;
  }

  // generic epilogue. Order: acc -> DEN -> +bias -> GELU -> RES (DEN before bias
  // so att = (pq@kvo)/den + bo works; plain BIAS/GELU paths unaffected).
  const long rowsPerBatch = (long)gridDim.x * GMT;
#pragma unroll
  for (int j = 0; j < 4; ++j) {
    const int cc = ccol0 + j * 16 + fm;
    const float bv = (flags & FLAG_BIAS) ? b2f(bias[cc]) : 0.f;
#pragma unroll
    for (int i = 0; i < 4; ++i) {
      const long rbase = crow0 + i * 16 + rq;
#pragma unroll
      for (int r = 0; r < 4; ++r) {
        const long rr = rbase + r;
        float v = acc[i][j][r] * alpha;
        if (flags & FLAG_DEN)
          v *= 1.f / (fmaxf(aux[zb * rowsPerBatch + rr], 0.f) + 1e-6f);
        v += bv;
        if (flags & FLAG_GELU) v = 0.5f * v * (1.f + erff(v * 0.7071067811865475f));
        const long idx = zc * sC + rr * (long)N + cc;
        if (flags & FLAG_RES) v += b2f(Res[idx]);
        if (flags & FLAG_F32OUT) ((float*)C)[idx] = v;
        else                     ((unsigned short*)C)[idx] = f2b(v);
      }
    }
  }
}

// ---------------- dtype shim ----------------
__global__ void detect_kernel(const unsigned short* __restrict__ lng,
                              int* __restrict__ flag) {
  if (threadIdx.x == 0 && blockIdx.x == 0) flag[0] = (lng[0] == 0) ? 1 : 0;
}

__global__ __launch_bounds__(256) void cvt_kernel(const void* __restrict__ in,
                                                  unsigned short* __restrict__ out,
                                                  long n, const int* __restrict__ flag) {
  long i = (long)blockIdx.x * 256 + threadIdx.x;
  if (i >= n) return;
  if (flag[0]) out[i] = f2b(((const float*)in)[i]);
  else         out[i] = ((const unsigned short*)in)[i];
}

// ---------------- small kernels ----------------
__global__ __launch_bounds__(256) void zero4_kernel(float* __restrict__ p) {
  long i = ((long)blockIdx.x * 256 + threadIdx.x) * 4;
  f32x4 z = {0.f, 0.f, 0.f, 0.f};
  *(f32x4*)&p[i] = z;
}

__global__ __launch_bounds__(256) void addpos_kernel(unsigned short* __restrict__ h,
                                                     const unsigned short* __restrict__ pos) {
  long i = ((long)blockIdx.x * 256 + threadIdx.x) * 8;
  long se = i % ((long)cS * cE);
  bf16x8 v = *(bf16x8*)&h[i];
  bf16x8 p = *(const bf16x8*)&pos[se];
#pragma unroll
  for (int r = 0; r < 8; ++r)
    v[r] = (short)f2b(b2f((unsigned short)v[r]) + b2f((unsigned short)p[r]));
  *(bf16x8*)&h[i] = v;
}

// gmax[0]=max(partials[0..512)) (q), gmax[1]=max(partials[512..1024)) (k)
__global__ __launch_bounds__(256) void reducemax2_kernel(const float* __restrict__ partials,
                                                         float* __restrict__ gmax) {
  __shared__ float sm[8];
  const int tid = threadIdx.x;
  for (int half = 0; half < 2; ++half) {
    float mx = -3.0e38f;
    for (int i = tid; i < 512; i += 256) mx = fmaxf(mx, partials[half * 512 + i]);
#pragma unroll
    for (int off = 32; off >= 1; off >>= 1) mx = fmaxf(mx, __shfl_down(mx, off, 64));
    if ((tid & 63) == 0) sm[(half << 2) + (tid >> 6)] = mx;
  }
  __syncthreads();
  if (tid == 0) gmax[0] = fmaxf(fmaxf(sm[0], sm[1]), fmaxf(sm[2], sm[3]));
  if (tid == 1) gmax[1] = fmaxf(fmaxf(sm[4], sm[5]), fmaxf(sm[6], sm[7]));
}

// elementwise exp (row-major): P = bf16(exp(lf - gm)/sqrt(M))
__global__ __launch_bounds__(256) void expq_kernel(const float* __restrict__ lf,
                                                   const float* __restrict__ gmx,
                                                   unsigned short* __restrict__ P) {
  long i = ((long)blockIdx.x * 256 + threadIdx.x) * 4;
  const float gm = gmx[0];
  f32x4 v = *(const f32x4*)&lf[i];
  bf16x4 o;
#pragma unroll
  for (int r = 0; r < 4; ++r)
    o[r] = (short)f2b(__expf(fminf(v[r] - gm, 0.f)) * PINV);
  *(bf16x4*)&P[i] = o;
}

// fused exp + transpose: lf (B x S x M f32 logits) -> out (B x M x S bf16 phi)
__global__ __launch_bounds__(256) void expT_kernel(const float* __restrict__ lf,
                                                   const float* __restrict__ gmx,
                                                   unsigned short* __restrict__ out) {
  __shared__ unsigned short t[32][33];
  const int b = blockIdx.z;
  const float gm = gmx[0];
  const int bx = blockIdx.x << 5, by = blockIdx.y << 5;   // bx: M, by: S
  const int tx = threadIdx.x & 31, ty = threadIdx.x >> 5;
  const float* src = lf + (long)b * cS * cM;
  unsigned short* dst = out + (long)b * cM * cS;
#pragma unroll
  for (int i = ty; i < 32; i += 8) {
    float l = src[(long)(by + i) * cM + bx + tx];
    t[i][tx] = f2b(__expf(fminf(l - gm, 0.f)) * PINV);
  }
  __syncthreads();
#pragma unroll
  for (int i = ty; i < 32; i += 8)
    dst[(long)(bx + i) * cS + by + tx] = t[tx][i];
}

// kv f32 accumulators -> bf16
__global__ __launch_bounds__(256) void kvcvt_kernel(const float* __restrict__ kvacc,
                                                    unsigned short* __restrict__ kvtb) {
  long i = ((long)blockIdx.x * 256 + threadIdx.x) * 4;
  f32x4 v = *(const f32x4*)&kvacc[i];
  bf16x4 o;
#pragma unroll
  for (int r = 0; r < 4; ++r) o[r] = (short)f2b(v[r]);
  *(bf16x4*)&kvtb[i] = o;
}

// out[l*ldo + m] = scale * sum_e bq[l][e] * R[l][e][m]   (tiny, pre-loop)
__global__ __launch_bounds__(128) void phibias_kernel(const unsigned short* __restrict__ bq,
                                                      const unsigned short* __restrict__ R,
                                                      unsigned short* __restrict__ out,
                                                      float scale, int ldo) {
  const int l = blockIdx.x, m = threadIdx.x;
  const unsigned short* b = bq + (long)l * cE;
  const unsigned short* r = R + (long)l * cE * cM;
  float a = 0.f;
  for (int e = 0; e < cE; ++e) a += b2f(b[e]) * b2f(r[(long)e * cM + m]);
  out[(long)l * ldo + m] = f2b(a * scale);
}

// packed bias for fused GEMM: [bv(512) | bk(512) | bq(512)] per layer
__global__ __launch_bounds__(256) void packb_kernel(const unsigned short* __restrict__ bv,
                                                    const unsigned short* __restrict__ bk,
                                                    const unsigned short* __restrict__ bq,
                                                    unsigned short* __restrict__ out) {
  const int l = blockIdx.x, t = threadIdx.x;
#pragma unroll
  for (int s = 0; s < 512; s += 256) {
    out[l * cNF + s + t]        = bv[l * 512 + s + t];
    out[l * cNF + 512 + s + t]  = bk[l * 512 + s + t];
    out[l * cNF + 1024 + s + t] = bq[l * 512 + s + t];
  }
}

// z[b][m] = sum_s qtb[b][m][s]   (qtb is B x M x S)
__global__ __launch_bounds__(256) void zsumt_kernel(const unsigned short* __restrict__ qtb,
                                                    float* __restrict__ z) {
  __shared__ float sred[4];
  const int b = blockIdx.x, m = blockIdx.y, tid = threadIdx.x;
  const unsigned short* p = qtb + ((long)b * cM + m) * cS + (long)tid * 16;
  bf16x8 a = *(const bf16x8*)p;
  bf16x8 c = *(const bf16x8*)(p + 8);
  float s = 0.f;
#pragma unroll
  for (int t = 0; t < 8; ++t) s += b2f((unsigned short)a[t]) + b2f((unsigned short)c[t]);
#pragma unroll
  for (int off = 32; off >= 1; off >>= 1) s += __shfl_down(s, off, 64);
  const int w = tid >> 6, lane = tid & 63;
  if (lane == 0) sred[w] = s;
  __syncthreads();
  if (tid == 0) z[b * cM + m] = sred[0] + sred[1] + sred[2] + sred[3];
}

// den[row] = dot(pq[row,:], z[b,:]); 4 rows/block
__global__ __launch_bounds__(256) void den_kernel(const unsigned short* __restrict__ P,
                                                  const float* __restrict__ z,
                                                  float* __restrict__ den) {
  const int w = threadIdx.x >> 6, lane = threadIdx.x & 63;
  const long row = (long)blockIdx.x * 4 + w;
  const float* zb = z + (row >> 12) * cM;
  const unsigned short* p = P + row * cM;
  float d = b2f(p[lane]) * zb[lane] + b2f(p[lane + 64]) * zb[lane + 64];
#pragma unroll
  for (int off = 32; off >= 1; off >>= 1) d += __shfl_down(d, off, 64);
  if (lane == 0) den[row] = d;
}

// layernorm in place (bf16 -> bf16), one row per block
__global__ __launch_bounds__(256) void ln_kernel(unsigned short* __restrict__ a,
                                                 const unsigned short* __restrict__ g,
                                                 const unsigned short* __restrict__ bb) {
  __shared__ float sred[8];
  const long row = blockIdx.x;
  unsigned short* ar = a + row * cE;
  const int tid = threadIdx.x;
  float v0 = b2f(ar[tid]), v1 = b2f(ar[tid + 256]);
  float s = v0 + v1, sq = v0 * v0 + v1 * v1;
#pragma unroll
  for (int off = 32; off >= 1; off >>= 1) {
    s  += __shfl_down(s, off, 64);
    sq += __shfl_down(sq, off, 64);
  }
  const int w = tid >> 6, lane = tid & 63;
  if (lane == 0) { sred[w] = s; sred[4 + w] = sq; }
  __syncthreads();
  const float st  = sred[0] + sred[1] + sred[2] + sred[3];
  const float sqt = sred[4] + sred[5] + sred[6] + sred[7];
  const float mean = st * (1.f / 512.f);
  const float var  = fmaxf(sqt * (1.f / 512.f) - mean * mean, 0.f);
  const float rstd = rsqrtf(var + 1e-5f);
  ar[tid]       = f2b((v0 - mean) * rstd * b2f(g[tid])       + b2f(bb[tid]));
  ar[tid + 256] = f2b((v1 - mean) * rstd * b2f(g[tid + 256]) + b2f(bb[tid + 256]));
}

// batched bf16 transpose: in (R x C) -> out (C x R); grid (C/32, R/32, batch)
__global__ __launch_bounds__(256) void transpose_kernel(const unsigned short* __restrict__ in,
                                                        unsigned short* __restrict__ out,
                                                        int R, int C, long sIn, long sOut) {
  __shared__ unsigned short t[32][33];
  in  += (long)blockIdx.z * sIn;
  out += (long)blockIdx.z * sOut;
  const int bx = blockIdx.x << 5, by = blockIdx.y << 5;
  const int tx = threadIdx.x & 31, ty = threadIdx.x >> 5;
#pragma unroll
  for (int i = ty; i < 32; i += 8) t[i][tx] = in[(long)(by + i) * C + bx + tx];
  __syncthreads();
#pragma unroll
  for (int i = ty; i < 32; i += 8) out[(long)(bx + i) * R + by + tx] = t[tx][i];
}

// final head
__global__ __launch_bounds__(256) void head_kernel(const unsigned short* __restrict__ h,
                                                   const unsigned short* __restrict__ Wr1,
                                                   const unsigned short* __restrict__ br1,
                                                   const unsigned short* __restrict__ Wr2,
                                                   const unsigned short* __restrict__ br2,
                                                   void* __restrict__ out,
                                                   const int* __restrict__ flag) {
  __shared__ float pooled[cE];
  __shared__ float red[4];
  const int b = blockIdx.x, tid = threadIdx.x;
  pooled[tid]       = b2f(h[(long)b * cS * cE + tid]);
  pooled[tid + 256] = b2f(h[(long)b * cS * cE + tid + 256]);
  __syncthreads();
  float acc = b2f(br1[tid]);
  for (int e = 0; e < cE; ++e) acc += pooled[e] * b2f(Wr1[e * cHE + tid]);
  acc = fmaxf(acc, 0.f) * b2f(Wr2[tid]);
#pragma unroll
  for (int off = 32; off >= 1; off >>= 1) acc += __shfl_down(acc, off, 64);
  const int w = tid >> 6, lane = tid & 63;
  if (lane == 0) red[w] = acc;
  __syncthreads();
  if (tid == 0) {
    float r = red[0] + red[1] + red[2] + red[3] + b2f(br2[0]);
    if (flag[0]) ((float*)out)[b] = r;
    else         ((unsigned short*)out)[b] = f2b(r);
  }
}

// ---------------- host ----------------
extern "C" void kernel_launch(void* const* d_in, const int* in_sizes, int n_in,
                              void* d_out, int out_size, void* d_ws, size_t ws_size,
                              hipStream_t stream) {
  (void)in_sizes; (void)n_in; (void)out_size;

  char* ws = (char*)d_ws;
  size_t off = 0;
  auto alloc = [&](size_t bytes) -> void* {
    void* p = ws + off;
    off += (bytes + 255) & ~(size_t)255;
    return p;
  };
  // ---- memory plan ----
  unsigned short* h   = (unsigned short*)alloc(cNBS * cE * 2);   // 67 MB residual
  unsigned short* X   = (unsigned short*)alloc(cNBS * cE * 2);   // 67 MB multi-use
  unsigned short* Y   = (unsigned short*)alloc(cNBS * cE * 2);   // 67 MB multi-use
  unsigned short* Pb  = (unsigned short*)alloc(cNBS * cM * 2);   // 16.8 MB phi(q)
  unsigned short* kvtb= (unsigned short*)alloc((long)cB * cM * cE * 2); // 2.1 MB kv (M x E)
  unsigned short* kvotb=(unsigned short*)alloc((long)cB * cE * cM * 2); // 2.1 MB (kv@Wo)^T
  float* kvacc        = (float*)alloc((long)cB * cM * cE * 4);   // 4 MB f32 kv acc
  float* vec64k       = (float*)alloc(cNBS * 4);                 // den
  float* rnorm2       = (float*)alloc(2 * cNBS * 4);             // 512 KB: [k | q] row-norms
  float* z            = (float*)alloc(cB * cM * 4);
  float* partials     = (float*)alloc(1024 * 4);                 // [q 512 | k 512] block maxes
  float* gmaxf        = (float*)alloc(256);                      // gmax[0]=q, gmax[1]=k
  int*   dflag        = (int*)alloc(256);
  unsigned short* WiT = (unsigned short*)alloc((long)cE * cDIN * 2);
  unsigned short* BigB= (unsigned short*)alloc((long)cL * cNF * cE * 2); // 6.3 MB [WvT|WkT|WqT]
  unsigned short* BigL= (unsigned short*)alloc((long)cL * 256 * cE * 2); // 1 MB [WqRT|WkRT]
  unsigned short* WoT = (unsigned short*)alloc((long)cL * cE * cE * 2);
  unsigned short* RT  = (unsigned short*)alloc((long)cL * cM * cE * 2);
  unsigned short* W1T = (unsigned short*)alloc((long)cL * cFF * cE * 2);
  unsigned short* W2T = (unsigned short*)alloc((long)cL * cE * cFF * 2);
  unsigned short* sb  = (unsigned short*)alloc(170000 * 2);

  // weight staging inside X (dead until first in-loop X use)
  unsigned short* WqB = X;
  unsigned short* WkB = WqB + (long)cL * cE * cE;
  unsigned short* WvB = WkB + (long)cL * cE * cE;
  unsigned short* WoB = WvB + (long)cL * cE * cE;
  unsigned short* RmB = WoB + (long)cL * cE * cE;
  unsigned short* W1B = RmB + (long)cL * cE * cM;
  unsigned short* W2B = W1B + (long)cL * cE * cFF;
  unsigned short* WiB = W2B + (long)cL * cE * cFF;
  // x, pos staging inside Y
  unsigned short* xb   = Y;
  unsigned short* posb = Y + cNBS * cDIN;
  // small tensors inside sb
  unsigned short* biC  = sb;
  unsigned short* bqC  = biC  + 512;
  unsigned short* bkC  = bqC  + 2048;
  unsigned short* bvC  = bkC  + 2048;
  unsigned short* boC  = bvC  + 2048;
  unsigned short* b1C  = boC  + 2048;
  unsigned short* b2C  = b1C  + 8192;
  unsigned short* lngC = b2C  + 2048;
  unsigned short* lnbC = lngC + 2048;
  unsigned short* Wr1C = lnbC + 2048;
  unsigned short* br1C = Wr1C + 131072;
  unsigned short* Wr2C = br1C + 256;
  unsigned short* br2C = Wr2C + 256;
  unsigned short* bqkC  = br2C + 16;            // [scale*(bq@R) | scale*(bk@R)], L x 256
  unsigned short* b1536C = bqkC + cL * 256;     // packed fused bias, L x 1536

  unsigned short* qtb  = X;                       // pk^T (B x M x S), 16.8 MB
  float* logfX         = (float*)X;               // [logf_q | logf_k] f32, 67 MB
  unsigned short* vtb  = Y;                       // v^T (B x E x S)
  unsigned short* ab   = Y;                       // a / y (LN in place)
  unsigned short* u1b  = X;                       // FFN hidden chunk (16384 x 2048)

  if (off > ws_size) return;

  // ---- dtype detect + convert all inputs to bf16 ----
  detect_kernel<<<1, 64, 0, stream>>>((const unsigned short*)d_in[13], dflag);
  auto cvt = [&](const void* src, unsigned short* dst, long n) {
    cvt_kernel<<<(unsigned)((n + 255) / 256), 256, 0, stream>>>(src, dst, n, dflag);
  };
  cvt(d_in[0],  xb,   cNBS * cDIN);
  cvt(d_in[1],  WiB,  (long)cDIN * cE);
  cvt(d_in[2],  biC,  cE);
  cvt(d_in[3],  posb, (long)cS * cE);
  cvt(d_in[4],  WqB,  (long)cL * cE * cE);
  cvt(d_in[5],  bqC,  (long)cL * cE);
  cvt(d_in[6],  WkB,  (long)cL * cE * cE);
  cvt(d_in[7],  bkC,  (long)cL * cE);
  cvt(d_in[8],  WvB,  (long)cL * cE * cE);
  cvt(d_in[9],  bvC,  (long)cL * cE);
  cvt(d_in[10], WoB,  (long)cL * cE * cE);
  cvt(d_in[11], boC,  (long)cL * cE);
  cvt(d_in[12], RmB,  (long)cL * cE * cM);
  cvt(d_in[13], lngC, (long)cL * cE);
  cvt(d_in[14], lnbC, (long)cL * cE);
  cvt(d_in[15], W1B,  (long)cL * cE * cFF);
  cvt(d_in[16], b1C,  (long)cL * cFF);
  cvt(d_in[17], W2B,  (long)cL * cFF * cE);
  cvt(d_in[18], b2C,  (long)cL * cE);
  cvt(d_in[19], Wr1C, (long)cE * cHE);
  cvt(d_in[20], br1C, cHE);
  cvt(d_in[21], Wr2C, cHE);
  cvt(d_in[22], br2C, 1);

  typedef const unsigned short* cus;
  auto gemm = [&](const void* A, const void* Bt, const void* bias_,
                  const float* aux_, float* pmax_, void* C,
                  long rows, int K, int N, int lda, int ldb, float alpha, int flags,
                  long sA, long sB, long sC, int batches, const void* Res_ = nullptr) {
    dim3 g((unsigned)(rows / 128), (unsigned)(N / 128), (unsigned)batches);
    gemm_kernel<<<g, dim3(256), 0, stream>>>(
        (const unsigned short*)A, (const unsigned short*)Bt,
        (const unsigned short*)bias_, (const unsigned short*)Res_,
        aux_, pmax_, C, K, N, lda, ldb, alpha, flags, sA, sB, sC);
  };

  // ---- weight pre-transposes (BigB = [WvT | WkT | WqT] per layer) ----
  transpose_kernel<<<dim3(16, 2, 1), 256, 0, stream>>>(WiB, WiT, cDIN, cE, 0, 0);
  transpose_kernel<<<dim3(16, 16, cL), 256, 0, stream>>>(WvB, BigB, cE, cE, (long)cE * cE, (long)cNF * cE);
  transpose_kernel<<<dim3(16, 16, cL), 256, 0, stream>>>(WkB, BigB + (long)512 * cE, cE, cE, (long)cE * cE, (long)cNF * cE);
  transpose_kernel<<<dim3(16, 16, cL), 256, 0, stream>>>(WqB, BigB + (long)1024 * cE, cE, cE, (long)cE * cE, (long)cNF * cE);
  transpose_kernel<<<dim3(16, 16, cL), 256, 0, stream>>>(WoB, WoT, cE, cE, (long)cE * cE, (long)cE * cE);
  transpose_kernel<<<dim3(4, 16, cL), 256, 0, stream>>>(RmB, RT, cE, cM, (long)cE * cM, (long)cE * cM);
  transpose_kernel<<<dim3(64, 16, cL), 256, 0, stream>>>(W1B, W1T, cE, cFF, (long)cE * cFF, (long)cE * cFF);
  transpose_kernel<<<dim3(16, 64, cL), 256, 0, stream>>>(W2B, W2T, cFF, cE, (long)cFF * cE, (long)cFF * cE);

  // ---- fold R into Wq/Wk: BigL = [(Wq@R)^T | (Wk@R)^T] per layer ----
  gemm(RT, WqB, nullptr, nullptr, nullptr, BigL, cM, cE, cE, cE, cE, 1.f, 0,
       (long)cM * cE, (long)cE * cE, (long)256 * cE, cL);
  gemm(RT, WkB, nullptr, nullptr, nullptr, BigL + (long)128 * cE, cM, cE, cE, cE, cE, 1.f, 0,
       (long)cM * cE, (long)cE * cE, (long)256 * cE, cL);
  phibias_kernel<<<cL, 128, 0, stream>>>(bqC, RmB, bqkC, PSCALE, 256);
  phibias_kernel<<<cL, 128, 0, stream>>>(bkC, RmB, bqkC + 128, PSCALE, 256);
  packb_kernel<<<cL, 256, 0, stream>>>(bvC, bkC, bqC, b1536C);

  // ---- input projection + positional embedding ----
  gemm(xb, WiT, biC, nullptr, nullptr, h, cNBS, cDIN, cE, cDIN, cDIN, 1.f,
       FLAG_BIAS, 0, 0, 0, 1);
  addpos_kernel<<<16384, 256, 0, stream>>>(h, posb);

  for (int i = 0; i < cL; ++i) {
    cus WoT_i = WoT + (long)i * cE * cE;  cus bo_i = boC + (long)i * cE;
    cus BigB_i = BigB + (long)i * cNF * cE;
    cus BigL_i = BigL + (long)i * 256 * cE;
    cus b1536_i = b1536C + (long)i * cNF;
    cus bqk_i = bqkC + (long)i * 256;
    cus g_i   = lngC + (long)i * cE;      cus b_i  = lnbC + (long)i * cE;
    cus W1T_i = W1T + (long)i * cFF * cE; cus b1_i = b1C + (long)i * cFF;
    cus W2T_i = W2T + (long)i * cE * cFF; cus b2_i = b2C + (long)i * cE;

    // --- fused one pass over h: v^T (VT), ||k||^2 + ||q||^2 (RNORM atomics);
    //     XCD-swizzled so each h-panel is fetched by exactly one L2 ---
    zero4_kernel<<<128, 256, 0, stream>>>(rnorm2);
    gemm_kernel<<<dim3(12, 512, 1), dim3(256), 0, stream>>>(
        h, BigB_i, b1536_i, nullptr, nullptr, rnorm2, vtb,
        cE, cNF, cE, cE, 1.f, FLAG_FUSED | FLAG_SWZ, 0, 0, (long)cE * cS);

    // --- dual logits: q (by=0) and k (by=1), f32 + block maxes; XCD-swizzled ---
    gemm_kernel<<<dim3(2, 512, 1), dim3(256), 0, stream>>>(
        h, BigL_i, bqk_i, nullptr, rnorm2, partials, logfX,
        cE, 256, cE, cE, PSCALE, FLAG_PHIK | FLAG_BIAS | FLAG_SWZ, 0, 0, 0);

    reducemax2_kernel<<<1, 256, 0, stream>>>(partials, gmaxf);
    expq_kernel<<<8192, 256, 0, stream>>>(logfX, gmaxf, Pb);
    expT_kernel<<<dim3(4, 128, cB), 256, 0, stream>>>(logfX + cNBS * cM, gmaxf + 1, qtb);

    // --- z, den ---
    zsumt_kernel<<<dim3(cB, cM), 256, 0, stream>>>(qtb, z);
    den_kernel<<<16384, 256, 0, stream>>>(Pb, z, vec64k);

    // --- kv[b] (M x E) = pk^T[b] @ v^T[b]^T, split-K x8 in-cache atomics ---
    zero4_kernel<<<1024, 256, 0, stream>>>(kvacc);
    gemm(qtb, vtb, nullptr, nullptr, nullptr, kvacc, cM, cS / 8, cE, cS, cS, 1.f,
         FLAG_SPLITK8 | FLAG_ATOMIC, (long)cM * cS, (long)cE * cS, (long)cM * cE, cB * 8);
    kvcvt_kernel<<<1024, 256, 0, stream>>>(kvacc, kvtb);

    // --- fold Wo into kv: kvo^T[b] (E x M) = WoT @ kv[b]^T  (tiny, 64 blocks) ---
    gemm(WoT_i, kvtb, nullptr, nullptr, nullptr, kvotb, cE, cE, cM, cE, cE, 1.f,
         0, 0, (long)cM * cE, (long)cE * cM, cB);

    // --- a[b] = (pq[b] @ kvo[b]) / (den+1e-6) + bo -> Y ; LN in place ---
    gemm(Pb, kvotb, bo_i, vec64k, nullptr, ab, cS, cM, cE, cM, cM, 1.f,
         FLAG_DEN | FLAG_BIAS, (long)cS * cM, (long)cE * cM, (long)cS * cE, cB);
    ln_kernel<<<cNBS, 256, 0, stream>>>(ab, g_i, b_i);

    // --- FFN in 4 row-chunks of 16384; h += ffn(y); XCD-swizzled ---
    for (int c = 0; c < 4; ++c) {
      const unsigned short* yc = ab + (long)c * 16384 * cE;
      unsigned short* hc = h + (long)c * 16384 * cE;
      gemm_kernel<<<dim3(16, 128, 1), dim3(256), 0, stream>>>(
          yc, W1T_i, b1_i, nullptr, nullptr, nullptr, u1b,
          cE, cFF, cE, cE, 1.f, FLAG_BIAS | FLAG_GELU | FLAG_SWZ, 0, 0, 0);
      gemm_kernel<<<dim3(4, 128, 1), dim3(256), 0, stream>>>(
          u1b, W2T_i, b2_i, hc, nullptr, nullptr, hc,
          cFF, cE, cFF, cFF, 1.f, FLAG_BIAS | FLAG_RES | FLAG_SWZ, 0, 0, 0);
    }
  }

  head_kernel<<<cB, 256, 0, stream>>>(h, Wr1C, br1C, Wr2C, br2C, d_out, dflag);
}

// Round 14
// 3623.967 us; speedup vs baseline: 1.2762x; 1.0249x over previous
//
#include <hip/hip_runtime.h>
#include <math.h>

// ---------------- problem constants ----------------
static constexpr int  cB   = 16;
static constexpr int  cS   = 4096;
static constexpr int  cDIN = 64;
static constexpr int  cE   = 512;
static constexpr int  cM   = 128;
static constexpr int  cL   = 4;
static constexpr int  cFF  = 2048;   // 4*E
static constexpr int  cHE  = 256;    // E/2
static constexpr long cNBS = (long)cB * cS;   // 65536 rows
static constexpr int  cNF  = 1792;   // fused N = 512(v)+512(k-norm)+512(q-norm)+128(logq)+128(logk)

typedef __attribute__((ext_vector_type(8))) short  bf16x8;
typedef __attribute__((ext_vector_type(4))) short  bf16x4;
typedef __attribute__((ext_vector_type(4))) float  f32x4;

typedef const __attribute__((address_space(1))) unsigned int g_u32;
typedef __attribute__((address_space(3))) unsigned int l_u32;

__device__ __forceinline__ float b2f(unsigned short u) {
  union { unsigned int i; float f; } x; x.i = ((unsigned int)u) << 16; return x.f;
}
__device__ __forceinline__ unsigned short f2b(float f) {
  union { float f; unsigned int i; } x; x.f = f;
  unsigned int r = x.i + 0x7FFFu + ((x.i >> 16) & 1u);   // RNE
  return (unsigned short)(r >> 16);
}

// phi math (round-6 post-mortem): max-shift and q-row-norm do NOT cancel out
// of num/(den+1e-6); faithful computation kept (round-7: absmax 0.0078).
// round-14: logits GEMM merged into FUSED -- epilogue stores RAW logits
// (PSCALE*acc + bias) + per-row raw max; the per-row norm (additive constant)
// and global max are applied later (reduceg + expq/expT). Identical math.
#define PSCALE 0.21022410381342863f     // 512^-0.25
#define PNRM   0.022097086912079608f    // 0.5 * PSCALE^2
#define PINV   0.08838834764831845f     // 1/sqrt(M)

// ---------------- GEMM: C[rows x N] = f(alpha*A@Bt^T + bias) -------------
// A: rows x K bf16 (row stride lda). Bt: N x K bf16 (row stride ldb).
#define FLAG_BIAS    2
#define FLAG_GELU    4
#define FLAG_RES     8     // += bf16 Res[idx]
#define FLAG_VT      16    // store transposed per 4096-row batch, batch stride sC
#define FLAG_DEN     32    // v = acc/(aux[zb*rowsPerBatch+rr]+1e-6) BEFORE bias
#define FLAG_RNORM   64    // no C store; atomicAdd row-norms of (acc+bias) into pmax[rnoff+row]
#define FLAG_F32OUT  256   // store f32
#define FLAG_SPLITK8 512   // blockIdx.z = batch*8 + k-chunk
#define FLAG_ATOMIC  1024  // f32 atomicAdd into C (indexed by batch zb)
#define FLAG_FUSED   2048  // (with SWZ, grid (14,512)): by<4 VT(v), by<8 RNORM(k),
                           // by<12 RNORM(q), by=12 raw q-logits, by=13 raw k-logits
#define FLAG_SWZ     4096  // grid (NBcols, nbx): XCD-aware remap so all column-blocks
                           // sharing an A-row-panel land on ONE XCD's L2 (round-9:
                           // FETCH 269.6 -> 41.5 MB on the FUSED dispatch)

#define GMT 128
#define GNT 128
#define GBK 64

// round-13 measured: GBK 32->64 + row&7 chunk-XOR = -258us (FUSED 158->136,
// MfmaUtil 33%, BANK_CONFLICT 1.3e7->5.2e5). LDS now exactly 32768 (wred gone).

__global__ __launch_bounds__(256, 2)
void gemm_kernel(const unsigned short* __restrict__ A,
                 const unsigned short* __restrict__ Bt,
                 const unsigned short* __restrict__ bias,
                 const unsigned short* __restrict__ Res,
                 const float* __restrict__ aux,
                 float* __restrict__ pmax,
                 void* __restrict__ C,
                 int K, int N, int lda, int ldb, float alpha, int flags,
                 long sA, long sB, long sC)
{
  // 32 KB shared: As(16K)+Bs(16K) during K-loop; stage aliases them post-loop (VT).
  __shared__ __align__(16) unsigned char sraw[32768];
  unsigned short (*As)[64] = (unsigned short (*)[64])sraw;
  unsigned short (*Bs)[64] = (unsigned short (*)[64])(sraw + 16384);
  unsigned short (*stage)[136] = (unsigned short (*)[136])sraw;   // VT post-loop (17408 B)

  const int tid  = threadIdx.x;
  const int lane = tid & 63;
  const int wid  = tid >> 6;

  int bx = blockIdx.x, by = blockIdx.y;
  if (flags & FLAG_SWZ) {
    // lid%8 = XCD (observed round-robin); give each XCD a contiguous bx range,
    // iterate by fastest within it -> A-panel read by exactly one L2.
    const unsigned lid  = blockIdx.x + gridDim.x * blockIdx.y;
    const unsigned xcd  = lid & 7u;
    const unsigned slot = lid >> 3;
    bx = (int)(xcd * (gridDim.y >> 3) + slot / gridDim.x);
    by = (int)(slot % gridDim.x);
  }

  long zb = blockIdx.z;            // batch index (for A/B/aux)
  const long zc = blockIdx.z;      // C-store base index (keeps k-chunk for split-K)
  int koff = 0;
  if (flags & FLAG_SPLITK8) { koff = (int)(zb & 7) * K; zb >>= 3; }

  const unsigned short* Ab = A + zb * sA + (long)bx * GMT * lda + koff;
  const unsigned short* Bb = Bt + zb * sB + (long)by * GNT * ldb + koff;

  // staging (128 rows x 64 cols per matrix, 4 stripes of 32 rows):
  // LDS dest stays LINEAR (stripe*4096 + tid*16 bytes, wave-contiguous);
  // global source chunk is XOR-swizzled by row&7 so fragment b128 reads
  // stay conflict-light despite 128B row stride.
  const int srow  = tid >> 3;                            // 0..31 within stripe
  const int scolG = (((tid & 7) ^ (srow & 7)) << 3);     // swizzled global col
  const unsigned short* gA = Ab + (long)srow * lda + scolG;
  const unsigned short* gB = Bb + (long)srow * ldb + scolG;
  l_u32* lA = (l_u32*)(sraw + tid * 16);
  l_u32* lB = (l_u32*)(sraw + 16384 + tid * 16);

  const f32x4 fzero = {0.f, 0.f, 0.f, 0.f};
  f32x4 acc[4][4];
#pragma unroll
  for (int i = 0; i < 4; ++i)
#pragma unroll
    for (int j = 0; j < 4; ++j) acc[i][j] = fzero;

  const int wm = (wid >> 1) << 6;
  const int wn = (wid & 1) << 6;
  const int fm = lane & 15;
  const int kqh = lane >> 4;   // 0..3 (which 16B chunk of the K=32 slice)

  const long ka32 = (long)32 * lda, kb32 = (long)32 * ldb;
  for (int k0 = 0; k0 < K; k0 += GBK) {
#pragma unroll
    for (int s = 0; s < 4; ++s) {
      __builtin_amdgcn_global_load_lds((g_u32*)(gA + (long)s * ka32 + k0),
                                       (l_u32*)((__attribute__((address_space(3))) char*)lA + s * 4096), 16, 0, 0);
      __builtin_amdgcn_global_load_lds((g_u32*)(gB + (long)s * kb32 + k0),
                                       (l_u32*)((__attribute__((address_space(3))) char*)lB + s * 4096), 16, 0, 0);
    }
    __syncthreads();

#pragma unroll
    for (int kk = 0; kk < 2; ++kk) {
      bf16x8 af[4], bfv[4];
#pragma unroll
      for (int i = 0; i < 4; ++i) {
        const int ca = ((((kk << 2) | kqh) ^ (fm & 7)) << 3);
        af[i]  = *(const bf16x8*)&As[wm + i * 16 + fm][ca];
        bfv[i] = *(const bf16x8*)&Bs[wn + i * 16 + fm][ca];
      }
#pragma unroll
      for (int i = 0; i < 4; ++i)
#pragma unroll
        for (int j = 0; j < 4; ++j)
          acc[i][j] = __builtin_amdgcn_mfma_f32_16x16x32_bf16(af[i], bfv[j], acc[i][j], 0, 0, 0);
    }
    __syncthreads();
  }

  // epilogue: C/D layout col=lane&15, row=(lane>>4)*4+reg  [verified m89/m91]
  const int rq = (lane >> 4) << 2;
  const long crow0 = (long)bx * GMT + wm;
  const int  ccol0 = by * GNT + wn;

  long rnoff = 0;
  if (flags & FLAG_FUSED) {
    if (by >= 12) {
      // raw phi logits: l = PSCALE*acc + bias(=scale*b@R). Store f32 + per-row
      // raw max (per column-half) -- norm & global max deferred (reduceg/exp).
      float* Lf  = (float*)Res + (long)(by - 12) * (cNBS * (long)cM);
      float* rmx = (float*)aux + ((long)(by - 12) * 2 + (wn >> 6)) * cNBS;
#pragma unroll
      for (int i = 0; i < 4; ++i)
#pragma unroll
        for (int r = 0; r < 4; ++r) {
          const long rr = crow0 + i * 16 + rq + r;
          float mx = -3.0e38f;
#pragma unroll
          for (int j = 0; j < 4; ++j) {
            const int cc = ccol0 + j * 16 + fm;
            float l = acc[i][j][r] * PSCALE + b2f(bias[cc]);
            mx = fmaxf(mx, l);
            Lf[rr * (long)cM + (cc & (cM - 1))] = l;
          }
          mx = fmaxf(mx, __shfl_xor(mx, 1, 64));
          mx = fmaxf(mx, __shfl_xor(mx, 2, 64));
          mx = fmaxf(mx, __shfl_xor(mx, 4, 64));
          mx = fmaxf(mx, __shfl_xor(mx, 8, 64));
          if (fm == 0) rmx[rr] = mx;
        }
      return;
    }
    if (by < 4) flags = FLAG_BIAS | FLAG_VT;
    else { flags = FLAG_BIAS | FLAG_RNORM; if (by >= 8) rnoff = cNBS; }
  }

  if (flags & FLAG_RNORM) {
    // row-norm of (acc*alpha + bias): reduce over this wave's 64 cols, atomic-add.
#pragma unroll
    for (int i = 0; i < 4; ++i)
#pragma unroll
      for (int r = 0; r < 4; ++r) {
        float s = 0.f;
#pragma unroll
        for (int j = 0; j < 4; ++j) {
          float v = acc[i][j][r] * alpha + b2f(bias[ccol0 + j * 16 + fm]);
          s += v * v;
        }
        s += __shfl_xor(s, 1, 64);
        s += __shfl_xor(s, 2, 64);
        s += __shfl_xor(s, 4, 64);
        s += __shfl_xor(s, 8, 64);
        if (fm == 0)
          unsafeAtomicAdd(&pmax[rnoff + crow0 + i * 16 + rq + r], s);
      }
    return;
  }

  if (flags & FLAG_ATOMIC) {
    // split-K reduction in-cache: f32 atomic add into C[zb]
    float* Cf = (float*)C + zb * sC;
#pragma unroll
    for (int j = 0; j < 4; ++j) {
      const int cc = ccol0 + j * 16 + fm;
#pragma unroll
      for (int i = 0; i < 4; ++i)
#pragma unroll
        for (int r = 0; r < 4; ++r) {
          const long rr = crow0 + i * 16 + rq + r;
          unsafeAtomicAdd(&Cf[rr * (long)N + cc], acc[i][j][r] * alpha);
        }
    }
    return;
  }

  if (flags & FLAG_VT) {
    // stage 64 cols x 128 rows in LDS, then coalesced column stores (64B/thread)
    unsigned short* Cb = (unsigned short*)C;
    const int bb = (bx * GMT) >> 12;
    const long sbase = (long)((bx * GMT) & (cS - 1));
#pragma unroll
    for (int rnd = 0; rnd < 2; ++rnd) {
      if ((wn >> 6) == rnd) {
#pragma unroll
        for (int j = 0; j < 4; ++j) {
          const int cc = ccol0 + j * 16 + fm;
          const float bv = (flags & FLAG_BIAS) ? b2f(bias[cc]) : 0.f;
          const int cl = j * 16 + fm;
#pragma unroll
          for (int i = 0; i < 4; ++i)
#pragma unroll
            for (int r = 0; r < 4; ++r)
              stage[cl][wm + i * 16 + rq + r] = f2b(acc[i][j][r] * alpha + bv);
        }
      }
      __syncthreads();
      {
        const int cl = tid >> 2;
        const int sseg = (tid & 3) << 5;
        const int gcol = by * GNT + rnd * 64 + cl;
        unsigned short* dst = Cb + (long)bb * sC + (long)gcol * cS + sbase + sseg;
#pragma unroll
        for (int t = 0; t < 4; ++t)
          *(bf16x8*)(dst + t * 8) = *(const bf16x8*)&stage[cl][sseg + t * 8];
      }
      __syncthreads();
    }
    return;
  }

  // generic epilogue. Order: acc -> DEN -> +bias -> GELU -> RES (DEN before bias
  // so att = (pq@kvo)/den + bo works; plain BIAS/GELU paths unaffected).
  const long rowsPerBatch = (long)gridDim.x * GMT;
#pragma unroll
  for (int j = 0; j < 4; ++j) {
    const int cc = ccol0 + j * 16 + fm;
    const float bv = (flags & FLAG_BIAS) ? b2f(bias[cc]) : 0.f;
#pragma unroll
    for (int i = 0; i < 4; ++i) {
      const long rbase = crow0 + i * 16 + rq;
#pragma unroll
      for (int r = 0; r < 4; ++r) {
        const long rr = rbase + r;
        float v = acc[i][j][r] * alpha;
        if (flags & FLAG_DEN)
          v *= 1.f / (fmaxf(aux[zb * rowsPerBatch + rr], 0.f) + 1e-6f);
        v += bv;
        if (flags & FLAG_GELU) v = 0.5f * v * (1.f + erff(v * 0.7071067811865475f));
        const long idx = zc * sC + rr * (long)N + cc;
        if (flags & FLAG_RES) v += b2f(Res[idx]);
        if (flags & FLAG_F32OUT) ((float*)C)[idx] = v;
        else                     ((unsigned short*)C)[idx] = f2b(v);
      }
    }
  }
}

// ---------------- dtype shim ----------------
__global__ void detect_kernel(const unsigned short* __restrict__ lng,
                              int* __restrict__ flag) {
  if (threadIdx.x == 0 && blockIdx.x == 0) flag[0] = (lng[0] == 0) ? 1 : 0;
}

__global__ __launch_bounds__(256) void cvt_kernel(const void* __restrict__ in,
                                                  unsigned short* __restrict__ out,
                                                  long n, const int* __restrict__ flag) {
  long i = (long)blockIdx.x * 256 + threadIdx.x;
  if (i >= n) return;
  if (flag[0]) out[i] = f2b(((const float*)in)[i]);
  else         out[i] = ((const unsigned short*)in)[i];
}

// ---------------- small kernels ----------------
__global__ __launch_bounds__(256) void zero4_kernel(float* __restrict__ p) {
  long i = ((long)blockIdx.x * 256 + threadIdx.x) * 4;
  f32x4 z = {0.f, 0.f, 0.f, 0.f};
  *(f32x4*)&p[i] = z;
}

__global__ __launch_bounds__(256) void addpos_kernel(unsigned short* __restrict__ h,
                                                     const unsigned short* __restrict__ pos) {
  long i = ((long)blockIdx.x * 256 + threadIdx.x) * 8;
  long se = i % ((long)cS * cE);
  bf16x8 v = *(bf16x8*)&h[i];
  bf16x8 p = *(const bf16x8*)&pos[se];
#pragma unroll
  for (int r = 0; r < 8; ++r)
    v[r] = (short)f2b(b2f((unsigned short)v[r]) + b2f((unsigned short)p[r]));
  *(bf16x8*)&h[i] = v;
}

// partials[b] = blockmax over 256 rows of (max(rmax halves) - PNRM*norm);
// b<256: q (rmax sides 0/1, norm at +cNBS); b>=256: k (sides 2/3, norm at 0).
__global__ __launch_bounds__(256) void reduceg_kernel(const float* __restrict__ rmax,
                                                      const float* __restrict__ rnorm2,
                                                      float* __restrict__ partials) {
  __shared__ float sm[4];
  const int b = blockIdx.x;
  const int side = b >> 8;                      // 0=q, 1=k
  const long row = ((long)(b & 255)) * 256 + threadIdx.x;
  const float nrm = PNRM * rnorm2[(side == 0 ? cNBS : 0) + row];
  float v = fmaxf(rmax[((long)side * 2 + 0) * cNBS + row],
                  rmax[((long)side * 2 + 1) * cNBS + row]) - nrm;
#pragma unroll
  for (int off = 32; off >= 1; off >>= 1) v = fmaxf(v, __shfl_down(v, off, 64));
  const int w = threadIdx.x >> 6, lane = threadIdx.x & 63;
  if (lane == 0) sm[w] = v;
  __syncthreads();
  if (threadIdx.x == 0)
    partials[b] = fmaxf(fmaxf(sm[0], sm[1]), fmaxf(sm[2], sm[3]));
}

// gmax[0]=max(partials[0..256)) (q), gmax[1]=max(partials[256..512)) (k)
__global__ __launch_bounds__(256) void reducemax2_kernel(const float* __restrict__ partials,
                                                         float* __restrict__ gmax) {
  __shared__ float sm[8];
  const int tid = threadIdx.x;
  for (int half = 0; half < 2; ++half) {
    float mx = partials[half * 256 + tid];
#pragma unroll
    for (int off = 32; off >= 1; off >>= 1) mx = fmaxf(mx, __shfl_down(mx, off, 64));
    if ((tid & 63) == 0) sm[(half << 2) + (tid >> 6)] = mx;
  }
  __syncthreads();
  if (tid == 0) gmax[0] = fmaxf(fmaxf(sm[0], sm[1]), fmaxf(sm[2], sm[3]));
  if (tid == 1) gmax[1] = fmaxf(fmaxf(sm[4], sm[5]), fmaxf(sm[6], sm[7]));
}

// elementwise exp (row-major): P = bf16(exp(raw - PNRM*norm[row] - gm)/sqrt(M))
__global__ __launch_bounds__(256) void expq_kernel(const float* __restrict__ lf,
                                                   const float* __restrict__ gmx,
                                                   const float* __restrict__ rn,
                                                   unsigned short* __restrict__ P) {
  long i = ((long)blockIdx.x * 256 + threadIdx.x) * 4;
  const float gm = gmx[0];
  const float nrm = PNRM * rn[i >> 7];          // 4 elems share a row (4 | 128)
  f32x4 v = *(const f32x4*)&lf[i];
  bf16x4 o;
#pragma unroll
  for (int r = 0; r < 4; ++r)
    o[r] = (short)f2b(__expf(fminf(v[r] - nrm - gm, 0.f)) * PINV);
  *(bf16x4*)&P[i] = o;
}

// fused exp + transpose: lf (B x S x M f32 raw logits) -> out (B x M x S bf16 phi)
__global__ __launch_bounds__(256) void expT_kernel(const float* __restrict__ lf,
                                                   const float* __restrict__ gmx,
                                                   const float* __restrict__ rn,
                                                   unsigned short* __restrict__ out) {
  __shared__ unsigned short t[32][33];
  const int b = blockIdx.z;
  const float gm = gmx[0];
  const int bx = blockIdx.x << 5, by = blockIdx.y << 5;   // bx: M, by: S
  const int tx = threadIdx.x & 31, ty = threadIdx.x >> 5;
  const float* src = lf + (long)b * cS * cM;
  unsigned short* dst = out + (long)b * cM * cS;
#pragma unroll
  for (int i = ty; i < 32; i += 8) {
    const float nrm = PNRM * rn[(long)b * cS + by + i];
    float l = src[(long)(by + i) * cM + bx + tx];
    t[i][tx] = f2b(__expf(fminf(l - nrm - gm, 0.f)) * PINV);
  }
  __syncthreads();
#pragma unroll
  for (int i = ty; i < 32; i += 8)
    dst[(long)(bx + i) * cS + by + tx] = t[tx][i];
}

// kv f32 accumulators -> bf16
__global__ __launch_bounds__(256) void kvcvt_kernel(const float* __restrict__ kvacc,
                                                    unsigned short* __restrict__ kvtb) {
  long i = ((long)blockIdx.x * 256 + threadIdx.x) * 4;
  f32x4 v = *(const f32x4*)&kvacc[i];
  bf16x4 o;
#pragma unroll
  for (int r = 0; r < 4; ++r) o[r] = (short)f2b(v[r]);
  *(bf16x4*)&kvtb[i] = o;
}

// out[l*ldo + m] = scale * sum_e bq[l][e] * R[l][e][m]   (tiny, pre-loop)
__global__ __launch_bounds__(128) void phibias_kernel(const unsigned short* __restrict__ bq,
                                                      const unsigned short* __restrict__ R,
                                                      unsigned short* __restrict__ out,
                                                      float scale, int ldo) {
  const int l = blockIdx.x, m = threadIdx.x;
  const unsigned short* b = bq + (long)l * cE;
  const unsigned short* r = R + (long)l * cE * cM;
  float a = 0.f;
  for (int e = 0; e < cE; ++e) a += b2f(b[e]) * b2f(r[(long)e * cM + m]);
  out[(long)l * ldo + m] = f2b(a * scale);
}

// packed bias for fused GEMM: [bv(512)|bk(512)|bq(512)|sbqR(128)|sbkR(128)]
__global__ __launch_bounds__(256) void packb_kernel(const unsigned short* __restrict__ bv,
                                                    const unsigned short* __restrict__ bk,
                                                    const unsigned short* __restrict__ bq,
                                                    const unsigned short* __restrict__ sqk,
                                                    unsigned short* __restrict__ out) {
  const int l = blockIdx.x, t = threadIdx.x;
#pragma unroll
  for (int s = 0; s < 512; s += 256) {
    out[l * cNF + s + t]        = bv[l * 512 + s + t];
    out[l * cNF + 512 + s + t]  = bk[l * 512 + s + t];
    out[l * cNF + 1024 + s + t] = bq[l * 512 + s + t];
  }
  out[l * cNF + 1536 + t] = sqk[l * 256 + t];   // [sbqR(128)|sbkR(128)]
}

// z[b][m] = sum_s qtb[b][m][s]   (qtb is B x M x S)
__global__ __launch_bounds__(256) void zsumt_kernel(const unsigned short* __restrict__ qtb,
                                                    float* __restrict__ z) {
  __shared__ float sred[4];
  const int b = blockIdx.x, m = blockIdx.y, tid = threadIdx.x;
  const unsigned short* p = qtb + ((long)b * cM + m) * cS + (long)tid * 16;
  bf16x8 a = *(const bf16x8*)p;
  bf16x8 c = *(const bf16x8*)(p + 8);
  float s = 0.f;
#pragma unroll
  for (int t = 0; t < 8; ++t) s += b2f((unsigned short)a[t]) + b2f((unsigned short)c[t]);
#pragma unroll
  for (int off = 32; off >= 1; off >>= 1) s += __shfl_down(s, off, 64);
  const int w = tid >> 6, lane = tid & 63;
  if (lane == 0) sred[w] = s;
  __syncthreads();
  if (tid == 0) z[b * cM + m] = sred[0] + sred[1] + sred[2] + sred[3];
}

// den[row] = dot(pq[row,:], z[b,:]); 4 rows/block
__global__ __launch_bounds__(256) void den_kernel(const unsigned short* __restrict__ P,
                                                  const float* __restrict__ z,
                                                  float* __restrict__ den) {
  const int w = threadIdx.x >> 6, lane = threadIdx.x & 63;
  const long row = (long)blockIdx.x * 4 + w;
  const float* zb = z + (row >> 12) * cM;
  const unsigned short* p = P + row * cM;
  float d = b2f(p[lane]) * zb[lane] + b2f(p[lane + 64]) * zb[lane + 64];
#pragma unroll
  for (int off = 32; off >= 1; off >>= 1) d += __shfl_down(d, off, 64);
  if (lane == 0) den[row] = d;
}

// layernorm in place (bf16 -> bf16), one row per block
__global__ __launch_bounds__(256) void ln_kernel(unsigned short* __restrict__ a,
                                                 const unsigned short* __restrict__ g,
                                                 const unsigned short* __restrict__ bb) {
  __shared__ float sred[8];
  const long row = blockIdx.x;
  unsigned short* ar = a + row * cE;
  const int tid = threadIdx.x;
  float v0 = b2f(ar[tid]), v1 = b2f(ar[tid + 256]);
  float s = v0 + v1, sq = v0 * v0 + v1 * v1;
#pragma unroll
  for (int off = 32; off >= 1; off >>= 1) {
    s  += __shfl_down(s, off, 64);
    sq += __shfl_down(sq, off, 64);
  }
  const int w = tid >> 6, lane = tid & 63;
  if (lane == 0) { sred[w] = s; sred[4 + w] = sq; }
  __syncthreads();
  const float st  = sred[0] + sred[1] + sred[2] + sred[3];
  const float sqt = sred[4] + sred[5] + sred[6] + sred[7];
  const float mean = st * (1.f / 512.f);
  const float var  = fmaxf(sqt * (1.f / 512.f) - mean * mean, 0.f);
  const float rstd = rsqrtf(var + 1e-5f);
  ar[tid]       = f2b((v0 - mean) * rstd * b2f(g[tid])       + b2f(bb[tid]));
  ar[tid + 256] = f2b((v1 - mean) * rstd * b2f(g[tid + 256]) + b2f(bb[tid + 256]));
}

// batched bf16 transpose: in (R x C) -> out (C x R); grid (C/32, R/32, batch)
__global__ __launch_bounds__(256) void transpose_kernel(const unsigned short* __restrict__ in,
                                                        unsigned short* __restrict__ out,
                                                        int R, int C, long sIn, long sOut) {
  __shared__ unsigned short t[32][33];
  in  += (long)blockIdx.z * sIn;
  out += (long)blockIdx.z * sOut;
  const int bx = blockIdx.x << 5, by = blockIdx.y << 5;
  const int tx = threadIdx.x & 31, ty = threadIdx.x >> 5;
#pragma unroll
  for (int i = ty; i < 32; i += 8) t[i][tx] = in[(long)(by + i) * C + bx + tx];
  __syncthreads();
#pragma unroll
  for (int i = ty; i < 32; i += 8) out[(long)(bx + i) * R + by + tx] = t[tx][i];
}

// final head
__global__ __launch_bounds__(256) void head_kernel(const unsigned short* __restrict__ h,
                                                   const unsigned short* __restrict__ Wr1,
                                                   const unsigned short* __restrict__ br1,
                                                   const unsigned short* __restrict__ Wr2,
                                                   const unsigned short* __restrict__ br2,
                                                   void* __restrict__ out,
                                                   const int* __restrict__ flag) {
  __shared__ float pooled[cE];
  __shared__ float red[4];
  const int b = blockIdx.x, tid = threadIdx.x;
  pooled[tid]       = b2f(h[(long)b * cS * cE + tid]);
  pooled[tid + 256] = b2f(h[(long)b * cS * cE + tid + 256]);
  __syncthreads();
  float acc = b2f(br1[tid]);
  for (int e = 0; e < cE; ++e) acc += pooled[e] * b2f(Wr1[e * cHE + tid]);
  acc = fmaxf(acc, 0.f) * b2f(Wr2[tid]);
#pragma unroll
  for (int off = 32; off >= 1; off >>= 1) acc += __shfl_down(acc, off, 64);
  const int w = tid >> 6, lane = tid & 63;
  if (lane == 0) red[w] = acc;
  __syncthreads();
  if (tid == 0) {
    float r = red[0] + red[1] + red[2] + red[3] + b2f(br2[0]);
    if (flag[0]) ((float*)out)[b] = r;
    else         ((unsigned short*)out)[b] = f2b(r);
  }
}

// ---------------- host ----------------
extern "C" void kernel_launch(void* const* d_in, const int* in_sizes, int n_in,
                              void* d_out, int out_size, void* d_ws, size_t ws_size,
                              hipStream_t stream) {
  (void)in_sizes; (void)n_in; (void)out_size;

  char* ws = (char*)d_ws;
  size_t off = 0;
  auto alloc = [&](size_t bytes) -> void* {
    void* p = ws + off;
    off += (bytes + 255) & ~(size_t)255;
    return p;
  };
  // ---- memory plan ----
  unsigned short* h   = (unsigned short*)alloc(cNBS * cE * 2);   // 67 MB residual
  unsigned short* X   = (unsigned short*)alloc(cNBS * cE * 2);   // 67 MB multi-use
  unsigned short* Y   = (unsigned short*)alloc(cNBS * cE * 2);   // 67 MB multi-use
  unsigned short* Pb  = (unsigned short*)alloc(cNBS * cM * 2);   // 16.8 MB phi(q)
  unsigned short* kvtb= (unsigned short*)alloc((long)cB * cM * cE * 2); // 2.1 MB kv (M x E)
  unsigned short* kvotb=(unsigned short*)alloc((long)cB * cE * cM * 2); // 2.1 MB (kv@Wo)^T
  float* kvacc        = (float*)alloc((long)cB * cM * cE * 4);   // 4 MB f32 kv acc
  float* vec64k       = (float*)alloc(cNBS * 4);                 // den
  float* rnorm2       = (float*)alloc(2 * cNBS * 4);             // 512 KB: [k | q] row-norms
  float* rmax         = (float*)alloc(4 * cNBS * 4);             // 1 MB: [q0|q1|k0|k1] row maxes
  float* z            = (float*)alloc(cB * cM * 4);
  float* partials     = (float*)alloc(1024 * 4);                 // [q 256 | k 256] block maxes
  float* gmaxf        = (float*)alloc(256);                      // gmax[0]=q, gmax[1]=k
  int*   dflag        = (int*)alloc(256);
  unsigned short* WiT = (unsigned short*)alloc((long)cE * cDIN * 2);
  unsigned short* BigB= (unsigned short*)alloc((long)cL * cNF * cE * 2); // 7.3 MB [WvT|WkT|WqT|WqRT|WkRT]
  unsigned short* WoT = (unsigned short*)alloc((long)cL * cE * cE * 2);
  unsigned short* RT  = (unsigned short*)alloc((long)cL * cM * cE * 2);
  unsigned short* W1T = (unsigned short*)alloc((long)cL * cFF * cE * 2);
  unsigned short* W2T = (unsigned short*)alloc((long)cL * cE * cFF * 2);
  unsigned short* sb  = (unsigned short*)alloc(170000 * 2);

  // weight staging inside X (dead until first in-loop X use)
  unsigned short* WqB = X;
  unsigned short* WkB = WqB + (long)cL * cE * cE;
  unsigned short* WvB = WkB + (long)cL * cE * cE;
  unsigned short* WoB = WvB + (long)cL * cE * cE;
  unsigned short* RmB = WoB + (long)cL * cE * cE;
  unsigned short* W1B = RmB + (long)cL * cE * cM;
  unsigned short* W2B = W1B + (long)cL * cE * cFF;
  unsigned short* WiB = W2B + (long)cL * cE * cFF;
  // x, pos staging inside Y
  unsigned short* xb   = Y;
  unsigned short* posb = Y + cNBS * cDIN;
  // small tensors inside sb
  unsigned short* biC  = sb;
  unsigned short* bqC  = biC  + 512;
  unsigned short* bkC  = bqC  + 2048;
  unsigned short* bvC  = bkC  + 2048;
  unsigned short* boC  = bvC  + 2048;
  unsigned short* b1C  = boC  + 2048;
  unsigned short* b2C  = b1C  + 8192;
  unsigned short* lngC = b2C  + 2048;
  unsigned short* lnbC = lngC + 2048;
  unsigned short* Wr1C = lnbC + 2048;
  unsigned short* br1C = Wr1C + 131072;
  unsigned short* Wr2C = br1C + 256;
  unsigned short* br2C = Wr2C + 256;
  unsigned short* bqkC  = br2C + 16;            // [scale*(bq@R) | scale*(bk@R)], L x 256
  unsigned short* b1792C = bqkC + cL * 256;     // packed fused bias, L x 1792

  unsigned short* qtb  = X;                       // pk^T (B x M x S), 16.8 MB
  float* logfX         = (float*)X;               // [raw logf_q | raw logf_k] f32, 67 MB
  unsigned short* vtb  = Y;                       // v^T (B x E x S)
  unsigned short* ab   = Y;                       // a / y (LN in place)
  unsigned short* u1b  = X;                       // FFN hidden chunk (16384 x 2048)

  if (off > ws_size) return;

  // ---- dtype detect + convert all inputs to bf16 ----
  detect_kernel<<<1, 64, 0, stream>>>((const unsigned short*)d_in[13], dflag);
  auto cvt = [&](const void* src, unsigned short* dst, long n) {
    cvt_kernel<<<(unsigned)((n + 255) / 256), 256, 0, stream>>>(src, dst, n, dflag);
  };
  cvt(d_in[0],  xb,   cNBS * cDIN);
  cvt(d_in[1],  WiB,  (long)cDIN * cE);
  cvt(d_in[2],  biC,  cE);
  cvt(d_in[3],  posb, (long)cS * cE);
  cvt(d_in[4],  WqB,  (long)cL * cE * cE);
  cvt(d_in[5],  bqC,  (long)cL * cE);
  cvt(d_in[6],  WkB,  (long)cL * cE * cE);
  cvt(d_in[7],  bkC,  (long)cL * cE);
  cvt(d_in[8],  WvB,  (long)cL * cE * cE);
  cvt(d_in[9],  bvC,  (long)cL * cE);
  cvt(d_in[10], WoB,  (long)cL * cE * cE);
  cvt(d_in[11], boC,  (long)cL * cE);
  cvt(d_in[12], RmB,  (long)cL * cE * cM);
  cvt(d_in[13], lngC, (long)cL * cE);
  cvt(d_in[14], lnbC, (long)cL * cE);
  cvt(d_in[15], W1B,  (long)cL * cE * cFF);
  cvt(d_in[16], b1C,  (long)cL * cFF);
  cvt(d_in[17], W2B,  (long)cL * cFF * cE);
  cvt(d_in[18], b2C,  (long)cL * cE);
  cvt(d_in[19], Wr1C, (long)cE * cHE);
  cvt(d_in[20], br1C, cHE);
  cvt(d_in[21], Wr2C, cHE);
  cvt(d_in[22], br2C, 1);

  typedef const unsigned short* cus;
  auto gemm = [&](const void* A, const void* Bt, const void* bias_,
                  const float* aux_, float* pmax_, void* C,
                  long rows, int K, int N, int lda, int ldb, float alpha, int flags,
                  long sA, long sB, long sC, int batches, const void* Res_ = nullptr) {
    dim3 g((unsigned)(rows / 128), (unsigned)(N / 128), (unsigned)batches);
    gemm_kernel<<<g, dim3(256), 0, stream>>>(
        (const unsigned short*)A, (const unsigned short*)Bt,
        (const unsigned short*)bias_, (const unsigned short*)Res_,
        aux_, pmax_, C, K, N, lda, ldb, alpha, flags, sA, sB, sC);
  };

  // ---- weight pre-transposes (BigB = [WvT|WkT|WqT|WqRT|WkRT] per layer) ----
  transpose_kernel<<<dim3(16, 2, 1), 256, 0, stream>>>(WiB, WiT, cDIN, cE, 0, 0);
  transpose_kernel<<<dim3(16, 16, cL), 256, 0, stream>>>(WvB, BigB, cE, cE, (long)cE * cE, (long)cNF * cE);
  transpose_kernel<<<dim3(16, 16, cL), 256, 0, stream>>>(WkB, BigB + (long)512 * cE, cE, cE, (long)cE * cE, (long)cNF * cE);
  transpose_kernel<<<dim3(16, 16, cL), 256, 0, stream>>>(WqB, BigB + (long)1024 * cE, cE, cE, (long)cE * cE, (long)cNF * cE);
  transpose_kernel<<<dim3(16, 16, cL), 256, 0, stream>>>(WoB, WoT, cE, cE, (long)cE * cE, (long)cE * cE);
  transpose_kernel<<<dim3(4, 16, cL), 256, 0, stream>>>(RmB, RT, cE, cM, (long)cE * cM, (long)cE * cM);
  transpose_kernel<<<dim3(64, 16, cL), 256, 0, stream>>>(W1B, W1T, cE, cFF, (long)cE * cFF, (long)cE * cFF);
  transpose_kernel<<<dim3(16, 64, cL), 256, 0, stream>>>(W2B, W2T, cFF, cE, (long)cFF * cE, (long)cFF * cE);

  // ---- fold R into Wq/Wk, directly into BigB rows 1536..1791 ----
  gemm(RT, WqB, nullptr, nullptr, nullptr, BigB + (long)1536 * cE, cM, cE, cE, cE, cE, 1.f, 0,
       (long)cM * cE, (long)cE * cE, (long)cNF * cE, cL);
  gemm(RT, WkB, nullptr, nullptr, nullptr, BigB + (long)1664 * cE, cM, cE, cE, cE, cE, 1.f, 0,
       (long)cM * cE, (long)cE * cE, (long)cNF * cE, cL);
  phibias_kernel<<<cL, 128, 0, stream>>>(bqC, RmB, bqkC, PSCALE, 256);
  phibias_kernel<<<cL, 128, 0, stream>>>(bkC, RmB, bqkC + 128, PSCALE, 256);
  packb_kernel<<<cL, 256, 0, stream>>>(bvC, bkC, bqC, bqkC, b1792C);

  // ---- input projection + positional embedding ----
  gemm(xb, WiT, biC, nullptr, nullptr, h, cNBS, cDIN, cE, cDIN, cDIN, 1.f,
       FLAG_BIAS, 0, 0, 0, 1);
  addpos_kernel<<<16384, 256, 0, stream>>>(h, posb);

  for (int i = 0; i < cL; ++i) {
    cus WoT_i = WoT + (long)i * cE * cE;  cus bo_i = boC + (long)i * cE;
    cus BigB_i = BigB + (long)i * cNF * cE;
    cus b1792_i = b1792C + (long)i * cNF;
    cus g_i   = lngC + (long)i * cE;      cus b_i  = lnbC + (long)i * cE;
    cus W1T_i = W1T + (long)i * cFF * cE; cus b1_i = b1C + (long)i * cFF;
    cus W2T_i = W2T + (long)i * cE * cFF; cus b2_i = b2C + (long)i * cE;

    // --- fused ONE pass over h: v^T (VT), ||k||^2+||q||^2 (RNORM atomics),
    //     raw q/k phi logits + per-row maxes; XCD-swizzled ---
    zero4_kernel<<<128, 256, 0, stream>>>(rnorm2);
    gemm_kernel<<<dim3(14, 512, 1), dim3(256), 0, stream>>>(
        h, BigB_i, b1792_i, (const unsigned short*)logfX, (const float*)rmax,
        rnorm2, vtb, cE, cNF, cE, cE, 1.f, FLAG_FUSED | FLAG_SWZ,
        0, 0, (long)cE * cS);

    // --- deferred norm+max: gm = max_r(rowmax - PNRM*norm), then exp ---
    reduceg_kernel<<<512, 256, 0, stream>>>(rmax, rnorm2, partials);
    reducemax2_kernel<<<1, 256, 0, stream>>>(partials, gmaxf);
    expq_kernel<<<8192, 256, 0, stream>>>(logfX, gmaxf, rnorm2 + cNBS, Pb);
    expT_kernel<<<dim3(4, 128, cB), 256, 0, stream>>>(logfX + cNBS * cM, gmaxf + 1, rnorm2, qtb);

    // --- z, den ---
    zsumt_kernel<<<dim3(cB, cM), 256, 0, stream>>>(qtb, z);
    den_kernel<<<16384, 256, 0, stream>>>(Pb, z, vec64k);

    // --- kv[b] (M x E) = pk^T[b] @ v^T[b]^T, split-K x8 in-cache atomics ---
    zero4_kernel<<<1024, 256, 0, stream>>>(kvacc);
    gemm(qtb, vtb, nullptr, nullptr, nullptr, kvacc, cM, cS / 8, cE, cS, cS, 1.f,
         FLAG_SPLITK8 | FLAG_ATOMIC, (long)cM * cS, (long)cE * cS, (long)cM * cE, cB * 8);
    kvcvt_kernel<<<1024, 256, 0, stream>>>(kvacc, kvtb);

    // --- fold Wo into kv: kvo^T[b] (E x M) = WoT @ kv[b]^T  (tiny, 64 blocks) ---
    gemm(WoT_i, kvtb, nullptr, nullptr, nullptr, kvotb, cE, cE, cM, cE, cE, 1.f,
         0, 0, (long)cM * cE, (long)cE * cM, cB);

    // --- a[b] = (pq[b] @ kvo[b]) / (den+1e-6) + bo -> Y ; LN in place ---
    gemm(Pb, kvotb, bo_i, vec64k, nullptr, ab, cS, cM, cE, cM, cM, 1.f,
         FLAG_DEN | FLAG_BIAS, (long)cS * cM, (long)cE * cM, (long)cS * cE, cB);
    ln_kernel<<<cNBS, 256, 0, stream>>>(ab, g_i, b_i);

    // --- FFN in 4 row-chunks of 16384; h += ffn(y); XCD-swizzled ---
    for (int c = 0; c < 4; ++c) {
      const unsigned short* yc = ab + (long)c * 16384 * cE;
      unsigned short* hc = h + (long)c * 16384 * cE;
      gemm_kernel<<<dim3(16, 128, 1), dim3(256), 0, stream>>>(
          yc, W1T_i, b1_i, nullptr, nullptr, nullptr, u1b,
          cE, cFF, cE, cE, 1.f, FLAG_BIAS | FLAG_GELU | FLAG_SWZ, 0, 0, 0);
      gemm_kernel<<<dim3(4, 128, 1), dim3(256), 0, stream>>>(
          u1b, W2T_i, b2_i, hc, nullptr, nullptr, hc,
          cFF, cE, cFF, cFF, 1.f, FLAG_BIAS | FLAG_RES | FLAG_SWZ, 0, 0, 0);
    }
  }

  head_kernel<<<cB, 256, 0, stream>>>(h, Wr1C, br1C, Wr2C, br2C, d_out, dflag);
}

// Round 15
// 3482.820 us; speedup vs baseline: 1.3280x; 1.0405x over previous
//
#include <hip/hip_runtime.h>
#include <math.h>

// ---------------- problem constants ----------------
static constexpr int  cB   = 16;
static constexpr int  cS   = 4096;
static constexpr int  cDIN = 64;
static constexpr int  cE   = 512;
static constexpr int  cM   = 128;
static constexpr int  cL   = 4;
static constexpr int  cFF  = 2048;   // 4*E
static constexpr int  cHE  = 256;    // E/2
static constexpr long cNBS = (long)cB * cS;   // 65536 rows
static constexpr int  cNF  = 1792;   // fused N = 512(v)+512(k-norm)+512(q-norm)+128(phiq)+128(phik)

typedef __attribute__((ext_vector_type(8))) short  bf16x8;
typedef __attribute__((ext_vector_type(4))) short  bf16x4;
typedef __attribute__((ext_vector_type(4))) float  f32x4;

typedef const __attribute__((address_space(1))) unsigned int g_u32;
typedef __attribute__((address_space(3))) unsigned int l_u32;

__device__ __forceinline__ float b2f(unsigned short u) {
  union { unsigned int i; float f; } x; x.i = ((unsigned int)u) << 16; return x.f;
}
__device__ __forceinline__ unsigned short f2b(float f) {
  union { float f; unsigned int i; } x; x.f = f;
  unsigned int r = x.i + 0x7FFFu + ((x.i >> 16) & 1u);   // RNE
  return (unsigned short)(r >> 16);
}

// phi math (round-6 post-mortem): max-shift and q-row-norm do NOT cancel out
// of num/(den+1e-6); faithful computation kept (round-7: absmax 0.0078).
// round-15: FUSED stores phi' = exp(l - halfmax) as bf16 (halfmax already
// in-epilogue); scaleq/scaleT apply exp(halfmax - PNRM*norm - gm). Same math,
// one extra bf16 rounding; halves the exp-pipeline traffic.
#define PSCALE 0.21022410381342863f     // 512^-0.25
#define PNRM   0.022097086912079608f    // 0.5 * PSCALE^2
#define PINV   0.08838834764831845f     // 1/sqrt(M)

// ---------------- GEMM: C[rows x N] = f(alpha*A@Bt^T + bias) -------------
// A: rows x K bf16 (row stride lda). Bt: N x K bf16 (row stride ldb).
#define FLAG_BIAS    2
#define FLAG_GELU    4
#define FLAG_RES     8     // += bf16 Res[idx]
#define FLAG_VT      16    // store transposed per 4096-row batch, batch stride sC
#define FLAG_DEN     32    // v = acc/(aux[zb*rowsPerBatch+rr]+1e-6) BEFORE bias
#define FLAG_RNORM   64    // no C store; atomicAdd row-norms of (acc+bias) into pmax[rnoff+row]
#define FLAG_F32OUT  256   // store f32
#define FLAG_SPLITK8 512   // blockIdx.z = batch*8 + k-chunk
#define FLAG_ATOMIC  1024  // f32 atomicAdd into C (indexed by batch zb)
#define FLAG_FUSED   2048  // (with SWZ, grid (14,512)): by<4 VT(v), by<8 RNORM(k),
                           // by<12 RNORM(q), by=12 phi'(q), by=13 phi'(k)
#define FLAG_SWZ     4096  // grid (NBcols, nbx): XCD-aware remap so all column-blocks
                           // sharing an A-row-panel land on ONE XCD's L2 (round-9:
                           // FETCH 269.6 -> 41.5 MB on the FUSED dispatch)

#define GMT 128
#define GNT 128
#define GBK 64

// round-13 measured: GBK 32->64 + row&7 chunk-XOR = -258us (FUSED 158->136,
// MfmaUtil 33%, BANK_CONFLICT 1.3e7->5.2e5).

__global__ __launch_bounds__(256, 2)
void gemm_kernel(const unsigned short* __restrict__ A,
                 const unsigned short* __restrict__ Bt,
                 const unsigned short* __restrict__ bias,
                 const unsigned short* __restrict__ Res,
                 const float* __restrict__ aux,
                 float* __restrict__ pmax,
                 void* __restrict__ C,
                 int K, int N, int lda, int ldb, float alpha, int flags,
                 long sA, long sB, long sC)
{
  // 32 KB shared: As(16K)+Bs(16K) during K-loop; stage aliases them post-loop (VT).
  __shared__ __align__(16) unsigned char sraw[32768];
  unsigned short (*As)[64] = (unsigned short (*)[64])sraw;
  unsigned short (*Bs)[64] = (unsigned short (*)[64])(sraw + 16384);
  unsigned short (*stage)[136] = (unsigned short (*)[136])sraw;   // VT post-loop (17408 B)

  const int tid  = threadIdx.x;
  const int lane = tid & 63;
  const int wid  = tid >> 6;

  int bx = blockIdx.x, by = blockIdx.y;
  if (flags & FLAG_SWZ) {
    // lid%8 = XCD (observed round-robin); give each XCD a contiguous bx range,
    // iterate by fastest within it -> A-panel read by exactly one L2.
    const unsigned lid  = blockIdx.x + gridDim.x * blockIdx.y;
    const unsigned xcd  = lid & 7u;
    const unsigned slot = lid >> 3;
    bx = (int)(xcd * (gridDim.y >> 3) + slot / gridDim.x);
    by = (int)(slot % gridDim.x);
  }

  long zb = blockIdx.z;            // batch index (for A/B/aux)
  const long zc = blockIdx.z;      // C-store base index (keeps k-chunk for split-K)
  int koff = 0;
  if (flags & FLAG_SPLITK8) { koff = (int)(zb & 7) * K; zb >>= 3; }

  const unsigned short* Ab = A + zb * sA + (long)bx * GMT * lda + koff;
  const unsigned short* Bb = Bt + zb * sB + (long)by * GNT * ldb + koff;

  // staging (128 rows x 64 cols per matrix, 4 stripes of 32 rows):
  // LDS dest stays LINEAR (stripe*4096 + tid*16 bytes, wave-contiguous);
  // global source chunk is XOR-swizzled by row&7 so fragment b128 reads
  // stay conflict-light despite 128B row stride.
  const int srow  = tid >> 3;                            // 0..31 within stripe
  const int scolG = (((tid & 7) ^ (srow & 7)) << 3);     // swizzled global col
  const unsigned short* gA = Ab + (long)srow * lda + scolG;
  const unsigned short* gB = Bb + (long)srow * ldb + scolG;
  l_u32* lA = (l_u32*)(sraw + tid * 16);
  l_u32* lB = (l_u32*)(sraw + 16384 + tid * 16);

  const f32x4 fzero = {0.f, 0.f, 0.f, 0.f};
  f32x4 acc[4][4];
#pragma unroll
  for (int i = 0; i < 4; ++i)
#pragma unroll
    for (int j = 0; j < 4; ++j) acc[i][j] = fzero;

  const int wm = (wid >> 1) << 6;
  const int wn = (wid & 1) << 6;
  const int fm = lane & 15;
  const int kqh = lane >> 4;   // 0..3 (which 16B chunk of the K=32 slice)

  const long ka32 = (long)32 * lda, kb32 = (long)32 * ldb;
  for (int k0 = 0; k0 < K; k0 += GBK) {
#pragma unroll
    for (int s = 0; s < 4; ++s) {
      __builtin_amdgcn_global_load_lds((g_u32*)(gA + (long)s * ka32 + k0),
                                       (l_u32*)((__attribute__((address_space(3))) char*)lA + s * 4096), 16, 0, 0);
      __builtin_amdgcn_global_load_lds((g_u32*)(gB + (long)s * kb32 + k0),
                                       (l_u32*)((__attribute__((address_space(3))) char*)lB + s * 4096), 16, 0, 0);
    }
    __syncthreads();

#pragma unroll
    for (int kk = 0; kk < 2; ++kk) {
      bf16x8 af[4], bfv[4];
#pragma unroll
      for (int i = 0; i < 4; ++i) {
        const int ca = ((((kk << 2) | kqh) ^ (fm & 7)) << 3);
        af[i]  = *(const bf16x8*)&As[wm + i * 16 + fm][ca];
        bfv[i] = *(const bf16x8*)&Bs[wn + i * 16 + fm][ca];
      }
#pragma unroll
      for (int i = 0; i < 4; ++i)
#pragma unroll
        for (int j = 0; j < 4; ++j)
          acc[i][j] = __builtin_amdgcn_mfma_f32_16x16x32_bf16(af[i], bfv[j], acc[i][j], 0, 0, 0);
    }
    __syncthreads();
  }

  // epilogue: C/D layout col=lane&15, row=(lane>>4)*4+reg  [verified m89/m91]
  const int rq = (lane >> 4) << 2;
  const long crow0 = (long)bx * GMT + wm;
  const int  ccol0 = by * GNT + wn;

  long rnoff = 0;
  if (flags & FLAG_FUSED) {
    if (by >= 12) {
      // phi' = exp(l - halfmax) bf16, l = PSCALE*acc + bias(=scale*b@R).
      // halfmax (per row, per 64-col wave half) stored to rmx; the per-row
      // norm and global max are applied later (reduceg + scaleq/scaleT).
      unsigned short* P = (unsigned short*)Res + (long)(by - 12) * (cNBS * (long)cM);
      float* rmx = (float*)aux + ((long)(by - 12) * 2 + (wn >> 6)) * cNBS;
#pragma unroll
      for (int i = 0; i < 4; ++i)
#pragma unroll
        for (int r = 0; r < 4; ++r) {
          const long rr = crow0 + i * 16 + rq + r;
          float lv[4];
          float mx = -3.0e38f;
#pragma unroll
          for (int j = 0; j < 4; ++j) {
            const int cc = ccol0 + j * 16 + fm;
            lv[j] = acc[i][j][r] * PSCALE + b2f(bias[cc]);
            mx = fmaxf(mx, lv[j]);
          }
          mx = fmaxf(mx, __shfl_xor(mx, 1, 64));
          mx = fmaxf(mx, __shfl_xor(mx, 2, 64));
          mx = fmaxf(mx, __shfl_xor(mx, 4, 64));
          mx = fmaxf(mx, __shfl_xor(mx, 8, 64));
          if (fm == 0) rmx[rr] = mx;
#pragma unroll
          for (int j = 0; j < 4; ++j) {
            const int cc = ccol0 + j * 16 + fm;
            P[rr * (long)cM + (cc & (cM - 1))] = f2b(__expf(lv[j] - mx));
          }
        }
      return;
    }
    if (by < 4) flags = FLAG_BIAS | FLAG_VT;
    else { flags = FLAG_BIAS | FLAG_RNORM; if (by >= 8) rnoff = cNBS; }
  }

  if (flags & FLAG_RNORM) {
    // row-norm of (acc*alpha + bias): reduce over this wave's 64 cols, atomic-add.
#pragma unroll
    for (int i = 0; i < 4; ++i)
#pragma unroll
      for (int r = 0; r < 4; ++r) {
        float s = 0.f;
#pragma unroll
        for (int j = 0; j < 4; ++j) {
          float v = acc[i][j][r] * alpha + b2f(bias[ccol0 + j * 16 + fm]);
          s += v * v;
        }
        s += __shfl_xor(s, 1, 64);
        s += __shfl_xor(s, 2, 64);
        s += __shfl_xor(s, 4, 64);
        s += __shfl_xor(s, 8, 64);
        if (fm == 0)
          unsafeAtomicAdd(&pmax[rnoff + crow0 + i * 16 + rq + r], s);
      }
    return;
  }

  if (flags & FLAG_ATOMIC) {
    // split-K reduction in-cache: f32 atomic add into C[zb]
    float* Cf = (float*)C + zb * sC;
#pragma unroll
    for (int j = 0; j < 4; ++j) {
      const int cc = ccol0 + j * 16 + fm;
#pragma unroll
      for (int i = 0; i < 4; ++i)
#pragma unroll
        for (int r = 0; r < 4; ++r) {
          const long rr = crow0 + i * 16 + rq + r;
          unsafeAtomicAdd(&Cf[rr * (long)N + cc], acc[i][j][r] * alpha);
        }
    }
    return;
  }

  if (flags & FLAG_VT) {
    // stage 64 cols x 128 rows in LDS, then coalesced column stores (64B/thread)
    unsigned short* Cb = (unsigned short*)C;
    const int bb = (bx * GMT) >> 12;
    const long sbase = (long)((bx * GMT) & (cS - 1));
#pragma unroll
    for (int rnd = 0; rnd < 2; ++rnd) {
      if ((wn >> 6) == rnd) {
#pragma unroll
        for (int j = 0; j < 4; ++j) {
          const int cc = ccol0 + j * 16 + fm;
          const float bv = (flags & FLAG_BIAS) ? b2f(bias[cc]) : 0.f;
          const int cl = j * 16 + fm;
#pragma unroll
          for (int i = 0; i < 4; ++i)
#pragma unroll
            for (int r = 0; r < 4; ++r)
              stage[cl][wm + i * 16 + rq + r] = f2b(acc[i][j][r] * alpha + bv);
        }
      }
      __syncthreads();
      {
        const int cl = tid >> 2;
        const int sseg = (tid & 3) << 5;
        const int gcol = by * GNT + rnd * 64 + cl;
        unsigned short* dst = Cb + (long)bb * sC + (long)gcol * cS + sbase + sseg;
#pragma unroll
        for (int t = 0; t < 4; ++t)
          *(bf16x8*)(dst + t * 8) = *(const bf16x8*)&stage[cl][sseg + t * 8];
      }
      __syncthreads();
    }
    return;
  }

  // generic epilogue. Order: acc -> DEN -> +bias -> GELU -> RES (DEN before bias
  // so att = (pq@kvo)/den + bo works; plain BIAS/GELU paths unaffected).
  const long rowsPerBatch = (long)gridDim.x * GMT;
#pragma unroll
  for (int j = 0; j < 4; ++j) {
    const int cc = ccol0 + j * 16 + fm;
    const float bv = (flags & FLAG_BIAS) ? b2f(bias[cc]) : 0.f;
#pragma unroll
    for (int i = 0; i < 4; ++i) {
      const long rbase = crow0 + i * 16 + rq;
#pragma unroll
      for (int r = 0; r < 4; ++r) {
        const long rr = rbase + r;
        float v = acc[i][j][r] * alpha;
        if (flags & FLAG_DEN)
          v *= 1.f / (fmaxf(aux[zb * rowsPerBatch + rr], 0.f) + 1e-6f);
        v += bv;
        if (flags & FLAG_GELU) v = 0.5f * v * (1.f + erff(v * 0.7071067811865475f));
        const long idx = zc * sC + rr * (long)N + cc;
        if (flags & FLAG_RES) v += b2f(Res[idx]);
        if (flags & FLAG_F32OUT) ((float*)C)[idx] = v;
        else                     ((unsigned short*)C)[idx] = f2b(v);
      }
    }
  }
}

// ---------------- dtype shim ----------------
__global__ void detect_kernel(const unsigned short* __restrict__ lng,
                              int* __restrict__ flag) {
  if (threadIdx.x == 0 && blockIdx.x == 0) flag[0] = (lng[0] == 0) ? 1 : 0;
}

// batched convert: all 23 inputs in one grid-strided launch (round-15:
// replaces 23 cvt dispatches, saving ~22 launch overheads)
struct CvtB { const void* s[23]; unsigned short* d[23]; long cum[24]; };

__global__ __launch_bounds__(256) void cvtall_kernel(CvtB b, const int* __restrict__ flag) {
  const long T = b.cum[23];
  const int f = flag[0];
  for (long i = (long)blockIdx.x * 256 + threadIdx.x; i < T;
       i += (long)gridDim.x * 256) {
    int t = 0;
#pragma unroll
    for (int k = 1; k < 23; ++k) t += (i >= b.cum[k]) ? 1 : 0;
    const long e = i - b.cum[t];
    b.d[t][e] = f ? f2b(((const float*)b.s[t])[e])
                  : ((const unsigned short*)b.s[t])[e];
  }
}

// ---------------- small kernels ----------------
__global__ __launch_bounds__(256) void zero4_kernel(float* __restrict__ p) {
  long i = ((long)blockIdx.x * 256 + threadIdx.x) * 4;
  f32x4 z = {0.f, 0.f, 0.f, 0.f};
  *(f32x4*)&p[i] = z;
}

__global__ __launch_bounds__(256) void addpos_kernel(unsigned short* __restrict__ h,
                                                     const unsigned short* __restrict__ pos) {
  long i = ((long)blockIdx.x * 256 + threadIdx.x) * 8;
  long se = i % ((long)cS * cE);
  bf16x8 v = *(bf16x8*)&h[i];
  bf16x8 p = *(const bf16x8*)&pos[se];
#pragma unroll
  for (int r = 0; r < 8; ++r)
    v[r] = (short)f2b(b2f((unsigned short)v[r]) + b2f((unsigned short)p[r]));
  *(bf16x8*)&h[i] = v;
}

// partials[b] = blockmax over 256 rows of (max(rmax halves) - PNRM*norm);
// b<256: q (rmax sides 0/1, norm at +cNBS); b>=256: k (sides 2/3, norm at 0).
__global__ __launch_bounds__(256) void reduceg_kernel(const float* __restrict__ rmax,
                                                      const float* __restrict__ rnorm2,
                                                      float* __restrict__ partials) {
  __shared__ float sm[4];
  const int b = blockIdx.x;
  const int side = b >> 8;                      // 0=q, 1=k
  const long row = ((long)(b & 255)) * 256 + threadIdx.x;
  const float nrm = PNRM * rnorm2[(side == 0 ? cNBS : 0) + row];
  float v = fmaxf(rmax[((long)side * 2 + 0) * cNBS + row],
                  rmax[((long)side * 2 + 1) * cNBS + row]) - nrm;
#pragma unroll
  for (int off = 32; off >= 1; off >>= 1) v = fmaxf(v, __shfl_down(v, off, 64));
  const int w = threadIdx.x >> 6, lane = threadIdx.x & 63;
  if (lane == 0) sm[w] = v;
  __syncthreads();
  if (threadIdx.x == 0)
    partials[b] = fmaxf(fmaxf(sm[0], sm[1]), fmaxf(sm[2], sm[3]));
}

// gmax[0]=max(partials[0..256)) (q), gmax[1]=max(partials[256..512)) (k)
__global__ __launch_bounds__(256) void reducemax2_kernel(const float* __restrict__ partials,
                                                         float* __restrict__ gmax) {
  __shared__ float sm[8];
  const int tid = threadIdx.x;
  for (int half = 0; half < 2; ++half) {
    float mx = partials[half * 256 + tid];
#pragma unroll
    for (int off = 32; off >= 1; off >>= 1) mx = fmaxf(mx, __shfl_down(mx, off, 64));
    if ((tid & 63) == 0) sm[(half << 2) + (tid >> 6)] = mx;
  }
  __syncthreads();
  if (tid == 0) gmax[0] = fmaxf(fmaxf(sm[0], sm[1]), fmaxf(sm[2], sm[3]));
  if (tid == 1) gmax[1] = fmaxf(fmaxf(sm[4], sm[5]), fmaxf(sm[6], sm[7]));
}

// in-place rescale: P *= exp(halfmax - PNRM*norm[row] - gm) * PINV
__global__ __launch_bounds__(256) void scaleq_kernel(unsigned short* __restrict__ P,
                                                     const float* __restrict__ gmx,
                                                     const float* __restrict__ rmax,
                                                     const float* __restrict__ rn) {
  long i = ((long)blockIdx.x * 256 + threadIdx.x) * 8;
  const float gm = gmx[0];
  const long row = i >> 7;
  const int half = (int)((i >> 6) & 1);
  const float f = __expf(rmax[(long)half * cNBS + row] - PNRM * rn[row] - gm) * PINV;
  bf16x8 v = *(bf16x8*)&P[i];
#pragma unroll
  for (int r = 0; r < 8; ++r)
    v[r] = (short)f2b(b2f((unsigned short)v[r]) * f);
  *(bf16x8*)&P[i] = v;
}

// rescale + transpose: phik (B x S x M bf16 phi') -> out (B x M x S bf16 phi)
__global__ __launch_bounds__(256) void scaleT_kernel(const unsigned short* __restrict__ phik,
                                                     const float* __restrict__ gmx,
                                                     const float* __restrict__ rmax,
                                                     const float* __restrict__ rn,
                                                     unsigned short* __restrict__ out) {
  __shared__ unsigned short t[32][33];
  const int b = blockIdx.z;
  const float gm = gmx[0];
  const int bx = blockIdx.x << 5, byy = blockIdx.y << 5;   // bx: M, byy: S
  const int tx = threadIdx.x & 31, ty = threadIdx.x >> 5;
  const int half = bx >> 6;
  const unsigned short* src = phik + (long)b * cS * cM;
  unsigned short* dst = out + (long)b * cM * cS;
#pragma unroll
  for (int i = ty; i < 32; i += 8) {
    const long row = (long)b * cS + byy + i;
    const float f = __expf(rmax[(long)half * cNBS + row] - PNRM * rn[row] - gm) * PINV;
    t[i][tx] = f2b(b2f(src[(long)(byy + i) * cM + bx + tx]) * f);
  }
  __syncthreads();
#pragma unroll
  for (int i = ty; i < 32; i += 8)
    dst[(long)(bx + i) * cS + byy + tx] = t[tx][i];
}

// kv f32 accumulators -> bf16
__global__ __launch_bounds__(256) void kvcvt_kernel(const float* __restrict__ kvacc,
                                                    unsigned short* __restrict__ kvtb) {
  long i = ((long)blockIdx.x * 256 + threadIdx.x) * 4;
  f32x4 v = *(const f32x4*)&kvacc[i];
  bf16x4 o;
#pragma unroll
  for (int r = 0; r < 4; ++r) o[r] = (short)f2b(v[r]);
  *(bf16x4*)&kvtb[i] = o;
}

// out[l*ldo + m] = scale * sum_e bq[l][e] * R[l][e][m]   (tiny, pre-loop)
__global__ __launch_bounds__(128) void phibias_kernel(const unsigned short* __restrict__ bq,
                                                      const unsigned short* __restrict__ R,
                                                      unsigned short* __restrict__ out,
                                                      float scale, int ldo) {
  const int l = blockIdx.x, m = threadIdx.x;
  const unsigned short* b = bq + (long)l * cE;
  const unsigned short* r = R + (long)l * cE * cM;
  float a = 0.f;
  for (int e = 0; e < cE; ++e) a += b2f(b[e]) * b2f(r[(long)e * cM + m]);
  out[(long)l * ldo + m] = f2b(a * scale);
}

// packed bias for fused GEMM: [bv(512)|bk(512)|bq(512)|sbqR(128)|sbkR(128)]
__global__ __launch_bounds__(256) void packb_kernel(const unsigned short* __restrict__ bv,
                                                    const unsigned short* __restrict__ bk,
                                                    const unsigned short* __restrict__ bq,
                                                    const unsigned short* __restrict__ sqk,
                                                    unsigned short* __restrict__ out) {
  const int l = blockIdx.x, t = threadIdx.x;
#pragma unroll
  for (int s = 0; s < 512; s += 256) {
    out[l * cNF + s + t]        = bv[l * 512 + s + t];
    out[l * cNF + 512 + s + t]  = bk[l * 512 + s + t];
    out[l * cNF + 1024 + s + t] = bq[l * 512 + s + t];
  }
  out[l * cNF + 1536 + t] = sqk[l * 256 + t];   // [sbqR(128)|sbkR(128)]
}

// z[b][m] = sum_s qtb[b][m][s]   (qtb is B x M x S)
__global__ __launch_bounds__(256) void zsumt_kernel(const unsigned short* __restrict__ qtb,
                                                    float* __restrict__ z) {
  __shared__ float sred[4];
  const int b = blockIdx.x, m = blockIdx.y, tid = threadIdx.x;
  const unsigned short* p = qtb + ((long)b * cM + m) * cS + (long)tid * 16;
  bf16x8 a = *(const bf16x8*)p;
  bf16x8 c = *(const bf16x8*)(p + 8);
  float s = 0.f;
#pragma unroll
  for (int t = 0; t < 8; ++t) s += b2f((unsigned short)a[t]) + b2f((unsigned short)c[t]);
#pragma unroll
  for (int off = 32; off >= 1; off >>= 1) s += __shfl_down(s, off, 64);
  const int w = tid >> 6, lane = tid & 63;
  if (lane == 0) sred[w] = s;
  __syncthreads();
  if (tid == 0) z[b * cM + m] = sred[0] + sred[1] + sred[2] + sred[3];
}

// den[row] = dot(pq[row,:], z[b,:]); 4 rows/block
__global__ __launch_bounds__(256) void den_kernel(const unsigned short* __restrict__ P,
                                                  const float* __restrict__ z,
                                                  float* __restrict__ den) {
  const int w = threadIdx.x >> 6, lane = threadIdx.x & 63;
  const long row = (long)blockIdx.x * 4 + w;
  const float* zb = z + (row >> 12) * cM;
  const unsigned short* p = P + row * cM;
  float d = b2f(p[lane]) * zb[lane] + b2f(p[lane + 64]) * zb[lane + 64];
#pragma unroll
  for (int off = 32; off >= 1; off >>= 1) d += __shfl_down(d, off, 64);
  if (lane == 0) den[row] = d;
}

// layernorm in place (bf16 -> bf16), one row per block
__global__ __launch_bounds__(256) void ln_kernel(unsigned short* __restrict__ a,
                                                 const unsigned short* __restrict__ g,
                                                 const unsigned short* __restrict__ bb) {
  __shared__ float sred[8];
  const long row = blockIdx.x;
  unsigned short* ar = a + row * cE;
  const int tid = threadIdx.x;
  float v0 = b2f(ar[tid]), v1 = b2f(ar[tid + 256]);
  float s = v0 + v1, sq = v0 * v0 + v1 * v1;
#pragma unroll
  for (int off = 32; off >= 1; off >>= 1) {
    s  += __shfl_down(s, off, 64);
    sq += __shfl_down(sq, off, 64);
  }
  const int w = tid >> 6, lane = tid & 63;
  if (lane == 0) { sred[w] = s; sred[4 + w] = sq; }
  __syncthreads();
  const float st  = sred[0] + sred[1] + sred[2] + sred[3];
  const float sqt = sred[4] + sred[5] + sred[6] + sred[7];
  const float mean = st * (1.f / 512.f);
  const float var  = fmaxf(sqt * (1.f / 512.f) - mean * mean, 0.f);
  const float rstd = rsqrtf(var + 1e-5f);
  ar[tid]       = f2b((v0 - mean) * rstd * b2f(g[tid])       + b2f(bb[tid]));
  ar[tid + 256] = f2b((v1 - mean) * rstd * b2f(g[tid + 256]) + b2f(bb[tid + 256]));
}

// batched bf16 transpose: in (R x C) -> out (C x R); grid (C/32, R/32, batch)
__global__ __launch_bounds__(256) void transpose_kernel(const unsigned short* __restrict__ in,
                                                        unsigned short* __restrict__ out,
                                                        int R, int C, long sIn, long sOut) {
  __shared__ unsigned short t[32][33];
  in  += (long)blockIdx.z * sIn;
  out += (long)blockIdx.z * sOut;
  const int bx = blockIdx.x << 5, by = blockIdx.y << 5;
  const int tx = threadIdx.x & 31, ty = threadIdx.x >> 5;
#pragma unroll
  for (int i = ty; i < 32; i += 8) t[i][tx] = in[(long)(by + i) * C + bx + tx];
  __syncthreads();
#pragma unroll
  for (int i = ty; i < 32; i += 8) out[(long)(bx + i) * R + by + tx] = t[tx][i];
}

// final head
__global__ __launch_bounds__(256) void head_kernel(const unsigned short* __restrict__ h,
                                                   const unsigned short* __restrict__ Wr1,
                                                   const unsigned short* __restrict__ br1,
                                                   const unsigned short* __restrict__ Wr2,
                                                   const unsigned short* __restrict__ br2,
                                                   void* __restrict__ out,
                                                   const int* __restrict__ flag) {
  __shared__ float pooled[cE];
  __shared__ float red[4];
  const int b = blockIdx.x, tid = threadIdx.x;
  pooled[tid]       = b2f(h[(long)b * cS * cE + tid]);
  pooled[tid + 256] = b2f(h[(long)b * cS * cE + tid + 256]);
  __syncthreads();
  float acc = b2f(br1[tid]);
  for (int e = 0; e < cE; ++e) acc += pooled[e] * b2f(Wr1[e * cHE + tid]);
  acc = fmaxf(acc, 0.f) * b2f(Wr2[tid]);
#pragma unroll
  for (int off = 32; off >= 1; off >>= 1) acc += __shfl_down(acc, off, 64);
  const int w = tid >> 6, lane = tid & 63;
  if (lane == 0) red[w] = acc;
  __syncthreads();
  if (tid == 0) {
    float r = red[0] + red[1] + red[2] + red[3] + b2f(br2[0]);
    if (flag[0]) ((float*)out)[b] = r;
    else         ((unsigned short*)out)[b] = f2b(r);
  }
}

// ---------------- host ----------------
extern "C" void kernel_launch(void* const* d_in, const int* in_sizes, int n_in,
                              void* d_out, int out_size, void* d_ws, size_t ws_size,
                              hipStream_t stream) {
  (void)in_sizes; (void)n_in; (void)out_size;

  char* ws = (char*)d_ws;
  size_t off = 0;
  auto alloc = [&](size_t bytes) -> void* {
    void* p = ws + off;
    off += (bytes + 255) & ~(size_t)255;
    return p;
  };
  // ---- memory plan ----
  unsigned short* h   = (unsigned short*)alloc(cNBS * cE * 2);   // 67 MB residual
  unsigned short* X   = (unsigned short*)alloc(cNBS * cE * 2);   // 67 MB multi-use
  unsigned short* Y   = (unsigned short*)alloc(cNBS * cE * 2);   // 67 MB multi-use
  unsigned short* Pb  = (unsigned short*)alloc(cNBS * cM * 2);   // 16.8 MB qtb
  unsigned short* kvtb= (unsigned short*)alloc((long)cB * cM * cE * 2); // 2.1 MB kv (M x E)
  unsigned short* kvotb=(unsigned short*)alloc((long)cB * cE * cM * 2); // 2.1 MB (kv@Wo)^T
  float* kvacc        = (float*)alloc((long)cB * cM * cE * 4);   // 4 MB f32 kv acc
  float* vec64k       = (float*)alloc(cNBS * 4);                 // den
  float* rnorm2       = (float*)alloc(2 * cNBS * 4);             // 512 KB: [k | q] row-norms
  float* rmax         = (float*)alloc(4 * cNBS * 4);             // 1 MB: [q0|q1|k0|k1] row maxes
  float* z            = (float*)alloc(cB * cM * 4);
  float* partials     = (float*)alloc(1024 * 4);                 // [q 256 | k 256] block maxes
  float* gmaxf        = (float*)alloc(256);                      // gmax[0]=q, gmax[1]=k
  int*   dflag        = (int*)alloc(256);
  unsigned short* WiT = (unsigned short*)alloc((long)cE * cDIN * 2);
  unsigned short* BigB= (unsigned short*)alloc((long)cL * cNF * cE * 2); // 7.3 MB [WvT|WkT|WqT|WqRT|WkRT]
  unsigned short* WoT = (unsigned short*)alloc((long)cL * cE * cE * 2);
  unsigned short* RT  = (unsigned short*)alloc((long)cL * cM * cE * 2);
  unsigned short* W1T = (unsigned short*)alloc((long)cL * cFF * cE * 2);
  unsigned short* W2T = (unsigned short*)alloc((long)cL * cE * cFF * 2);
  unsigned short* sb  = (unsigned short*)alloc(170000 * 2);

  // weight staging inside X (dead until first in-loop X use)
  unsigned short* WqB = X;
  unsigned short* WkB = WqB + (long)cL * cE * cE;
  unsigned short* WvB = WkB + (long)cL * cE * cE;
  unsigned short* WoB = WvB + (long)cL * cE * cE;
  unsigned short* RmB = WoB + (long)cL * cE * cE;
  unsigned short* W1B = RmB + (long)cL * cE * cM;
  unsigned short* W2B = W1B + (long)cL * cE * cFF;
  unsigned short* WiB = W2B + (long)cL * cE * cFF;
  // x, pos staging inside Y
  unsigned short* xb   = Y;
  unsigned short* posb = Y + cNBS * cDIN;
  // small tensors inside sb
  unsigned short* biC  = sb;
  unsigned short* bqC  = biC  + 512;
  unsigned short* bkC  = bqC  + 2048;
  unsigned short* bvC  = bkC  + 2048;
  unsigned short* boC  = bvC  + 2048;
  unsigned short* b1C  = boC  + 2048;
  unsigned short* b2C  = b1C  + 8192;
  unsigned short* lngC = b2C  + 2048;
  unsigned short* lnbC = lngC + 2048;
  unsigned short* Wr1C = lnbC + 2048;
  unsigned short* br1C = Wr1C + 131072;
  unsigned short* Wr2C = br1C + 256;
  unsigned short* br2C = Wr2C + 256;
  unsigned short* bqkC  = br2C + 16;            // [scale*(bq@R) | scale*(bk@R)], L x 256
  unsigned short* b1792C = bqkC + cL * 256;     // packed fused bias, L x 1792

  unsigned short* pq   = X;                       // phi'(q)->phi(q), B x S x M, 16.8 MB
  unsigned short* phik = X + (long)cNBS * cM;     // phi'(k), B x S x M, 16.8 MB
  unsigned short* qtb  = Pb;                      // pk^T (B x M x S), 16.8 MB
  unsigned short* vtb  = Y;                       // v^T (B x E x S)
  unsigned short* ab   = Y;                       // a / y (LN in place)
  unsigned short* u1b  = X;                       // FFN hidden chunk (16384 x 2048)

  if (off > ws_size) return;

  // ---- dtype detect + convert all inputs to bf16 (single batched launch) ----
  detect_kernel<<<1, 64, 0, stream>>>((const unsigned short*)d_in[13], dflag);
  {
    CvtB cb;
    long len[23];
    int ix = 0;
    auto addcv = [&](const void* s_, unsigned short* d_, long n_) {
      cb.s[ix] = s_; cb.d[ix] = d_; len[ix] = n_; ++ix;
    };
    addcv(d_in[0],  xb,   cNBS * cDIN);
    addcv(d_in[1],  WiB,  (long)cDIN * cE);
    addcv(d_in[2],  biC,  cE);
    addcv(d_in[3],  posb, (long)cS * cE);
    addcv(d_in[4],  WqB,  (long)cL * cE * cE);
    addcv(d_in[5],  bqC,  (long)cL * cE);
    addcv(d_in[6],  WkB,  (long)cL * cE * cE);
    addcv(d_in[7],  bkC,  (long)cL * cE);
    addcv(d_in[8],  WvB,  (long)cL * cE * cE);
    addcv(d_in[9],  bvC,  (long)cL * cE);
    addcv(d_in[10], WoB,  (long)cL * cE * cE);
    addcv(d_in[11], boC,  (long)cL * cE);
    addcv(d_in[12], RmB,  (long)cL * cE * cM);
    addcv(d_in[13], lngC, (long)cL * cE);
    addcv(d_in[14], lnbC, (long)cL * cE);
    addcv(d_in[15], W1B,  (long)cL * cE * cFF);
    addcv(d_in[16], b1C,  (long)cL * cFF);
    addcv(d_in[17], W2B,  (long)cL * cFF * cE);
    addcv(d_in[18], b2C,  (long)cL * cE);
    addcv(d_in[19], Wr1C, (long)cE * cHE);
    addcv(d_in[20], br1C, cHE);
    addcv(d_in[21], Wr2C, cHE);
    addcv(d_in[22], br2C, 1);
    cb.cum[0] = 0;
    for (int k = 0; k < 23; ++k) cb.cum[k + 1] = cb.cum[k] + len[k];
    cvtall_kernel<<<2048, 256, 0, stream>>>(cb, dflag);
  }

  typedef const unsigned short* cus;
  auto gemm = [&](const void* A, const void* Bt, const void* bias_,
                  const float* aux_, float* pmax_, void* C,
                  long rows, int K, int N, int lda, int ldb, float alpha, int flags,
                  long sA, long sB, long sC, int batches, const void* Res_ = nullptr) {
    dim3 g((unsigned)(rows / 128), (unsigned)(N / 128), (unsigned)batches);
    gemm_kernel<<<g, dim3(256), 0, stream>>>(
        (const unsigned short*)A, (const unsigned short*)Bt,
        (const unsigned short*)bias_, (const unsigned short*)Res_,
        aux_, pmax_, C, K, N, lda, ldb, alpha, flags, sA, sB, sC);
  };

  // ---- weight pre-transposes (BigB = [WvT|WkT|WqT|WqRT|WkRT] per layer) ----
  transpose_kernel<<<dim3(16, 2, 1), 256, 0, stream>>>(WiB, WiT, cDIN, cE, 0, 0);
  transpose_kernel<<<dim3(16, 16, cL), 256, 0, stream>>>(WvB, BigB, cE, cE, (long)cE * cE, (long)cNF * cE);
  transpose_kernel<<<dim3(16, 16, cL), 256, 0, stream>>>(WkB, BigB + (long)512 * cE, cE, cE, (long)cE * cE, (long)cNF * cE);
  transpose_kernel<<<dim3(16, 16, cL), 256, 0, stream>>>(WqB, BigB + (long)1024 * cE, cE, cE, (long)cE * cE, (long)cNF * cE);
  transpose_kernel<<<dim3(16, 16, cL), 256, 0, stream>>>(WoB, WoT, cE, cE, (long)cE * cE, (long)cE * cE);
  transpose_kernel<<<dim3(4, 16, cL), 256, 0, stream>>>(RmB, RT, cE, cM, (long)cE * cM, (long)cE * cM);
  transpose_kernel<<<dim3(64, 16, cL), 256, 0, stream>>>(W1B, W1T, cE, cFF, (long)cE * cFF, (long)cE * cFF);
  transpose_kernel<<<dim3(16, 64, cL), 256, 0, stream>>>(W2B, W2T, cFF, cE, (long)cFF * cE, (long)cFF * cE);

  // ---- fold R into Wq/Wk, directly into BigB rows 1536..1791 ----
  gemm(RT, WqB, nullptr, nullptr, nullptr, BigB + (long)1536 * cE, cM, cE, cE, cE, cE, 1.f, 0,
       (long)cM * cE, (long)cE * cE, (long)cNF * cE, cL);
  gemm(RT, WkB, nullptr, nullptr, nullptr, BigB + (long)1664 * cE, cM, cE, cE, cE, cE, 1.f, 0,
       (long)cM * cE, (long)cE * cE, (long)cNF * cE, cL);
  phibias_kernel<<<cL, 128, 0, stream>>>(bqC, RmB, bqkC, PSCALE, 256);
  phibias_kernel<<<cL, 128, 0, stream>>>(bkC, RmB, bqkC + 128, PSCALE, 256);
  packb_kernel<<<cL, 256, 0, stream>>>(bvC, bkC, bqC, bqkC, b1792C);

  // ---- input projection + positional embedding ----
  gemm(xb, WiT, biC, nullptr, nullptr, h, cNBS, cDIN, cE, cDIN, cDIN, 1.f,
       FLAG_BIAS, 0, 0, 0, 1);
  addpos_kernel<<<16384, 256, 0, stream>>>(h, posb);

  for (int i = 0; i < cL; ++i) {
    cus WoT_i = WoT + (long)i * cE * cE;  cus bo_i = boC + (long)i * cE;
    cus BigB_i = BigB + (long)i * cNF * cE;
    cus b1792_i = b1792C + (long)i * cNF;
    cus g_i   = lngC + (long)i * cE;      cus b_i  = lnbC + (long)i * cE;
    cus W1T_i = W1T + (long)i * cFF * cE; cus b1_i = b1C + (long)i * cFF;
    cus W2T_i = W2T + (long)i * cE * cFF; cus b2_i = b2C + (long)i * cE;

    // --- fused ONE pass over h: v^T (VT), ||k||^2+||q||^2 (RNORM atomics),
    //     phi'(q/k) bf16 + per-row-half maxes; XCD-swizzled ---
    zero4_kernel<<<128, 256, 0, stream>>>(rnorm2);
    gemm_kernel<<<dim3(14, 512, 1), dim3(256), 0, stream>>>(
        h, BigB_i, b1792_i, (const unsigned short*)pq, (const float*)rmax,
        rnorm2, vtb, cE, cNF, cE, cE, 1.f, FLAG_FUSED | FLAG_SWZ,
        0, 0, (long)cE * cS);

    // --- deferred norm+max: gm = max_r(rowmax - PNRM*norm), then rescale ---
    reduceg_kernel<<<512, 256, 0, stream>>>(rmax, rnorm2, partials);
    reducemax2_kernel<<<1, 256, 0, stream>>>(partials, gmaxf);
    scaleq_kernel<<<4096, 256, 0, stream>>>(pq, gmaxf, rmax, rnorm2 + cNBS);
    scaleT_kernel<<<dim3(4, 128, cB), 256, 0, stream>>>(phik, gmaxf + 1, rmax + 2 * cNBS, rnorm2, qtb);

    // --- z, den ---
    zsumt_kernel<<<dim3(cB, cM), 256, 0, stream>>>(qtb, z);
    den_kernel<<<16384, 256, 0, stream>>>(pq, z, vec64k);

    // --- kv[b] (M x E) = pk^T[b] @ v^T[b]^T, split-K x8 in-cache atomics ---
    zero4_kernel<<<1024, 256, 0, stream>>>(kvacc);
    gemm(qtb, vtb, nullptr, nullptr, nullptr, kvacc, cM, cS / 8, cE, cS, cS, 1.f,
         FLAG_SPLITK8 | FLAG_ATOMIC, (long)cM * cS, (long)cE * cS, (long)cM * cE, cB * 8);
    kvcvt_kernel<<<1024, 256, 0, stream>>>(kvacc, kvtb);

    // --- fold Wo into kv: kvo^T[b] (E x M) = WoT @ kv[b]^T  (tiny, 64 blocks) ---
    gemm(WoT_i, kvtb, nullptr, nullptr, nullptr, kvotb, cE, cE, cM, cE, cE, 1.f,
         0, 0, (long)cM * cE, (long)cE * cM, cB);

    // --- a[b] = (pq[b] @ kvo[b]) / (den+1e-6) + bo -> Y ; LN in place ---
    gemm(pq, kvotb, bo_i, vec64k, nullptr, ab, cS, cM, cE, cM, cM, 1.f,
         FLAG_DEN | FLAG_BIAS, (long)cS * cM, (long)cE * cM, (long)cS * cE, cB);
    ln_kernel<<<cNBS, 256, 0, stream>>>(ab, g_i, b_i);

    // --- FFN in 4 row-chunks of 16384; h += ffn(y); XCD-swizzled ---
    for (int c = 0; c < 4; ++c) {
      const unsigned short* yc = ab + (long)c * 16384 * cE;
      unsigned short* hc = h + (long)c * 16384 * cE;
      gemm_kernel<<<dim3(16, 128, 1), dim3(256), 0, stream>>>(
          yc, W1T_i, b1_i, nullptr, nullptr, nullptr, u1b,
          cE, cFF, cE, cE, 1.f, FLAG_BIAS | FLAG_GELU | FLAG_SWZ, 0, 0, 0);
      gemm_kernel<<<dim3(4, 128, 1), dim3(256), 0, stream>>>(
          u1b, W2T_i, b2_i, hc, nullptr, nullptr, hc,
          cFF, cE, cFF, cFF, 1.f, FLAG_BIAS | FLAG_RES | FLAG_SWZ, 0, 0, 0);
    }
  }

  head_kernel<<<cB, 256, 0, stream>>>(h, Wr1C, br1C, Wr2C, br2C, d_out, dflag);
}